// Round 2
// baseline (4620.006 us; speedup 1.0000x reference)
//
#include <hip/hip_runtime.h>
#include <hip/hip_bf16.h>
#include <math.h>

#define B_ 8
#define N_ 2000
#define C_ 32
#define T_ 12
#define K_ 3
#define FC_ 64
#define FT_ 64

__device__ __forceinline__ float sigmoidf(float v) { return 1.0f / (1.0f + __expf(-v)); }
__device__ __forceinline__ float bf2f(unsigned short u) {
    union { unsigned int i; float f; } v; v.i = ((unsigned int)u) << 16; return v.f;
}

// ---------------- temporal attention ----------------
// lhs1[b][t][c] = sum_n x[b][n][c][t] * U1[n]
__global__ __launch_bounds__(256) void k_lhs1(const float* __restrict__ x, const float* __restrict__ U1,
                                              float* __restrict__ lhs1) {
    int b = blockIdx.x / T_, t = blockIdx.x % T_;
    int tid = threadIdx.x;
    float acc[C_];
#pragma unroll
    for (int c = 0; c < C_; ++c) acc[c] = 0.f;
    for (int n = tid; n < N_; n += 256) {
        float u = U1[n];
        const float* xp = x + ((b * N_ + n) * C_) * T_ + t;
#pragma unroll
        for (int c = 0; c < C_; ++c) acc[c] += xp[c * T_] * u;
    }
#pragma unroll
    for (int c = 0; c < C_; ++c) {
        float v = acc[c];
        for (int off = 32; off > 0; off >>= 1) v += __shfl_down(v, off);
        acc[c] = v;
    }
    __shared__ float red[4][C_];
    int w = tid >> 6, lane = tid & 63;
    if (lane == 0) {
#pragma unroll
        for (int c = 0; c < C_; ++c) red[w][c] = acc[c];
    }
    __syncthreads();
    if (tid < C_) lhs1[(b * T_ + t) * C_ + tid] = red[0][tid] + red[1][tid] + red[2][tid] + red[3][tid];
}

// rhsT[b][n][t] = sum_c U3[c] * x[b][n][c][t]
__global__ __launch_bounds__(256) void k_rhs(const float* __restrict__ x, const float* __restrict__ U3,
                                             float* __restrict__ rhsT) {
    int gid = blockIdx.x * 256 + threadIdx.x;
    if (gid >= B_ * N_ * T_) return;
    int t = gid % T_;
    int bn = gid / T_;
    const float* xp = x + bn * (C_ * T_) + t;
    float a = 0.f;
#pragma unroll
    for (int c = 0; c < C_; ++c) a += U3[c] * xp[c * T_];
    rhsT[gid] = a;
}

// lhsT[b][t][n] = sum_c lhs1[b][t][c] * U2[c][n]
__global__ __launch_bounds__(256) void k_lhsT(const float* __restrict__ lhs1, const float* __restrict__ U2,
                                              float* __restrict__ lhsT) {
    int gid = blockIdx.x * 256 + threadIdx.x;
    if (gid >= B_ * T_ * N_) return;
    int n = gid % N_;
    int bt = gid / N_;
    const float* l1 = lhs1 + bt * C_;
    float a = 0.f;
#pragma unroll
    for (int c = 0; c < C_; ++c) a += l1[c] * U2[c * N_ + n];
    lhsT[gid] = a;
}

// P = lhs @ rhs, E = Ve @ sigmoid(P+be), At = softmax(E, axis=1)  (per b)
__global__ __launch_bounds__(256) void k_tatt(const float* __restrict__ lhsT, const float* __restrict__ rhsT,
                                              const float* __restrict__ be, const float* __restrict__ Ve,
                                              float* __restrict__ At) {
    int b = blockIdx.x;
    int tid = threadIdx.x;
    __shared__ float sL[T_][257];
    __shared__ float sR[256][T_];
    __shared__ float sp[144], sE[144], mk[12], sk[12];
    float acc = 0.f;
    int tP = tid / 12, uP = tid % 12;
    for (int n0 = 0; n0 < N_; n0 += 256) {
        int n = n0 + tid;
#pragma unroll
        for (int t = 0; t < T_; ++t) sL[t][tid] = (n < N_) ? lhsT[(b * T_ + t) * N_ + n] : 0.f;
#pragma unroll
        for (int t = 0; t < T_; ++t) sR[tid][t] = (n < N_) ? rhsT[(b * N_ + n) * T_ + t] : 0.f;
        __syncthreads();
        if (tid < 144) {
#pragma unroll 4
            for (int nn = 0; nn < 256; ++nn) acc += sL[tP][nn] * sR[nn][uP];
        }
        __syncthreads();
    }
    if (tid < 144) sp[tid] = sigmoidf(acc + be[tid]);
    __syncthreads();
    if (tid < 144) {
        float e = 0.f;
#pragma unroll
        for (int j = 0; j < T_; ++j) e += Ve[tP * T_ + j] * sp[j * T_ + uP];
        sE[tid] = e;
    }
    __syncthreads();
    if (tid < T_) {
        float m = -1e30f;
#pragma unroll
        for (int i = 0; i < T_; ++i) m = fmaxf(m, sE[i * T_ + tid]);
        float s = 0.f;
#pragma unroll
        for (int i = 0; i < T_; ++i) s += __expf(sE[i * T_ + tid] - m);
        mk[tid] = m; sk[tid] = 1.0f / s;
    }
    __syncthreads();
    if (tid < 144) At[b * 144 + tid] = __expf(sE[tid] - mk[uP]) * sk[uP];
}

// x_TAt[b][n][c][t] = sum_u x[b][n][c][u] * At[b][u][t]
__global__ __launch_bounds__(256) void k_xTAt(const float* __restrict__ x, const float* __restrict__ At,
                                              float* __restrict__ xTA) {
    int bx = blockIdx.x;  // 0..1999
    int b = bx / 250;
    int pair = (bx % 250) * 256 + threadIdx.x;  // n*32+c
    __shared__ float atl[144];
    if (threadIdx.x < 144) atl[threadIdx.x] = At[b * 144 + threadIdx.x];
    __syncthreads();
    const float* xp = x + (b * 64000 + pair) * T_;
    float r[T_], o[T_];
#pragma unroll
    for (int t = 0; t < T_; ++t) r[t] = xp[t];
#pragma unroll
    for (int t = 0; t < T_; ++t) {
        float a = 0.f;
#pragma unroll
        for (int u = 0; u < T_; ++u) a += r[u] * atl[u * T_ + t];
        o[t] = a;
    }
    float* op = xTA + (b * 64000 + pair) * T_;
#pragma unroll
    for (int t = 0; t < T_; ++t) op[t] = o[t];
}

// ---------------- spatial attention ----------------
// lhs_s[b][n][t], rhs_s[b][t][n]
__global__ __launch_bounds__(256) void k_sprep(const float* __restrict__ xTA, const float* __restrict__ W1,
                                               const float* __restrict__ W2, const float* __restrict__ W3,
                                               float* __restrict__ lhs_s, float* __restrict__ rhs_s) {
    int gid = blockIdx.x * 256 + threadIdx.x;
    if (gid >= B_ * N_) return;
    int b = gid / N_, n = gid % N_;
    const float* xp = xTA + gid * (C_ * T_);
    float ls[T_], rs[T_];
#pragma unroll
    for (int t = 0; t < T_; ++t) { ls[t] = 0.f; rs[t] = 0.f; }
    for (int c = 0; c < C_; ++c) {
        float row[T_];
#pragma unroll
        for (int t = 0; t < T_; ++t) row[t] = xp[c * T_ + t];
        float l1 = 0.f;
#pragma unroll
        for (int t = 0; t < T_; ++t) l1 += row[t] * W1[t];
        float w3 = W3[c];
#pragma unroll
        for (int t = 0; t < T_; ++t) { ls[t] += l1 * W2[c * T_ + t]; rs[t] += w3 * row[t]; }
    }
    float* lp = lhs_s + gid * T_;
#pragma unroll
    for (int t = 0; t < T_; ++t) lp[t] = ls[t];
#pragma unroll
    for (int t = 0; t < T_; ++t) rhs_s[(b * T_ + t) * N_ + n] = rs[t];
}

// S[b] = Vs @ sigmoid(lhs_s @ rhs_s + bs) : fused sigmoid, bf16 output
__global__ __launch_bounds__(256) void k_gemm_S(const float* __restrict__ A,
                                                const float* __restrict__ lhs_s,
                                                const float* __restrict__ rhs_s,
                                                const float* __restrict__ bs,
                                                __hip_bfloat16* __restrict__ Cm) {
    int b = blockIdx.z;
    int i0 = blockIdx.y * 128, k0 = blockIdx.x * 128;
    __hip_bfloat16* Cp = Cm + b * 4000000;
    __shared__ float As[8][132];
    __shared__ float Bs[8][128];
    __shared__ float sR[T_][128];
    __shared__ float sL[8][T_];
    int t = threadIdx.x;
    int tx = t & 15, ty = t >> 4;
    // stage rhs_s columns for this block once
    for (int q = t; q < T_ * 128; q += 256) {
        int tt = q >> 7, kk = q & 127;
        int col = k0 + kk;
        sR[tt][kk] = (col < 2000) ? rhs_s[b * (T_ * N_) + tt * N_ + col] : 0.f;
    }
    float acc[8][8];
#pragma unroll
    for (int i = 0; i < 8; ++i)
#pragma unroll
        for (int j = 0; j < 8; ++j) acc[i][j] = 0.f;
    int ar = t >> 1, ap = (t & 1) * 4;
    int bpp = t >> 5, bc = (t & 31) * 4;
    for (int p = 0; p < 2000; p += 8) {
        float4 av = make_float4(0.f, 0.f, 0.f, 0.f);
        int arow = i0 + ar;
        if (arow < 2000) av = *(const float4*)(A + arow * 2000 + p + ap);
        __syncthreads();  // previous iteration's reads of As/Bs done
        As[ap + 0][ar] = av.x; As[ap + 1][ar] = av.y; As[ap + 2][ar] = av.z; As[ap + 3][ar] = av.w;
        if (t < 8 * T_) {
            int r = t / T_, tt = t % T_;
            sL[r][tt] = lhs_s[(b * N_ + p + r) * T_ + tt];
        }
        __syncthreads();  // As, sL (and sR on iter 0) visible
        // build B tile = sigmoid(lhs_s @ rhs_s + bs)
        const float* bsrow = bs + (p + bpp) * 2000;
#pragma unroll
        for (int e = 0; e < 4; ++e) {
            int col = k0 + bc + e;
            float d = 0.f;
            if (col < 2000) {
                d = bsrow[col];
#pragma unroll
                for (int tt = 0; tt < T_; ++tt) d += sL[bpp][tt] * sR[tt][bc + e];
                d = sigmoidf(d);
            }
            Bs[bpp][bc + e] = d;
        }
        __syncthreads();  // Bs visible
#pragma unroll
        for (int pp = 0; pp < 8; ++pp) {
            float a[8], bb[8];
            *(float4*)&a[0] = *(const float4*)&As[pp][ty * 8];
            *(float4*)&a[4] = *(const float4*)&As[pp][ty * 8 + 4];
            *(float4*)&bb[0] = *(const float4*)&Bs[pp][tx * 8];
            *(float4*)&bb[4] = *(const float4*)&Bs[pp][tx * 8 + 4];
#pragma unroll
            for (int i = 0; i < 8; ++i)
#pragma unroll
                for (int j = 0; j < 8; ++j) acc[i][j] = fmaf(a[i], bb[j], acc[i][j]);
        }
    }
#pragma unroll
    for (int i = 0; i < 8; ++i) {
        int grow = i0 + ty * 8 + i;
        if (grow >= 2000) continue;
        int gcol = k0 + tx * 8;
        __hip_bfloat16* crow = Cp + grow * 2000 + gcol;
        if (gcol + 7 < 2000) {
            union { ushort4 u[2]; __hip_bfloat16 h[8]; } pk;
#pragma unroll
            for (int j = 0; j < 8; ++j) pk.h[j] = __float2bfloat16(acc[i][j]);
            *(ushort4*)crow = pk.u[0];
            *(ushort4*)(crow + 4) = pk.u[1];
        } else {
#pragma unroll
            for (int j = 0; j < 8; ++j)
                if (gcol + j < 2000) crow[j] = __float2bfloat16(acc[i][j]);
        }
    }
}

// ---- column softmax over i (axis=1) of S[b][i][k], bf16 in place ----
__global__ __launch_bounds__(256) void k_sm1(const __hip_bfloat16* __restrict__ S, float* __restrict__ pm, float* __restrict__ ps) {
    int k = blockIdx.x * 256 + threadIdx.x;
    int is = blockIdx.y, b = blockIdx.z;
    if (k >= N_) return;
    const __hip_bfloat16* sp = S + b * 4000000 + k;
    float m = -1e30f, s = 0.f;
    for (int i = is * 250; i < is * 250 + 250; ++i) {
        float v = __bfloat162float(sp[i * 2000]);
        float mn = fmaxf(m, v);
        s = s * __expf(m - mn) + __expf(v - mn);
        m = mn;
    }
    int o = (b * 8 + is) * 2048 + k;
    pm[o] = m; ps[o] = s;
}

__global__ __launch_bounds__(256) void k_sm2(const float* __restrict__ pm, const float* __restrict__ ps,
                                             float* __restrict__ gm, float* __restrict__ gs) {
    int k = blockIdx.x * 256 + threadIdx.x;
    int b = blockIdx.y;
    if (k >= N_) return;
    float m = -1e30f;
#pragma unroll
    for (int is = 0; is < 8; ++is) m = fmaxf(m, pm[(b * 8 + is) * 2048 + k]);
    float s = 0.f;
#pragma unroll
    for (int is = 0; is < 8; ++is) s += ps[(b * 8 + is) * 2048 + k] * __expf(pm[(b * 8 + is) * 2048 + k] - m);
    gm[b * 2048 + k] = m;
    gs[b * 2048 + k] = 1.0f / s;
}

__global__ __launch_bounds__(256) void k_sm3(__hip_bfloat16* __restrict__ S, const float* __restrict__ gm, const float* __restrict__ gs) {
    int k = blockIdx.x * 256 + threadIdx.x;
    int is = blockIdx.y, b = blockIdx.z;
    if (k >= N_) return;
    float m = gm[b * 2048 + k], r = gs[b * 2048 + k];
    __hip_bfloat16* sp = S + b * 4000000 + k;
    for (int i = is * 250; i < is * 250 + 250; ++i) {
        float v = __bfloat162float(sp[i * 2000]);
        sp[i * 2000] = __float2bfloat16(__expf(v - m) * r);
    }
}

// h2[b][kk][i][r] = sum_j (cheb[kk][j][i]*SAt[b][j][i]) * x[b][j][r],  r = c*12+t (384)
__global__ __launch_bounds__(256) void k_gemm_cheb(const float* __restrict__ cheb, const __hip_bfloat16* __restrict__ SAt,
                                                   const float* __restrict__ x, __hip_bfloat16* __restrict__ h2) {
    int bk = blockIdx.z;
    int b = bk / 3, kk = bk % 3;
    int i0 = blockIdx.y * 128;
    int r0 = blockIdx.x * 128;
    const float* chp = cheb + kk * 4000000;
    const __hip_bfloat16* sap = SAt + b * 4000000;
    const float* xp = x + b * 768000;
    __hip_bfloat16* hp = h2 + bk * 768000;
    __shared__ float As[8][132];
    __shared__ float Bs[8][128];
    int t = threadIdx.x;
    int tx = t & 15, ty = t >> 4;
    float acc[8][8];
#pragma unroll
    for (int i = 0; i < 8; ++i)
#pragma unroll
        for (int j = 0; j < 8; ++j) acc[i][j] = 0.f;
    int ajj = t >> 5, ai = (t & 31) * 4;
    for (int p = 0; p < 2000; p += 8) {
        int icol = i0 + ai;
        int jrow = p + ajj;
        float4 prod;
        if (icol + 3 < 2000) {
            float4 cv = *(const float4*)(chp + jrow * 2000 + icol);
            ushort4 sv = *(const ushort4*)((const unsigned short*)sap + jrow * 2000 + icol);
            prod = make_float4(cv.x * bf2f(sv.x), cv.y * bf2f(sv.y), cv.z * bf2f(sv.z), cv.w * bf2f(sv.w));
        } else {
            float p0 = 0.f, p1 = 0.f, p2 = 0.f, p3 = 0.f;
            const float* cb = chp + jrow * 2000;
            const __hip_bfloat16* sb = sap + jrow * 2000;
            if (icol + 0 < 2000) p0 = cb[icol + 0] * __bfloat162float(sb[icol + 0]);
            if (icol + 1 < 2000) p1 = cb[icol + 1] * __bfloat162float(sb[icol + 1]);
            if (icol + 2 < 2000) p2 = cb[icol + 2] * __bfloat162float(sb[icol + 2]);
            if (icol + 3 < 2000) p3 = cb[icol + 3] * __bfloat162float(sb[icol + 3]);
            prod = make_float4(p0, p1, p2, p3);
        }
        float4 bv = *(const float4*)(xp + jrow * 384 + r0 + ai);
        __syncthreads();
        *(float4*)&As[ajj][ai] = prod;
        *(float4*)&Bs[ajj][ai] = bv;
        __syncthreads();
#pragma unroll
        for (int pp = 0; pp < 8; ++pp) {
            float a[8], bb[8];
            *(float4*)&a[0] = *(const float4*)&As[pp][ty * 8];
            *(float4*)&a[4] = *(const float4*)&As[pp][ty * 8 + 4];
            *(float4*)&bb[0] = *(const float4*)&Bs[pp][tx * 8];
            *(float4*)&bb[4] = *(const float4*)&Bs[pp][tx * 8 + 4];
#pragma unroll
            for (int i = 0; i < 8; ++i)
#pragma unroll
                for (int j = 0; j < 8; ++j) acc[i][j] = fmaf(a[i], bb[j], acc[i][j]);
        }
    }
#pragma unroll
    for (int i = 0; i < 8; ++i) {
        int grow = i0 + ty * 8 + i;
        if (grow < 2000) {
            __hip_bfloat16* crow = hp + grow * 384 + r0 + tx * 8;
            union { ushort4 u[2]; __hip_bfloat16 h[8]; } pk;
#pragma unroll
            for (int j = 0; j < 8; ++j) pk.h[j] = __float2bfloat16(acc[i][j]);
            *(ushort4*)crow = pk.u[0];
            *(ushort4*)(crow + 4) = pk.u[1];
        }
    }
}

// gcn[b][i][f][t] = relu(sum_{k,c} h2[b][k][i][c*12+t] * Theta[k][c][f])
__global__ __launch_bounds__(256) void k_theta(const __hip_bfloat16* __restrict__ h2, const float* __restrict__ Theta,
                                               float* __restrict__ gcn) {
    int b = blockIdx.x / N_, i = blockIdx.x % N_;
    __shared__ float hs[K_ * 384];
    __shared__ float th[K_ * C_ * FC_];
    int tid = threadIdx.x;
    for (int q = tid; q < K_ * 384; q += 256) {
        int kq = q / 384, r = q % 384;
        hs[q] = __bfloat162float(h2[(b * K_ + kq) * 768000 + i * 384 + r]);
    }
    for (int q = tid; q < K_ * C_ * FC_; q += 256) th[q] = Theta[q];
    __syncthreads();
    float* gp = gcn + (b * N_ + i) * 768;
#pragma unroll
    for (int q = 0; q < 3; ++q) {
        int idx = q * 256 + tid;
        int f = idx / T_, tt = idx % T_;
        float a = 0.f;
#pragma unroll
        for (int kc = 0; kc < K_ * C_; ++kc)
            a += hs[(kc >> 5) * 384 + (kc & 31) * T_ + tt] * th[kc * FC_ + f];
        gp[idx] = fmaxf(a, 0.f);
    }
}

// time conv (1x3,pad1) + residual 1x1 conv + relu + LayerNorm over F + output (B,N,F,T)
__global__ __launch_bounds__(256) void k_final(const float* __restrict__ x, const float* __restrict__ gcn,
                                               const float* __restrict__ tc_w, const float* __restrict__ tc_b,
                                               const float* __restrict__ rc_w, const float* __restrict__ rc_b,
                                               const float* __restrict__ ln_g, const float* __restrict__ ln_b,
                                               float* __restrict__ out) {
    __shared__ float gl[4][FC_][T_];
    __shared__ float xl[4][C_][T_];
    int w = threadIdx.x >> 6, lane = threadIdx.x & 63;
    int idx = blockIdx.x * 4 + w;  // b*2000+n
    const float* gp = gcn + idx * (FC_ * T_) + lane * T_;
#pragma unroll
    for (int t = 0; t < T_; ++t) gl[w][lane][t] = gp[t];
    if (lane < C_) {
        const float* xp = x + idx * (C_ * T_) + lane * T_;
#pragma unroll
        for (int t = 0; t < T_; ++t) xl[w][lane][t] = xp[t];
    }
    __syncthreads();
    int fo = lane;
    float acc[T_];
    float bias = rc_b[fo] + tc_b[fo];
#pragma unroll
    for (int t = 0; t < T_; ++t) acc[t] = bias;
    for (int c = 0; c < C_; ++c) {
        float wr = rc_w[fo * C_ + c];
#pragma unroll
        for (int t = 0; t < T_; ++t) acc[t] = fmaf(xl[w][c][t], wr, acc[t]);
    }
    for (int fi = 0; fi < FC_; ++fi) {
        const float* tw = tc_w + (fo * FC_ + fi) * 3;
        float w0 = tw[0], w1 = tw[1], w2 = tw[2];
        float g[T_];
#pragma unroll
        for (int t = 0; t < T_; ++t) g[t] = gl[w][fi][t];
#pragma unroll
        for (int t = 0; t < T_; ++t) {
            float left = (t > 0) ? g[t - 1] : 0.f;
            float right = (t < T_ - 1) ? g[t + 1] : 0.f;
            acc[t] += left * w0 + g[t] * w1 + right * w2;
        }
    }
    float z[T_], o[T_];
#pragma unroll
    for (int t = 0; t < T_; ++t) z[t] = fmaxf(acc[t], 0.f);
    float lg = ln_g[fo], lb = ln_b[fo];
#pragma unroll
    for (int t = 0; t < T_; ++t) {
        float s = z[t], q = z[t] * z[t];
        for (int off = 32; off > 0; off >>= 1) {
            s += __shfl_xor(s, off);
            q += __shfl_xor(q, off);
        }
        float mu = s * (1.0f / 64.0f);
        float var = q * (1.0f / 64.0f) - mu * mu;
        float rs = rsqrtf(var + 1e-5f);
        o[t] = (z[t] - mu) * rs * lg + lb;
    }
    float* op = out + (idx * 64 + fo) * T_;
#pragma unroll
    for (int t = 0; t < T_; ++t) op[t] = o[t];
}

extern "C" void kernel_launch(void* const* d_in, const int* in_sizes, int n_in,
                              void* d_out, int out_size, void* d_ws, size_t ws_size,
                              hipStream_t stream) {
    const float* x     = (const float*)d_in[0];
    const float* cheb  = (const float*)d_in[1];
    const float* U1    = (const float*)d_in[2];
    const float* U2    = (const float*)d_in[3];
    const float* U3    = (const float*)d_in[4];
    const float* be    = (const float*)d_in[5];
    const float* Ve    = (const float*)d_in[6];
    const float* W1    = (const float*)d_in[7];
    const float* W2    = (const float*)d_in[8];
    const float* W3    = (const float*)d_in[9];
    const float* bs    = (const float*)d_in[10];
    const float* Vs    = (const float*)d_in[11];
    const float* Theta = (const float*)d_in[12];
    const float* tc_w  = (const float*)d_in[13];
    const float* tc_b  = (const float*)d_in[14];
    const float* rc_w  = (const float*)d_in[15];
    const float* rc_b  = (const float*)d_in[16];
    const float* ln_g  = (const float*)d_in[17];
    const float* ln_b  = (const float*)d_in[18];
    float* out = (float*)d_out;

    // ---- workspace layout (total ~105 MB) ----
    float* ws    = (float*)d_ws;
    float* At    = ws;                  // 1152
    float* lhs1  = At + 1152;           // 3072
    float* lhsT  = lhs1 + 3072;         // 192000
    float* rhsT  = lhsT + 192000;       // 192000
    float* lhs_s = rhsT + 192000;       // 192000
    float* rhs_s = lhs_s + 192000;      // 192000
    float* pm    = rhs_s + 192000;      // 131072
    float* ps    = pm + 131072;         // 131072
    float* gm    = ps + 131072;         // 16384
    float* gs    = gm + 16384;          // 16384
    float* big   = gs + 16384;          // region of 16,000,000 floats (64 MB)
    // lifetimes: xTA (dead after k_sprep) -> S bf16 (dead after k_gemm_cheb) -> gcn
    float* xTA = big;                              // 3,072,000 floats
    __hip_bfloat16* Sb = (__hip_bfloat16*)big;     // 32,000,000 bf16
    float* gcn = big;                              // 12,288,000 floats
    __hip_bfloat16* h2 = (__hip_bfloat16*)(big + 16000000);  // 18,432,000 bf16 (36.9 MB)

    k_lhs1<<<B_ * T_, 256, 0, stream>>>(x, U1, lhs1);
    k_rhs<<<(B_ * N_ * T_ + 255) / 256, 256, 0, stream>>>(x, U3, rhsT);
    k_lhsT<<<(B_ * T_ * N_ + 255) / 256, 256, 0, stream>>>(lhs1, U2, lhsT);
    k_tatt<<<B_, 256, 0, stream>>>(lhsT, rhsT, be, Ve, At);
    k_xTAt<<<2000, 256, 0, stream>>>(x, At, xTA);
    k_sprep<<<(B_ * N_ + 255) / 256, 256, 0, stream>>>(xTA, W1, W2, W3, lhs_s, rhs_s);
    k_gemm_S<<<dim3(16, 16, 8), 256, 0, stream>>>(Vs, lhs_s, rhs_s, bs, Sb);
    k_sm1<<<dim3(8, 8, 8), 256, 0, stream>>>(Sb, pm, ps);
    k_sm2<<<dim3(8, 8), 256, 0, stream>>>(pm, ps, gm, gs);
    k_sm3<<<dim3(8, 8, 8), 256, 0, stream>>>(Sb, gm, gs);
    k_gemm_cheb<<<dim3(3, 16, 24), 256, 0, stream>>>(cheb, Sb, x, h2);
    k_theta<<<B_ * N_, 256, 0, stream>>>(h2, Theta, gcn);
    k_final<<<B_ * N_ / 4, 256, 0, stream>>>(x, gcn, tc_w, tc_b, rc_w, rc_b, ln_g, ln_b, out);
}

// Round 3
// 1121.910 us; speedup vs baseline: 4.1180x; 4.1180x over previous
//
#include <hip/hip_runtime.h>
#include <hip/hip_bf16.h>
#include <math.h>

#define B_ 8
#define N_ 2000
#define C_ 32
#define T_ 12
#define K_ 3
#define FC_ 64
#define FT_ 64
#define PW 2048   // padded width (K and row pads, zero-filled)

typedef short bf16x8 __attribute__((ext_vector_type(8)));
typedef float f32x4 __attribute__((ext_vector_type(4)));

__device__ __forceinline__ float sigmoidf(float v) { return 1.0f / (1.0f + __expf(-v)); }
__device__ __forceinline__ float bf2f(unsigned short u) {
    union { unsigned int i; float f; } v; v.i = ((unsigned int)u) << 16; return v.f;
}
__device__ __forceinline__ unsigned short f2bf(float f) {
    union { __hip_bfloat16 h; unsigned short u; } v; v.h = __float2bfloat16(f); return v.u;
}

// ---------------- temporal attention ----------------
__global__ __launch_bounds__(256) void k_lhs1(const float* __restrict__ x, const float* __restrict__ U1,
                                              float* __restrict__ lhs1) {
    int b = blockIdx.x / T_, t = blockIdx.x % T_;
    int tid = threadIdx.x;
    float acc[C_];
#pragma unroll
    for (int c = 0; c < C_; ++c) acc[c] = 0.f;
    for (int n = tid; n < N_; n += 256) {
        float u = U1[n];
        const float* xp = x + ((b * N_ + n) * C_) * T_ + t;
#pragma unroll
        for (int c = 0; c < C_; ++c) acc[c] += xp[c * T_] * u;
    }
#pragma unroll
    for (int c = 0; c < C_; ++c) {
        float v = acc[c];
        for (int off = 32; off > 0; off >>= 1) v += __shfl_down(v, off);
        acc[c] = v;
    }
    __shared__ float red[4][C_];
    int w = tid >> 6, lane = tid & 63;
    if (lane == 0) {
#pragma unroll
        for (int c = 0; c < C_; ++c) red[w][c] = acc[c];
    }
    __syncthreads();
    if (tid < C_) lhs1[(b * T_ + t) * C_ + tid] = red[0][tid] + red[1][tid] + red[2][tid] + red[3][tid];
}

__global__ __launch_bounds__(256) void k_rhs(const float* __restrict__ x, const float* __restrict__ U3,
                                             float* __restrict__ rhsT) {
    int gid = blockIdx.x * 256 + threadIdx.x;
    if (gid >= B_ * N_ * T_) return;
    int t = gid % T_;
    int bn = gid / T_;
    const float* xp = x + bn * (C_ * T_) + t;
    float a = 0.f;
#pragma unroll
    for (int c = 0; c < C_; ++c) a += U3[c] * xp[c * T_];
    rhsT[gid] = a;
}

__global__ __launch_bounds__(256) void k_lhsT(const float* __restrict__ lhs1, const float* __restrict__ U2,
                                              float* __restrict__ lhsT) {
    int gid = blockIdx.x * 256 + threadIdx.x;
    if (gid >= B_ * T_ * N_) return;
    int n = gid % N_;
    int bt = gid / N_;
    const float* l1 = lhs1 + bt * C_;
    float a = 0.f;
#pragma unroll
    for (int c = 0; c < C_; ++c) a += l1[c] * U2[c * N_ + n];
    lhsT[gid] = a;
}

__global__ __launch_bounds__(256) void k_tatt(const float* __restrict__ lhsT, const float* __restrict__ rhsT,
                                              const float* __restrict__ be, const float* __restrict__ Ve,
                                              float* __restrict__ At) {
    int b = blockIdx.x;
    int tid = threadIdx.x;
    __shared__ float sL[T_][257];
    __shared__ float sR[256][T_];
    __shared__ float sp[144], sE[144], mk[12], sk[12];
    float acc = 0.f;
    int tP = tid / 12, uP = tid % 12;
    for (int n0 = 0; n0 < N_; n0 += 256) {
        int n = n0 + tid;
#pragma unroll
        for (int t = 0; t < T_; ++t) sL[t][tid] = (n < N_) ? lhsT[(b * T_ + t) * N_ + n] : 0.f;
#pragma unroll
        for (int t = 0; t < T_; ++t) sR[tid][t] = (n < N_) ? rhsT[(b * N_ + n) * T_ + t] : 0.f;
        __syncthreads();
        if (tid < 144) {
#pragma unroll 4
            for (int nn = 0; nn < 256; ++nn) acc += sL[tP][nn] * sR[nn][uP];
        }
        __syncthreads();
    }
    if (tid < 144) sp[tid] = sigmoidf(acc + be[tid]);
    __syncthreads();
    if (tid < 144) {
        float e = 0.f;
#pragma unroll
        for (int j = 0; j < T_; ++j) e += Ve[tP * T_ + j] * sp[j * T_ + uP];
        sE[tid] = e;
    }
    __syncthreads();
    if (tid < T_) {
        float m = -1e30f;
#pragma unroll
        for (int i = 0; i < T_; ++i) m = fmaxf(m, sE[i * T_ + tid]);
        float s = 0.f;
#pragma unroll
        for (int i = 0; i < T_; ++i) s += __expf(sE[i * T_ + tid] - m);
        mk[tid] = m; sk[tid] = 1.0f / s;
    }
    __syncthreads();
    if (tid < 144) At[b * 144 + tid] = __expf(sE[tid] - mk[uP]) * sk[uP];
}

__global__ __launch_bounds__(256) void k_xTAt(const float* __restrict__ x, const float* __restrict__ At,
                                              float* __restrict__ xTA) {
    int bx = blockIdx.x;
    int b = bx / 250;
    int pair = (bx % 250) * 256 + threadIdx.x;
    __shared__ float atl[144];
    if (threadIdx.x < 144) atl[threadIdx.x] = At[b * 144 + threadIdx.x];
    __syncthreads();
    const float* xp = x + (b * 64000 + pair) * T_;
    float r[T_], o[T_];
#pragma unroll
    for (int t = 0; t < T_; ++t) r[t] = xp[t];
#pragma unroll
    for (int t = 0; t < T_; ++t) {
        float a = 0.f;
#pragma unroll
        for (int u = 0; u < T_; ++u) a += r[u] * atl[u * T_ + t];
        o[t] = a;
    }
    float* op = xTA + (b * 64000 + pair) * T_;
#pragma unroll
    for (int t = 0; t < T_; ++t) op[t] = o[t];
}

// ---------------- spatial attention prep ----------------
__global__ __launch_bounds__(256) void k_sprep(const float* __restrict__ xTA, const float* __restrict__ W1,
                                               const float* __restrict__ W2, const float* __restrict__ W3,
                                               float* __restrict__ lhs_s, float* __restrict__ rhs_s) {
    int gid = blockIdx.x * 256 + threadIdx.x;
    if (gid >= B_ * N_) return;
    int b = gid / N_, n = gid % N_;
    const float* xp = xTA + gid * (C_ * T_);
    float ls[T_], rs[T_];
#pragma unroll
    for (int t = 0; t < T_; ++t) { ls[t] = 0.f; rs[t] = 0.f; }
    for (int c = 0; c < C_; ++c) {
        float row[T_];
#pragma unroll
        for (int t = 0; t < T_; ++t) row[t] = xp[c * T_ + t];
        float l1 = 0.f;
#pragma unroll
        for (int t = 0; t < T_; ++t) l1 += row[t] * W1[t];
        float w3 = W3[c];
#pragma unroll
        for (int t = 0; t < T_; ++t) { ls[t] += l1 * W2[c * T_ + t]; rs[t] += w3 * row[t]; }
    }
    float* lp = lhs_s + gid * T_;
#pragma unroll
    for (int t = 0; t < T_; ++t) lp[t] = ls[t];
#pragma unroll
    for (int t = 0; t < T_; ++t) rhs_s[(b * T_ + t) * N_ + n] = rs[t];
}

// ---------------- conversions / transposes (padded to PW, zero-filled) ----------------
// Vsb[j][p] bf16, [2048][2048]
__global__ __launch_bounds__(256) void k_vsb(const float* __restrict__ Vs, unsigned short* __restrict__ Vsb) {
    int gid = blockIdx.x * 256 + threadIdx.x;     // 2048*256 chunks of 8
    int row = gid >> 8, chunk = gid & 255;
    int p0 = chunk * 8;
    unsigned short o[8];
#pragma unroll
    for (int e = 0; e < 8; ++e) {
        int p = p0 + e;
        o[e] = (row < N_ && p < N_) ? f2bf(Vs[row * N_ + p]) : (unsigned short)0;
    }
    *(int4*)(Vsb + (size_t)row * PW + p0) = *(int4*)o;
}

// chebT[kk][i][j] = cheb[kk][j][i], bf16 [2048][2048] per kk
__global__ __launch_bounds__(256) void k_chebT(const float* __restrict__ cheb, unsigned short* __restrict__ chebT) {
    int j0 = blockIdx.x * 64, i0 = blockIdx.y * 64, kk = blockIdx.z;
    __shared__ float Tl[64][65];
    int t = threadIdx.x;
    int rr = t >> 2, c0 = (t & 3) * 16;
    int j = j0 + rr;
#pragma unroll
    for (int e = 0; e < 16; ++e) {
        int i = i0 + c0 + e;
        Tl[rr][c0 + e] = (j < N_ && i < N_) ? cheb[(size_t)kk * 4000000 + (size_t)j * N_ + i] : 0.f;
    }
    __syncthreads();
    int l = t & 63, w = t >> 6;
    unsigned short o[16];
#pragma unroll
    for (int e = 0; e < 16; ++e) o[e] = f2bf(Tl[w * 16 + e][l]);
    unsigned short* dst = chebT + (size_t)kk * PW * PW + (size_t)(i0 + l) * PW + j0 + w * 16;
    *(int4*)dst = *(int4*)o;
    *(int4*)(dst + 8) = *(int4*)(o + 8);
}

// xT[b][r][j] = x[b][j][r], bf16 [384][2048] per b
__global__ __launch_bounds__(256) void k_xT(const float* __restrict__ x, unsigned short* __restrict__ xT) {
    int j0 = blockIdx.x * 64, r0 = blockIdx.y * 64, b = blockIdx.z;
    __shared__ float Tl[64][65];
    int t = threadIdx.x;
    int rr = t >> 2, c0 = (t & 3) * 16;
    int j = j0 + rr;
#pragma unroll
    for (int e = 0; e < 16; ++e) {
        int r = r0 + c0 + e;
        Tl[rr][c0 + e] = (j < N_) ? x[(size_t)(b * N_ + j) * 384 + r] : 0.f;
    }
    __syncthreads();
    int l = t & 63, w = t >> 6;
    unsigned short o[16];
#pragma unroll
    for (int e = 0; e < 16; ++e) o[e] = f2bf(Tl[w * 16 + e][l]);
    unsigned short* dst = xT + (size_t)b * 384 * PW + (size_t)(r0 + l) * PW + j0 + w * 16;
    *(int4*)dst = *(int4*)o;
    *(int4*)(dst + 8) = *(int4*)(o + 8);
}

// sigT[b][i][p] = sigmoid(lhs_s[p].rhs_s[:,i] + bs[p][i]), bf16 [2048][2048] per b
__global__ __launch_bounds__(256) void k_sig(const float* __restrict__ lhs_s, const float* __restrict__ rhs_s,
                                             const float* __restrict__ bs, unsigned short* __restrict__ sigT) {
    int p0 = blockIdx.x * 64, i0 = blockIdx.y * 64, b = blockIdx.z;
    __shared__ float sL[64][12];
    __shared__ float sR[12][64];
    __shared__ float bsl[64][65];
    int t = threadIdx.x;
    for (int q = t; q < 768; q += 256) {
        int pp = q / 12, tt = q % 12;
        int p = p0 + pp;
        sL[pp][tt] = (p < N_) ? lhs_s[(b * N_ + p) * 12 + tt] : 0.f;
    }
    for (int q = t; q < 768; q += 256) {
        int tt = q >> 6, ii = q & 63;
        int i = i0 + ii;
        sR[tt][ii] = (i < N_) ? rhs_s[b * (T_ * N_) + tt * N_ + i] : 0.f;
    }
    {
        int pp = t >> 2, c0 = (t & 3) * 16;
        int p = p0 + pp;
        if (p < N_ && i0 + c0 + 15 < N_) {
            const float* src = bs + (size_t)p * N_ + i0 + c0;
#pragma unroll
            for (int e = 0; e < 16; e += 4) *(float4*)&bsl[pp][c0 + e] = *(const float4*)(src + e);
        } else {
#pragma unroll
            for (int e = 0; e < 16; ++e) {
                int i = i0 + c0 + e;
                bsl[pp][c0 + e] = (p < N_ && i < N_) ? bs[(size_t)p * N_ + i] : 0.f;
            }
        }
    }
    __syncthreads();
    int ii = t & 63, w = t >> 6;
    int i = i0 + ii;
    unsigned short o[16];
#pragma unroll
    for (int e = 0; e < 16; ++e) {
        int pl = w * 16 + e;
        int p = p0 + pl;
        float v = 0.f;
        if (p < N_ && i < N_) {
            float d = bsl[pl][ii];
#pragma unroll
            for (int tt = 0; tt < 12; ++tt) d += sL[pl][tt] * sR[tt][ii];
            v = sigmoidf(d);
        }
        o[e] = f2bf(v);
    }
    unsigned short* dst = sigT + (size_t)b * PW * PW + (size_t)i * PW + p0 + w * 16;
    *(int4*)dst = *(int4*)o;
    *(int4*)(dst + 8) = *(int4*)(o + 8);
}

// ---------------- MFMA GEMM: S[j][i] = sum_p Vs[j][p] * sig[p][i] ----------------
__global__ __launch_bounds__(256) void k_gemm_S_mfma(const unsigned short* __restrict__ Vsb,
                                                     const unsigned short* __restrict__ sigT,
                                                     unsigned short* __restrict__ S) {
    int b = blockIdx.z;
    int i0 = blockIdx.x * 128;   // N cols
    int j0 = blockIdx.y * 128;   // M rows
    const unsigned short* Bp = sigT + (size_t)b * PW * PW;
    __shared__ unsigned short As[128 * 40];
    __shared__ unsigned short Bs[128 * 40];
    int t = threadIdx.x;
    int lane = t & 63, w = t >> 6;
    int wr = w >> 1, wc = w & 1;
    f32x4 acc[4][4];
#pragma unroll
    for (int a = 0; a < 4; ++a)
#pragma unroll
        for (int c = 0; c < 4; ++c)
#pragma unroll
            for (int q = 0; q < 4; ++q) acc[a][c][q] = 0.f;
    int sr = t >> 1, sseg = t & 1;
    const int4* ga = (const int4*)(Vsb + (size_t)(j0 + sr) * PW);
    const int4* gb = (const int4*)(Bp + (size_t)(i0 + sr) * PW);
    for (int p = 0; p < PW; p += 32) {
        int4 a0 = ga[(p >> 3) + sseg * 2], a1 = ga[(p >> 3) + sseg * 2 + 1];
        int4 b0 = gb[(p >> 3) + sseg * 2], b1 = gb[(p >> 3) + sseg * 2 + 1];
        __syncthreads();
        *(int4*)&As[sr * 40 + sseg * 16] = a0; *(int4*)&As[sr * 40 + sseg * 16 + 8] = a1;
        *(int4*)&Bs[sr * 40 + sseg * 16] = b0; *(int4*)&Bs[sr * 40 + sseg * 16 + 8] = b1;
        __syncthreads();
        int ko = (lane >> 4) * 8;
        bf16x8 af[4], bfr[4];
#pragma unroll
        for (int f = 0; f < 4; ++f) {
            af[f] = *(const bf16x8*)&As[(wr * 64 + f * 16 + (lane & 15)) * 40 + ko];
            bfr[f] = *(const bf16x8*)&Bs[(wc * 64 + f * 16 + (lane & 15)) * 40 + ko];
        }
#pragma unroll
        for (int fm = 0; fm < 4; ++fm)
#pragma unroll
            for (int fn = 0; fn < 4; ++fn)
                acc[fm][fn] = __builtin_amdgcn_mfma_f32_16x16x32_bf16(af[fm], bfr[fn], acc[fm][fn], 0, 0, 0);
    }
    unsigned short* Sp = S + (size_t)b * 4000000;
#pragma unroll
    for (int fm = 0; fm < 4; ++fm) {
        int row0 = j0 + wr * 64 + fm * 16 + ((lane >> 4) << 2);
#pragma unroll
        for (int fn = 0; fn < 4; ++fn) {
            int col = i0 + wc * 64 + fn * 16 + (lane & 15);
            if (col >= N_) continue;
#pragma unroll
            for (int q = 0; q < 4; ++q) {
                int row = row0 + q;
                if (row < N_) Sp[(size_t)row * N_ + col] = f2bf(acc[fm][fn][q]);
            }
        }
    }
}

// ---- column softmax over rows j of S[b][j][i] (bf16) ----
__global__ __launch_bounds__(256) void k_sm1(const unsigned short* __restrict__ S, float* __restrict__ pm, float* __restrict__ ps) {
    int k = blockIdx.x * 256 + threadIdx.x;
    int is = blockIdx.y, b = blockIdx.z;
    if (k >= N_) return;
    const unsigned short* sp = S + (size_t)b * 4000000 + k;
    float m = -1e30f, s = 0.f;
    for (int i = is * 250; i < is * 250 + 250; ++i) {
        float v = bf2f(sp[(size_t)i * N_]);
        float mn = fmaxf(m, v);
        s = s * __expf(m - mn) + __expf(v - mn);
        m = mn;
    }
    int o = (b * 8 + is) * 2048 + k;
    pm[o] = m; ps[o] = s;
}

__global__ __launch_bounds__(256) void k_sm2(const float* __restrict__ pm, const float* __restrict__ ps,
                                             float* __restrict__ gm, float* __restrict__ gs) {
    int k = blockIdx.x * 256 + threadIdx.x;
    int b = blockIdx.y;
    if (k >= N_) return;
    float m = -1e30f;
#pragma unroll
    for (int is = 0; is < 8; ++is) m = fmaxf(m, pm[(b * 8 + is) * 2048 + k]);
    float s = 0.f;
#pragma unroll
    for (int is = 0; is < 8; ++is) s += ps[(b * 8 + is) * 2048 + k] * __expf(pm[(b * 8 + is) * 2048 + k] - m);
    gm[b * 2048 + k] = m;
    gs[b * 2048 + k] = 1.0f / s;
}

// normalize + transpose: SAtT[b][i][j] = softmaxed S, bf16 [2048][2048] per b (pads zero)
__global__ __launch_bounds__(256) void k_sm3T(const unsigned short* __restrict__ S,
                                              const float* __restrict__ gm, const float* __restrict__ gs,
                                              unsigned short* __restrict__ SAtT) {
    int j0 = blockIdx.x * 64, i0 = blockIdx.y * 64, b = blockIdx.z;
    __shared__ float Tl[64][65];
    int t = threadIdx.x;
    int rr = t >> 2, c0 = (t & 3) * 16;
    int j = j0 + rr;
#pragma unroll
    for (int e = 0; e < 16; ++e) {
        int i = i0 + c0 + e;
        float v = 0.f;
        if (j < N_ && i < N_) {
            float sv = bf2f(S[(size_t)b * 4000000 + (size_t)j * N_ + i]);
            v = __expf(sv - gm[b * 2048 + i]) * gs[b * 2048 + i];
        }
        Tl[rr][c0 + e] = v;
    }
    __syncthreads();
    int l = t & 63, w = t >> 6;
    unsigned short o[16];
#pragma unroll
    for (int e = 0; e < 16; ++e) o[e] = f2bf(Tl[w * 16 + e][l]);
    unsigned short* dst = SAtT + (size_t)b * PW * PW + (size_t)(i0 + l) * PW + j0 + w * 16;
    *(int4*)dst = *(int4*)o;
    *(int4*)(dst + 8) = *(int4*)(o + 8);
}

// ---------------- MFMA GEMM: h2[i][r] = sum_j (chebT*SAtT)[i][j] * xT[r][j] ----------------
__global__ __launch_bounds__(256) void k_gemm_cheb_mfma(const unsigned short* __restrict__ chebT,
                                                        const unsigned short* __restrict__ SAtT,
                                                        const unsigned short* __restrict__ xT,
                                                        unsigned short* __restrict__ h2) {
    int bk = blockIdx.z;
    int b = bk / 3, kk = bk % 3;
    int i0 = blockIdx.y * 128;   // M
    int r0 = blockIdx.x * 128;   // N
    const unsigned short* Ac = chebT + (size_t)kk * PW * PW;
    const unsigned short* As_ = SAtT + (size_t)b * PW * PW;
    const unsigned short* Bx = xT + (size_t)b * 384 * PW;
    __shared__ unsigned short As[128 * 40];
    __shared__ unsigned short Bs[128 * 40];
    int t = threadIdx.x;
    int lane = t & 63, w = t >> 6;
    int wr = w >> 1, wc = w & 1;
    f32x4 acc[4][4];
#pragma unroll
    for (int a = 0; a < 4; ++a)
#pragma unroll
        for (int c = 0; c < 4; ++c)
#pragma unroll
            for (int q = 0; q < 4; ++q) acc[a][c][q] = 0.f;
    int sr = t >> 1, sseg = t & 1;
    const int4* gc = (const int4*)(Ac + (size_t)(i0 + sr) * PW);
    const int4* gsat = (const int4*)(As_ + (size_t)(i0 + sr) * PW);
    const int4* gb = (const int4*)(Bx + (size_t)(r0 + sr) * PW);
    union U8 { int4 v; unsigned short s[8]; };
    for (int p = 0; p < PW; p += 32) {
        U8 c0, c1, s0, s1;
        c0.v = gc[(p >> 3) + sseg * 2]; c1.v = gc[(p >> 3) + sseg * 2 + 1];
        s0.v = gsat[(p >> 3) + sseg * 2]; s1.v = gsat[(p >> 3) + sseg * 2 + 1];
        int4 b0 = gb[(p >> 3) + sseg * 2], b1 = gb[(p >> 3) + sseg * 2 + 1];
        U8 o0, o1;
#pragma unroll
        for (int e = 0; e < 8; ++e) {
            o0.s[e] = f2bf(bf2f(c0.s[e]) * bf2f(s0.s[e]));
            o1.s[e] = f2bf(bf2f(c1.s[e]) * bf2f(s1.s[e]));
        }
        __syncthreads();
        *(int4*)&As[sr * 40 + sseg * 16] = o0.v; *(int4*)&As[sr * 40 + sseg * 16 + 8] = o1.v;
        *(int4*)&Bs[sr * 40 + sseg * 16] = b0;   *(int4*)&Bs[sr * 40 + sseg * 16 + 8] = b1;
        __syncthreads();
        int ko = (lane >> 4) * 8;
        bf16x8 af[4], bfr[4];
#pragma unroll
        for (int f = 0; f < 4; ++f) {
            af[f] = *(const bf16x8*)&As[(wr * 64 + f * 16 + (lane & 15)) * 40 + ko];
            bfr[f] = *(const bf16x8*)&Bs[(wc * 64 + f * 16 + (lane & 15)) * 40 + ko];
        }
#pragma unroll
        for (int fm = 0; fm < 4; ++fm)
#pragma unroll
            for (int fn = 0; fn < 4; ++fn)
                acc[fm][fn] = __builtin_amdgcn_mfma_f32_16x16x32_bf16(af[fm], bfr[fn], acc[fm][fn], 0, 0, 0);
    }
    unsigned short* hp = h2 + (size_t)bk * 768000;
#pragma unroll
    for (int fm = 0; fm < 4; ++fm) {
        int row0 = i0 + wr * 64 + fm * 16 + ((lane >> 4) << 2);
#pragma unroll
        for (int fn = 0; fn < 4; ++fn) {
            int col = r0 + wc * 64 + fn * 16 + (lane & 15);
#pragma unroll
            for (int q = 0; q < 4; ++q) {
                int row = row0 + q;
                if (row < N_) hp[(size_t)row * 384 + col] = f2bf(acc[fm][fn][q]);
            }
        }
    }
}

// ---------------- fused Theta-mix + time conv + residual + relu + LayerNorm ----------------
__global__ __launch_bounds__(256) void k_final2(const float* __restrict__ x, const unsigned short* __restrict__ h2,
                                                const float* __restrict__ Theta,
                                                const float* __restrict__ tc_w, const float* __restrict__ tc_b,
                                                const float* __restrict__ rc_w, const float* __restrict__ rc_b,
                                                const float* __restrict__ ln_g, const float* __restrict__ ln_b,
                                                float* __restrict__ out) {
    __shared__ float th[6144];        // Theta [3][32][64]
    __shared__ float hl[4][3][384];
    __shared__ float gl[4][FC_][T_];
    __shared__ float xl[4][C_][T_];
    int t = threadIdx.x;
    int idx0 = blockIdx.x * 4;
    int b = idx0 / N_;
    for (int q = t; q < 6144; q += 256) th[q] = Theta[q];
    for (int q = t; q < 4608; q += 256) {
        int node = q / 1152, rem = q % 1152;
        int kk = rem / 384, r = rem % 384;
        int n = (idx0 + node) % N_;
        hl[node][kk][r] = bf2f(h2[(size_t)(b * 3 + kk) * 768000 + (size_t)n * 384 + r]);
    }
    for (int q = t; q < 1536; q += 256) {
        int node = q / 384, rem = q % 384;
        xl[node][rem / 12][rem % 12] = x[(size_t)(idx0 + node) * 384 + rem];
    }
    __syncthreads();
    int w = t >> 6, lane = t & 63;
    float g[T_];
#pragma unroll
    for (int tt = 0; tt < T_; ++tt) g[tt] = 0.f;
    for (int kk = 0; kk < 3; ++kk)
        for (int c = 0; c < 32; ++c) {
            float wv = th[kk * 2048 + c * 64 + lane];
            const float* hp = &hl[w][kk][c * 12];
#pragma unroll
            for (int tt = 0; tt < T_; ++tt) g[tt] += hp[tt] * wv;
        }
#pragma unroll
    for (int tt = 0; tt < T_; ++tt) gl[w][lane][tt] = fmaxf(g[tt], 0.f);
    __syncthreads();
    int fo = lane;
    float acc[T_];
    float bias = rc_b[fo] + tc_b[fo];
#pragma unroll
    for (int tt = 0; tt < T_; ++tt) acc[tt] = bias;
    for (int c = 0; c < C_; ++c) {
        float wr_ = rc_w[fo * C_ + c];
#pragma unroll
        for (int tt = 0; tt < T_; ++tt) acc[tt] = fmaf(xl[w][c][tt], wr_, acc[tt]);
    }
    for (int fi = 0; fi < FC_; ++fi) {
        const float* tw = tc_w + (fo * FC_ + fi) * 3;
        float w0 = tw[0], w1 = tw[1], w2 = tw[2];
        float gg[T_];
#pragma unroll
        for (int tt = 0; tt < T_; ++tt) gg[tt] = gl[w][fi][tt];
#pragma unroll
        for (int tt = 0; tt < T_; ++tt) {
            float left = (tt > 0) ? gg[tt - 1] : 0.f;
            float right = (tt < T_ - 1) ? gg[tt + 1] : 0.f;
            acc[tt] += left * w0 + gg[tt] * w1 + right * w2;
        }
    }
    float z[T_], o[T_];
#pragma unroll
    for (int tt = 0; tt < T_; ++tt) z[tt] = fmaxf(acc[tt], 0.f);
    float lg = ln_g[fo], lb = ln_b[fo];
#pragma unroll
    for (int tt = 0; tt < T_; ++tt) {
        float s = z[tt], q = z[tt] * z[tt];
        for (int off = 32; off > 0; off >>= 1) {
            s += __shfl_xor(s, off);
            q += __shfl_xor(q, off);
        }
        float mu = s * (1.0f / 64.0f);
        float var = q * (1.0f / 64.0f) - mu * mu;
        float rs = rsqrtf(var + 1e-5f);
        o[tt] = (z[tt] - mu) * rs * lg + lb;
    }
    float* op = out + ((size_t)(idx0 + w) * 64 + fo) * T_;
#pragma unroll
    for (int tt = 0; tt < T_; ++tt) op[tt] = o[tt];
}

extern "C" void kernel_launch(void* const* d_in, const int* in_sizes, int n_in,
                              void* d_out, int out_size, void* d_ws, size_t ws_size,
                              hipStream_t stream) {
    const float* x     = (const float*)d_in[0];
    const float* cheb  = (const float*)d_in[1];
    const float* U1    = (const float*)d_in[2];
    const float* U2    = (const float*)d_in[3];
    const float* U3    = (const float*)d_in[4];
    const float* be    = (const float*)d_in[5];
    const float* Ve    = (const float*)d_in[6];
    const float* W1    = (const float*)d_in[7];
    const float* W2    = (const float*)d_in[8];
    const float* W3    = (const float*)d_in[9];
    const float* bs    = (const float*)d_in[10];
    const float* Vs    = (const float*)d_in[11];
    const float* Theta = (const float*)d_in[12];
    const float* tc_w  = (const float*)d_in[13];
    const float* tc_b  = (const float*)d_in[14];
    const float* rc_w  = (const float*)d_in[15];
    const float* rc_b  = (const float*)d_in[16];
    const float* ln_g  = (const float*)d_in[17];
    const float* ln_b  = (const float*)d_in[18];
    float* out = (float*)d_out;

    // ---- workspace layout (~181.5 MB) ----
    float* ws    = (float*)d_ws;
    float* At    = ws;                       // 1152
    float* lhs1  = ws + 1152;                // 3072
    float* lhsT  = ws + 4224;                // 192000
    float* rhsT  = ws + 196224;              // 192000
    float* lhs_s = ws + 388224;              // 192000
    float* rhs_s = ws + 580224;              // 192000
    float* pm    = ws + 772224;              // 131072
    float* ps    = ws + 903296;              // 131072
    float* gm    = ws + 1034368;             // 16384
    float* gs    = ws + 1050752;             // 16384
    unsigned short* Vsb   = (unsigned short*)(ws + 1067136);   // 2048*2048 bf16
    unsigned short* chebT = (unsigned short*)(ws + 3164288);   // 3 * 2048*2048 bf16
    unsigned short* xT    = (unsigned short*)(ws + 9455744);   // 8 * 384*2048 bf16
    unsigned short* sigT  = (unsigned short*)(ws + 12601472);  // 8 * 2048*2048 bf16 (region2)
    unsigned short* SAtT  = sigT;                              // reuse after gemm_S
    float* region1 = ws + 29378688;                            // 16,000,000 floats
    float* xTA = region1;                                      // 3,072,000 f32
    unsigned short* Sb = (unsigned short*)region1;             // 8 * 2000*2000 bf16
    unsigned short* h2 = (unsigned short*)region1;             // 24 * 2000*384 bf16

    // prep / temporal attention
    k_vsb<<<2048, 256, 0, stream>>>(Vs, Vsb);
    k_chebT<<<dim3(32, 32, 3), 256, 0, stream>>>(cheb, chebT);
    k_xT<<<dim3(32, 6, 8), 256, 0, stream>>>(x, xT);
    k_lhs1<<<B_ * T_, 256, 0, stream>>>(x, U1, lhs1);
    k_rhs<<<(B_ * N_ * T_ + 255) / 256, 256, 0, stream>>>(x, U3, rhsT);
    k_lhsT<<<(B_ * T_ * N_ + 255) / 256, 256, 0, stream>>>(lhs1, U2, lhsT);
    k_tatt<<<B_, 256, 0, stream>>>(lhsT, rhsT, be, Ve, At);
    k_xTAt<<<2000, 256, 0, stream>>>(x, At, xTA);
    k_sprep<<<(B_ * N_ + 255) / 256, 256, 0, stream>>>(xTA, W1, W2, W3, lhs_s, rhs_s);
    // spatial attention
    k_sig<<<dim3(32, 32, 8), 256, 0, stream>>>(lhs_s, rhs_s, bs, sigT);
    k_gemm_S_mfma<<<dim3(16, 16, 8), 256, 0, stream>>>(Vsb, sigT, Sb);
    k_sm1<<<dim3(8, 8, 8), 256, 0, stream>>>(Sb, pm, ps);
    k_sm2<<<dim3(8, 8), 256, 0, stream>>>(pm, ps, gm, gs);
    k_sm3T<<<dim3(32, 32, 8), 256, 0, stream>>>(Sb, gm, gs, SAtT);
    // chebyshev gcn
    k_gemm_cheb_mfma<<<dim3(3, 16, 24), 256, 0, stream>>>(chebT, SAtT, xT, h2);
    // fused theta + conv + LN
    k_final2<<<B_ * N_ / 4, 256, 0, stream>>>(x, h2, Theta, tc_w, tc_b, rc_w, rc_b, ln_g, ln_b, out);
}

// Round 5
// 908.850 us; speedup vs baseline: 5.0834x; 1.2344x over previous
//
#include <hip/hip_runtime.h>
#include <hip/hip_bf16.h>
#include <math.h>

#define B_ 8
#define N_ 2000
#define C_ 32
#define T_ 12
#define K_ 3
#define FC_ 64
#define FT_ 64
#define PW 2048   // padded width (K and row pads, zero-filled)

typedef short bf16x8 __attribute__((ext_vector_type(8)));
typedef float f32x4 __attribute__((ext_vector_type(4)));

__device__ __forceinline__ float sigmoidf(float v) { return 1.0f / (1.0f + __expf(-v)); }
__device__ __forceinline__ float bf2f(unsigned short u) {
    union { unsigned int i; float f; } v; v.i = ((unsigned int)u) << 16; return v.f;
}
__device__ __forceinline__ unsigned short f2bf(float f) {
    union { __hip_bfloat16 h; unsigned short u; } v; v.h = __float2bfloat16(f); return v.u;
}

// ---------------- temporal attention ----------------
__global__ __launch_bounds__(256) void k_lhs1(const float* __restrict__ x, const float* __restrict__ U1,
                                              float* __restrict__ lhs1) {
    int b = blockIdx.x / T_, t = blockIdx.x % T_;
    int tid = threadIdx.x;
    float acc[C_];
#pragma unroll
    for (int c = 0; c < C_; ++c) acc[c] = 0.f;
    for (int n = tid; n < N_; n += 256) {
        float u = U1[n];
        const float* xp = x + ((b * N_ + n) * C_) * T_ + t;
#pragma unroll
        for (int c = 0; c < C_; ++c) acc[c] += xp[c * T_] * u;
    }
#pragma unroll
    for (int c = 0; c < C_; ++c) {
        float v = acc[c];
        for (int off = 32; off > 0; off >>= 1) v += __shfl_down(v, off);
        acc[c] = v;
    }
    __shared__ float red[4][C_];
    int w = tid >> 6, lane = tid & 63;
    if (lane == 0) {
#pragma unroll
        for (int c = 0; c < C_; ++c) red[w][c] = acc[c];
    }
    __syncthreads();
    if (tid < C_) lhs1[(b * T_ + t) * C_ + tid] = red[0][tid] + red[1][tid] + red[2][tid] + red[3][tid];
}

__global__ __launch_bounds__(256) void k_rhs(const float* __restrict__ x, const float* __restrict__ U3,
                                             float* __restrict__ rhsT) {
    int gid = blockIdx.x * 256 + threadIdx.x;
    if (gid >= B_ * N_ * T_) return;
    int t = gid % T_;
    int bn = gid / T_;
    const float* xp = x + bn * (C_ * T_) + t;
    float a = 0.f;
#pragma unroll
    for (int c = 0; c < C_; ++c) a += U3[c] * xp[c * T_];
    rhsT[gid] = a;
}

__global__ __launch_bounds__(256) void k_lhsT(const float* __restrict__ lhs1, const float* __restrict__ U2,
                                              float* __restrict__ lhsT) {
    int gid = blockIdx.x * 256 + threadIdx.x;
    if (gid >= B_ * T_ * N_) return;
    int n = gid % N_;
    int bt = gid / N_;
    const float* l1 = lhs1 + bt * C_;
    float a = 0.f;
#pragma unroll
    for (int c = 0; c < C_; ++c) a += l1[c] * U2[c * N_ + n];
    lhsT[gid] = a;
}

__global__ __launch_bounds__(256) void k_tatt(const float* __restrict__ lhsT, const float* __restrict__ rhsT,
                                              const float* __restrict__ be, const float* __restrict__ Ve,
                                              float* __restrict__ At) {
    int b = blockIdx.x;
    int tid = threadIdx.x;
    __shared__ float sL[T_][257];
    __shared__ float sR[256][T_];
    __shared__ float sp[144], sE[144], mk[12], sk[12];
    float acc = 0.f;
    int tP = tid / 12, uP = tid % 12;
    for (int n0 = 0; n0 < N_; n0 += 256) {
        int n = n0 + tid;
#pragma unroll
        for (int t = 0; t < T_; ++t) sL[t][tid] = (n < N_) ? lhsT[(b * T_ + t) * N_ + n] : 0.f;
#pragma unroll
        for (int t = 0; t < T_; ++t) sR[tid][t] = (n < N_) ? rhsT[(b * N_ + n) * T_ + t] : 0.f;
        __syncthreads();
        if (tid < 144) {
#pragma unroll 4
            for (int nn = 0; nn < 256; ++nn) acc += sL[tP][nn] * sR[nn][uP];
        }
        __syncthreads();
    }
    if (tid < 144) sp[tid] = sigmoidf(acc + be[tid]);
    __syncthreads();
    if (tid < 144) {
        float e = 0.f;
#pragma unroll
        for (int j = 0; j < T_; ++j) e += Ve[tP * T_ + j] * sp[j * T_ + uP];
        sE[tid] = e;
    }
    __syncthreads();
    if (tid < T_) {
        float m = -1e30f;
#pragma unroll
        for (int i = 0; i < T_; ++i) m = fmaxf(m, sE[i * T_ + tid]);
        float s = 0.f;
#pragma unroll
        for (int i = 0; i < T_; ++i) s += __expf(sE[i * T_ + tid] - m);
        mk[tid] = m; sk[tid] = 1.0f / s;
    }
    __syncthreads();
    if (tid < 144) At[b * 144 + tid] = __expf(sE[tid] - mk[uP]) * sk[uP];
}

__global__ __launch_bounds__(256) void k_xTAt(const float* __restrict__ x, const float* __restrict__ At,
                                              float* __restrict__ xTA) {
    int bx = blockIdx.x;
    int b = bx / 250;
    int pair = (bx % 250) * 256 + threadIdx.x;
    __shared__ float atl[144];
    if (threadIdx.x < 144) atl[threadIdx.x] = At[b * 144 + threadIdx.x];
    __syncthreads();
    const float* xp = x + (b * 64000 + pair) * T_;
    float r[T_], o[T_];
#pragma unroll
    for (int t = 0; t < T_; ++t) r[t] = xp[t];
#pragma unroll
    for (int t = 0; t < T_; ++t) {
        float a = 0.f;
#pragma unroll
        for (int u = 0; u < T_; ++u) a += r[u] * atl[u * T_ + t];
        o[t] = a;
    }
    float* op = xTA + (b * 64000 + pair) * T_;
#pragma unroll
    for (int t = 0; t < T_; ++t) op[t] = o[t];
}

// ---------------- spatial attention prep ----------------
__global__ __launch_bounds__(256) void k_sprep(const float* __restrict__ xTA, const float* __restrict__ W1,
                                               const float* __restrict__ W2, const float* __restrict__ W3,
                                               float* __restrict__ lhs_s, float* __restrict__ rhs_s) {
    int gid = blockIdx.x * 256 + threadIdx.x;
    if (gid >= B_ * N_) return;
    int b = gid / N_, n = gid % N_;
    const float* xp = xTA + gid * (C_ * T_);
    float ls[T_], rs[T_];
#pragma unroll
    for (int t = 0; t < T_; ++t) { ls[t] = 0.f; rs[t] = 0.f; }
    for (int c = 0; c < C_; ++c) {
        float row[T_];
#pragma unroll
        for (int t = 0; t < T_; ++t) row[t] = xp[c * T_ + t];
        float l1 = 0.f;
#pragma unroll
        for (int t = 0; t < T_; ++t) l1 += row[t] * W1[t];
        float w3 = W3[c];
#pragma unroll
        for (int t = 0; t < T_; ++t) { ls[t] += l1 * W2[c * T_ + t]; rs[t] += w3 * row[t]; }
    }
    float* lp = lhs_s + gid * T_;
#pragma unroll
    for (int t = 0; t < T_; ++t) lp[t] = ls[t];
#pragma unroll
    for (int t = 0; t < T_; ++t) rhs_s[(b * T_ + t) * N_ + n] = rs[t];
}

// ---------------- weight transposes: tcwT[fi][f][3], rcwT[c][f] ----------------
__global__ __launch_bounds__(256) void k_wprep(const float* __restrict__ tc_w, const float* __restrict__ rc_w,
                                               float* __restrict__ tcwT, float* __restrict__ rcwT) {
    int gid = blockIdx.x * 256 + threadIdx.x;
    if (gid < 12288) {
        int fi = gid / 192, rem = gid % 192, f = rem / 3, d = rem % 3;
        tcwT[gid] = tc_w[(f * 64 + fi) * 3 + d];
    } else if (gid < 14336) {
        int q = gid - 12288;
        int c = q >> 6, f = q & 63;
        rcwT[q] = rc_w[f * 32 + c];
    }
}

// ---------------- conversions / transposes (padded to PW, zero-filled) ----------------
__global__ __launch_bounds__(256) void k_vsb(const float* __restrict__ Vs, unsigned short* __restrict__ Vsb) {
    int gid = blockIdx.x * 256 + threadIdx.x;
    int row = gid >> 8, chunk = gid & 255;
    int p0 = chunk * 8;
    unsigned short o[8];
#pragma unroll
    for (int e = 0; e < 8; ++e) {
        int p = p0 + e;
        o[e] = (row < N_ && p < N_) ? f2bf(Vs[row * N_ + p]) : (unsigned short)0;
    }
    *(int4*)(Vsb + (size_t)row * PW + p0) = *(int4*)o;
}

__global__ __launch_bounds__(256) void k_chebT(const float* __restrict__ cheb, unsigned short* __restrict__ chebT) {
    int j0 = blockIdx.x * 64, i0 = blockIdx.y * 64, kk = blockIdx.z;
    __shared__ float Tl[64][65];
    int t = threadIdx.x;
    int rr = t >> 2, c0 = (t & 3) * 16;
    int j = j0 + rr;
#pragma unroll
    for (int e = 0; e < 16; ++e) {
        int i = i0 + c0 + e;
        Tl[rr][c0 + e] = (j < N_ && i < N_) ? cheb[(size_t)kk * 4000000 + (size_t)j * N_ + i] : 0.f;
    }
    __syncthreads();
    int l = t & 63, w = t >> 6;
    unsigned short o[16];
#pragma unroll
    for (int e = 0; e < 16; ++e) o[e] = f2bf(Tl[w * 16 + e][l]);
    unsigned short* dst = chebT + (size_t)kk * PW * PW + (size_t)(i0 + l) * PW + j0 + w * 16;
    *(int4*)dst = *(int4*)o;
    *(int4*)(dst + 8) = *(int4*)(o + 8);
}

__global__ __launch_bounds__(256) void k_xT(const float* __restrict__ x, unsigned short* __restrict__ xT) {
    int j0 = blockIdx.x * 64, r0 = blockIdx.y * 64, b = blockIdx.z;
    __shared__ float Tl[64][65];
    int t = threadIdx.x;
    int rr = t >> 2, c0 = (t & 3) * 16;
    int j = j0 + rr;
#pragma unroll
    for (int e = 0; e < 16; ++e) {
        int r = r0 + c0 + e;
        Tl[rr][c0 + e] = (j < N_) ? x[(size_t)(b * N_ + j) * 384 + r] : 0.f;
    }
    __syncthreads();
    int l = t & 63, w = t >> 6;
    unsigned short o[16];
#pragma unroll
    for (int e = 0; e < 16; ++e) o[e] = f2bf(Tl[w * 16 + e][l]);
    unsigned short* dst = xT + (size_t)b * 384 * PW + (size_t)(r0 + l) * PW + j0 + w * 16;
    *(int4*)dst = *(int4*)o;
    *(int4*)(dst + 8) = *(int4*)(o + 8);
}

__global__ __launch_bounds__(256) void k_sig(const float* __restrict__ lhs_s, const float* __restrict__ rhs_s,
                                             const float* __restrict__ bs, unsigned short* __restrict__ sigT) {
    int p0 = blockIdx.x * 64, i0 = blockIdx.y * 64, b = blockIdx.z;
    __shared__ float sL[64][12];
    __shared__ float sR[12][64];
    __shared__ float bsl[64][65];
    int t = threadIdx.x;
    for (int q = t; q < 768; q += 256) {
        int pp = q / 12, tt = q % 12;
        int p = p0 + pp;
        sL[pp][tt] = (p < N_) ? lhs_s[(b * N_ + p) * 12 + tt] : 0.f;
    }
    for (int q = t; q < 768; q += 256) {
        int tt = q >> 6, ii = q & 63;
        int i = i0 + ii;
        sR[tt][ii] = (i < N_) ? rhs_s[b * (T_ * N_) + tt * N_ + i] : 0.f;
    }
    {
        int pp = t >> 2, c0 = (t & 3) * 16;
        int p = p0 + pp;
        if (p < N_ && i0 + c0 + 15 < N_) {
            const float* src = bs + (size_t)p * N_ + i0 + c0;
#pragma unroll
            for (int e = 0; e < 16; e += 4) *(float4*)&bsl[pp][c0 + e] = *(const float4*)(src + e);
        } else {
#pragma unroll
            for (int e = 0; e < 16; ++e) {
                int i = i0 + c0 + e;
                bsl[pp][c0 + e] = (p < N_ && i < N_) ? bs[(size_t)p * N_ + i] : 0.f;
            }
        }
    }
    __syncthreads();
    int ii = t & 63, w = t >> 6;
    int i = i0 + ii;
    unsigned short o[16];
#pragma unroll
    for (int e = 0; e < 16; ++e) {
        int pl = w * 16 + e;
        int p = p0 + pl;
        float v = 0.f;
        if (p < N_ && i < N_) {
            float d = bsl[pl][ii];
#pragma unroll
            for (int tt = 0; tt < 12; ++tt) d += sL[pl][tt] * sR[tt][ii];
            v = sigmoidf(d);
        }
        o[e] = f2bf(v);
    }
    unsigned short* dst = sigT + (size_t)b * PW * PW + (size_t)i * PW + p0 + w * 16;
    *(int4*)dst = *(int4*)o;
    *(int4*)(dst + 8) = *(int4*)(o + 8);
}

// ---------------- MFMA GEMM: S[j][i] = sum_p Vs[j][p] * sig[p][i] ----------------
__global__ __launch_bounds__(256) void k_gemm_S_mfma(const unsigned short* __restrict__ Vsb,
                                                     const unsigned short* __restrict__ sigT,
                                                     unsigned short* __restrict__ S) {
    int b = blockIdx.z;
    int i0 = blockIdx.x * 128;
    int j0 = blockIdx.y * 128;
    const unsigned short* Bp = sigT + (size_t)b * PW * PW;
    __shared__ unsigned short As[128 * 40];
    __shared__ unsigned short Bs[128 * 40];
    int t = threadIdx.x;
    int lane = t & 63, w = t >> 6;
    int wr = w >> 1, wc = w & 1;
    f32x4 acc[4][4];
#pragma unroll
    for (int a = 0; a < 4; ++a)
#pragma unroll
        for (int c = 0; c < 4; ++c)
#pragma unroll
            for (int q = 0; q < 4; ++q) acc[a][c][q] = 0.f;
    int sr = t >> 1, sseg = t & 1;
    const int4* ga = (const int4*)(Vsb + (size_t)(j0 + sr) * PW);
    const int4* gb = (const int4*)(Bp + (size_t)(i0 + sr) * PW);
    // prologue prefetch
    int4 a0 = ga[sseg * 2], a1 = ga[sseg * 2 + 1];
    int4 b0 = gb[sseg * 2], b1 = gb[sseg * 2 + 1];
    for (int p = 0; p < PW; p += 32) {
        __syncthreads();
        *(int4*)&As[sr * 40 + sseg * 16] = a0; *(int4*)&As[sr * 40 + sseg * 16 + 8] = a1;
        *(int4*)&Bs[sr * 40 + sseg * 16] = b0; *(int4*)&Bs[sr * 40 + sseg * 16 + 8] = b1;
        __syncthreads();
        if (p + 32 < PW) {
            int o = ((p + 32) >> 3) + sseg * 2;
            a0 = ga[o]; a1 = ga[o + 1]; b0 = gb[o]; b1 = gb[o + 1];
        }
        int ko = (lane >> 4) * 8;
        bf16x8 af[4], bfr[4];
#pragma unroll
        for (int f = 0; f < 4; ++f) {
            af[f] = *(const bf16x8*)&As[(wr * 64 + f * 16 + (lane & 15)) * 40 + ko];
            bfr[f] = *(const bf16x8*)&Bs[(wc * 64 + f * 16 + (lane & 15)) * 40 + ko];
        }
#pragma unroll
        for (int fm = 0; fm < 4; ++fm)
#pragma unroll
            for (int fn = 0; fn < 4; ++fn)
                acc[fm][fn] = __builtin_amdgcn_mfma_f32_16x16x32_bf16(af[fm], bfr[fn], acc[fm][fn], 0, 0, 0);
    }
    unsigned short* Sp = S + (size_t)b * 4000000;
#pragma unroll
    for (int fm = 0; fm < 4; ++fm) {
        int row0 = j0 + wr * 64 + fm * 16 + ((lane >> 4) << 2);
#pragma unroll
        for (int fn = 0; fn < 4; ++fn) {
            int col = i0 + wc * 64 + fn * 16 + (lane & 15);
            if (col >= N_) continue;
#pragma unroll
            for (int q = 0; q < 4; ++q) {
                int row = row0 + q;
                if (row < N_) Sp[(size_t)row * N_ + col] = f2bf(acc[fm][fn][q]);
            }
        }
    }
}

// ---- column softmax over rows j of S[b][j][i] (bf16) ----
__global__ __launch_bounds__(256) void k_sm1(const unsigned short* __restrict__ S, float* __restrict__ pm, float* __restrict__ ps) {
    int k = blockIdx.x * 256 + threadIdx.x;
    int is = blockIdx.y, b = blockIdx.z;
    if (k >= N_) return;
    const unsigned short* sp = S + (size_t)b * 4000000 + k;
    float m = -1e30f, s = 0.f;
    for (int i = is * 250; i < is * 250 + 250; ++i) {
        float v = bf2f(sp[(size_t)i * N_]);
        float mn = fmaxf(m, v);
        s = s * __expf(m - mn) + __expf(v - mn);
        m = mn;
    }
    int o = (b * 8 + is) * 2048 + k;
    pm[o] = m; ps[o] = s;
}

__global__ __launch_bounds__(256) void k_sm2(const float* __restrict__ pm, const float* __restrict__ ps,
                                             float* __restrict__ gm, float* __restrict__ gs) {
    int k = blockIdx.x * 256 + threadIdx.x;
    int b = blockIdx.y;
    if (k >= N_) return;
    float m = -1e30f;
#pragma unroll
    for (int is = 0; is < 8; ++is) m = fmaxf(m, pm[(b * 8 + is) * 2048 + k]);
    float s = 0.f;
#pragma unroll
    for (int is = 0; is < 8; ++is) s += ps[(b * 8 + is) * 2048 + k] * __expf(pm[(b * 8 + is) * 2048 + k] - m);
    gm[b * 2048 + k] = m;
    gs[b * 2048 + k] = 1.0f / s;
}

__global__ __launch_bounds__(256) void k_sm3T(const unsigned short* __restrict__ S,
                                              const float* __restrict__ gm, const float* __restrict__ gs,
                                              unsigned short* __restrict__ SAtT) {
    int j0 = blockIdx.x * 64, i0 = blockIdx.y * 64, b = blockIdx.z;
    __shared__ float Tl[64][65];
    int t = threadIdx.x;
    int rr = t >> 2, c0 = (t & 3) * 16;
    int j = j0 + rr;
#pragma unroll
    for (int e = 0; e < 16; ++e) {
        int i = i0 + c0 + e;
        float v = 0.f;
        if (j < N_ && i < N_) {
            float sv = bf2f(S[(size_t)b * 4000000 + (size_t)j * N_ + i]);
            v = __expf(sv - gm[b * 2048 + i]) * gs[b * 2048 + i];
        }
        Tl[rr][c0 + e] = v;
    }
    __syncthreads();
    int l = t & 63, w = t >> 6;
    unsigned short o[16];
#pragma unroll
    for (int e = 0; e < 16; ++e) o[e] = f2bf(Tl[w * 16 + e][l]);
    unsigned short* dst = SAtT + (size_t)b * PW * PW + (size_t)(i0 + l) * PW + j0 + w * 16;
    *(int4*)dst = *(int4*)o;
    *(int4*)(dst + 8) = *(int4*)(o + 8);
}

// ---------------- MFMA GEMM: h2[i][r] = sum_j (chebT*SAtT)[i][j] * xT[r][j] ----------------
__global__ __launch_bounds__(256) void k_gemm_cheb_mfma(const unsigned short* __restrict__ chebT,
                                                        const unsigned short* __restrict__ SAtT,
                                                        const unsigned short* __restrict__ xT,
                                                        unsigned short* __restrict__ h2) {
    int bk = blockIdx.z;
    int b = bk / 3, kk = bk % 3;
    int i0 = blockIdx.y * 128;
    int r0 = blockIdx.x * 128;
    const unsigned short* Ac = chebT + (size_t)kk * PW * PW;
    const unsigned short* As_ = SAtT + (size_t)b * PW * PW;
    const unsigned short* Bx = xT + (size_t)b * 384 * PW;
    __shared__ unsigned short As[128 * 40];
    __shared__ unsigned short Bs[128 * 40];
    int t = threadIdx.x;
    int lane = t & 63, w = t >> 6;
    int wr = w >> 1, wc = w & 1;
    f32x4 acc[4][4];
#pragma unroll
    for (int a = 0; a < 4; ++a)
#pragma unroll
        for (int c = 0; c < 4; ++c)
#pragma unroll
            for (int q = 0; q < 4; ++q) acc[a][c][q] = 0.f;
    int sr = t >> 1, sseg = t & 1;
    const int4* gc = (const int4*)(Ac + (size_t)(i0 + sr) * PW);
    const int4* gsat = (const int4*)(As_ + (size_t)(i0 + sr) * PW);
    const int4* gb = (const int4*)(Bx + (size_t)(r0 + sr) * PW);
    union U8 { int4 v; unsigned short s[8]; };
    // prologue prefetch
    U8 c0r, c1r, s0r, s1r;
    c0r.v = gc[sseg * 2]; c1r.v = gc[sseg * 2 + 1];
    s0r.v = gsat[sseg * 2]; s1r.v = gsat[sseg * 2 + 1];
    int4 br0 = gb[sseg * 2], br1 = gb[sseg * 2 + 1];
    for (int p = 0; p < PW; p += 32) {
        U8 o0, o1;
#pragma unroll
        for (int e = 0; e < 8; ++e) {
            o0.s[e] = f2bf(bf2f(c0r.s[e]) * bf2f(s0r.s[e]));
            o1.s[e] = f2bf(bf2f(c1r.s[e]) * bf2f(s1r.s[e]));
        }
        __syncthreads();
        *(int4*)&As[sr * 40 + sseg * 16] = o0.v; *(int4*)&As[sr * 40 + sseg * 16 + 8] = o1.v;
        *(int4*)&Bs[sr * 40 + sseg * 16] = br0;  *(int4*)&Bs[sr * 40 + sseg * 16 + 8] = br1;
        __syncthreads();
        if (p + 32 < PW) {
            int o = ((p + 32) >> 3) + sseg * 2;
            c0r.v = gc[o]; c1r.v = gc[o + 1];
            s0r.v = gsat[o]; s1r.v = gsat[o + 1];
            br0 = gb[o]; br1 = gb[o + 1];
        }
        int ko = (lane >> 4) * 8;
        bf16x8 af[4], bfr[4];
#pragma unroll
        for (int f = 0; f < 4; ++f) {
            af[f] = *(const bf16x8*)&As[(wr * 64 + f * 16 + (lane & 15)) * 40 + ko];
            bfr[f] = *(const bf16x8*)&Bs[(wc * 64 + f * 16 + (lane & 15)) * 40 + ko];
        }
#pragma unroll
        for (int fm = 0; fm < 4; ++fm)
#pragma unroll
            for (int fn = 0; fn < 4; ++fn)
                acc[fm][fn] = __builtin_amdgcn_mfma_f32_16x16x32_bf16(af[fm], bfr[fn], acc[fm][fn], 0, 0, 0);
    }
    unsigned short* hp = h2 + (size_t)bk * 768000;
#pragma unroll
    for (int fm = 0; fm < 4; ++fm) {
        int row0 = i0 + wr * 64 + fm * 16 + ((lane >> 4) << 2);
#pragma unroll
        for (int fn = 0; fn < 4; ++fn) {
            int col = r0 + wc * 64 + fn * 16 + (lane & 15);
#pragma unroll
            for (int q = 0; q < 4; ++q) {
                int row = row0 + q;
                if (row < N_) hp[(size_t)row * 384 + col] = f2bf(acc[fm][fn][q]);
            }
        }
    }
}

// ---------------- fused tail: theta mix + time conv + residual + relu + LayerNorm ----------------
// block: 64 nodes x 8 f-groups (512 threads). LDS: gl[64][385] uints (98.5KB) + th bf16 12KB (red overlays th).
__global__ __launch_bounds__(512) void k_final3(const float* __restrict__ x, const unsigned short* __restrict__ h2,
                                                const float* __restrict__ ThetaG,
                                                const float* __restrict__ tcwT, const float* __restrict__ tc_b,
                                                const float* __restrict__ rcwT, const float* __restrict__ rc_b,
                                                const float* __restrict__ ln_g, const float* __restrict__ ln_b,
                                                float* __restrict__ out) {
    __shared__ __align__(16) char smem[110848];
    unsigned int* gl = (unsigned int*)smem;                      // [64][385] packed bf16 pairs
    unsigned short* th = (unsigned short*)(smem + 98560);        // [6144] Theta bf16
    float* red_s = (float*)(smem + 98560);                       // overlays th after theta: [64][13]
    float* red_q = red_s + 64 * 13;

    int tid = threadIdx.x;
    int n_l = tid & 63, fg = tid >> 6;
    int b = blockIdx.y;
    int node = blockIdx.x * 64 + n_l;
    bool ok = node < N_;
    int nd = ok ? node : N_ - 1;

    for (int q = tid; q < 6144; q += 512) th[q] = f2bf(ThetaG[q]);
    __syncthreads();

    // ---- theta mix ----
    float acc[8][12];
#pragma unroll
    for (int ff = 0; ff < 8; ++ff)
#pragma unroll
        for (int t = 0; t < 12; ++t) acc[ff][t] = 0.f;
    const unsigned short* hb = h2 + (size_t)b * 3 * 768000 + (size_t)nd * 384;
#pragma unroll
    for (int kk = 0; kk < 3; ++kk) {
        const unsigned short* hp = hb + (size_t)kk * 768000;
#pragma unroll 2
        for (int c = 0; c < 32; ++c) {
            const unsigned short* hq = hp + c * 12;
            uint2 u0 = *(const uint2*)(hq);
            uint2 u1 = *(const uint2*)(hq + 4);
            uint2 u2 = *(const uint2*)(hq + 8);
            float h[12];
            h[0] = bf2f((unsigned short)u0.x);  h[1] = bf2f((unsigned short)(u0.x >> 16));
            h[2] = bf2f((unsigned short)u0.y);  h[3] = bf2f((unsigned short)(u0.y >> 16));
            h[4] = bf2f((unsigned short)u1.x);  h[5] = bf2f((unsigned short)(u1.x >> 16));
            h[6] = bf2f((unsigned short)u1.y);  h[7] = bf2f((unsigned short)(u1.y >> 16));
            h[8] = bf2f((unsigned short)u2.x);  h[9] = bf2f((unsigned short)(u2.x >> 16));
            h[10] = bf2f((unsigned short)u2.y); h[11] = bf2f((unsigned short)(u2.y >> 16));
            const unsigned short* wv = th + (kk * 32 + c) * 64 + fg * 8;
            uint2 w01 = *(const uint2*)wv;
            uint2 w23 = *(const uint2*)(wv + 4);
            float wf[8];
            wf[0] = bf2f((unsigned short)w01.x); wf[1] = bf2f((unsigned short)(w01.x >> 16));
            wf[2] = bf2f((unsigned short)w01.y); wf[3] = bf2f((unsigned short)(w01.y >> 16));
            wf[4] = bf2f((unsigned short)w23.x); wf[5] = bf2f((unsigned short)(w23.x >> 16));
            wf[6] = bf2f((unsigned short)w23.y); wf[7] = bf2f((unsigned short)(w23.y >> 16));
#pragma unroll
            for (int ff = 0; ff < 8; ++ff)
#pragma unroll
                for (int t = 0; t < 12; ++t) acc[ff][t] = fmaf(h[t], wf[ff], acc[ff][t]);
        }
    }
    // relu + pack into gl
    unsigned int* gr = gl + n_l * 385 + fg * 48;
#pragma unroll
    for (int ff = 0; ff < 8; ++ff)
#pragma unroll
        for (int tp = 0; tp < 6; ++tp) {
            float a0 = fmaxf(acc[ff][2 * tp], 0.f), a1 = fmaxf(acc[ff][2 * tp + 1], 0.f);
            gr[ff * 6 + tp] = (unsigned int)f2bf(a0) | ((unsigned int)f2bf(a1) << 16);
        }
    __syncthreads();

    // ---- residual (1x1 conv) + time conv (1x3) ----
    float z[8][12];
#pragma unroll
    for (int ff = 0; ff < 8; ++ff) {
        float bias = tc_b[fg * 8 + ff] + rc_b[fg * 8 + ff];
#pragma unroll
        for (int t = 0; t < 12; ++t) z[ff][t] = bias;
    }
    const float* xp = x + (size_t)(b * 2000 + nd) * 384;
#pragma unroll 2
    for (int c = 0; c < 32; ++c) {
        float4 x0 = *(const float4*)(xp + c * 12);
        float4 x1 = *(const float4*)(xp + c * 12 + 4);
        float4 x2 = *(const float4*)(xp + c * 12 + 8);
        float xv[12] = {x0.x, x0.y, x0.z, x0.w, x1.x, x1.y, x1.z, x1.w, x2.x, x2.y, x2.z, x2.w};
        float4 r0 = *(const float4*)(rcwT + c * 64 + fg * 8);
        float4 r1 = *(const float4*)(rcwT + c * 64 + fg * 8 + 4);
        float rw[8] = {r0.x, r0.y, r0.z, r0.w, r1.x, r1.y, r1.z, r1.w};
#pragma unroll
        for (int ff = 0; ff < 8; ++ff)
#pragma unroll
            for (int t = 0; t < 12; ++t) z[ff][t] = fmaf(xv[t], rw[ff], z[ff][t]);
    }
    const unsigned int* grow = gl + n_l * 385;
    for (int fi = 0; fi < 64; ++fi) {
        float g[12];
#pragma unroll
        for (int j = 0; j < 6; ++j) {
            unsigned int u = grow[fi * 6 + j];
            g[2 * j] = bf2f((unsigned short)u);
            g[2 * j + 1] = bf2f((unsigned short)(u >> 16));
        }
        const float* wp = tcwT + (fi * 64 + fg * 8) * 3;
        float4 w0 = *(const float4*)(wp);
        float4 w1 = *(const float4*)(wp + 4);
        float4 w2 = *(const float4*)(wp + 8);
        float4 w3 = *(const float4*)(wp + 12);
        float4 w4 = *(const float4*)(wp + 16);
        float4 w5 = *(const float4*)(wp + 20);
        float wb[24] = {w0.x, w0.y, w0.z, w0.w, w1.x, w1.y, w1.z, w1.w,
                        w2.x, w2.y, w2.z, w2.w, w3.x, w3.y, w3.z, w3.w,
                        w4.x, w4.y, w4.z, w4.w, w5.x, w5.y, w5.z, w5.w};
#pragma unroll
        for (int ff = 0; ff < 8; ++ff) {
            float a0 = wb[ff * 3], a1 = wb[ff * 3 + 1], a2 = wb[ff * 3 + 2];
            z[ff][0] = fmaf(g[0], a1, fmaf(g[1], a2, z[ff][0]));
#pragma unroll
            for (int t = 1; t < 11; ++t)
                z[ff][t] = fmaf(g[t - 1], a0, fmaf(g[t], a1, fmaf(g[t + 1], a2, z[ff][t])));
            z[ff][11] = fmaf(g[10], a0, fmaf(g[11], a1, z[ff][11]));
        }
    }
    // relu
#pragma unroll
    for (int ff = 0; ff < 8; ++ff)
#pragma unroll
        for (int t = 0; t < 12; ++t) z[ff][t] = fmaxf(z[ff][t], 0.f);

    // ---- LayerNorm over 64 f ----
    float s[12], q[12];
#pragma unroll
    for (int t = 0; t < 12; ++t) { s[t] = 0.f; q[t] = 0.f; }
#pragma unroll
    for (int ff = 0; ff < 8; ++ff)
#pragma unroll
        for (int t = 0; t < 12; ++t) { s[t] += z[ff][t]; q[t] += z[ff][t] * z[ff][t]; }
    __syncthreads();
    for (int g = 0; g < 8; ++g) {
        if (fg == g) {
            if (g == 0) {
#pragma unroll
                for (int t = 0; t < 12; ++t) { red_s[n_l * 13 + t] = s[t]; red_q[n_l * 13 + t] = q[t]; }
            } else {
#pragma unroll
                for (int t = 0; t < 12; ++t) { red_s[n_l * 13 + t] += s[t]; red_q[n_l * 13 + t] += q[t]; }
            }
        }
        __syncthreads();
    }
    float mu[12], rs[12];
#pragma unroll
    for (int t = 0; t < 12; ++t) {
        float m = red_s[n_l * 13 + t] * (1.0f / 64.0f);
        float v = red_q[n_l * 13 + t] * (1.0f / 64.0f) - m * m;
        mu[t] = m;
        rs[t] = rsqrtf(v + 1e-5f);
    }
    if (ok) {
        float* op = out + ((size_t)(b * 2000 + node) * 64 + fg * 8) * 12;
#pragma unroll
        for (int ff = 0; ff < 8; ++ff) {
            float lg = ln_g[fg * 8 + ff], lb = ln_b[fg * 8 + ff];
            float o[12];
#pragma unroll
            for (int t = 0; t < 12; ++t) o[t] = (z[ff][t] - mu[t]) * rs[t] * lg + lb;
#pragma unroll
            for (int tq = 0; tq < 3; ++tq)
                *(float4*)(op + ff * 12 + tq * 4) = make_float4(o[tq * 4], o[tq * 4 + 1], o[tq * 4 + 2], o[tq * 4 + 3]);
        }
    }
}

extern "C" void kernel_launch(void* const* d_in, const int* in_sizes, int n_in,
                              void* d_out, int out_size, void* d_ws, size_t ws_size,
                              hipStream_t stream) {
    const float* x     = (const float*)d_in[0];
    const float* cheb  = (const float*)d_in[1];
    const float* U1    = (const float*)d_in[2];
    const float* U2    = (const float*)d_in[3];
    const float* U3    = (const float*)d_in[4];
    const float* be    = (const float*)d_in[5];
    const float* Ve    = (const float*)d_in[6];
    const float* W1    = (const float*)d_in[7];
    const float* W2    = (const float*)d_in[8];
    const float* W3    = (const float*)d_in[9];
    const float* bs    = (const float*)d_in[10];
    const float* Vs    = (const float*)d_in[11];
    const float* Theta = (const float*)d_in[12];
    const float* tc_w  = (const float*)d_in[13];
    const float* tc_b  = (const float*)d_in[14];
    const float* rc_w  = (const float*)d_in[15];
    const float* rc_b  = (const float*)d_in[16];
    const float* ln_g  = (const float*)d_in[17];
    const float* ln_b  = (const float*)d_in[18];
    float* out = (float*)d_out;

    // ---- workspace layout (corrected; ~173 MiB) ----
    float* ws    = (float*)d_ws;
    float* At    = ws;                       // 1152                -> 1152
    float* lhs1  = ws + 1152;                // 3072                -> 4224
    float* lhsT  = ws + 4224;                // 192000              -> 196224
    float* rhsT  = ws + 196224;              // 192000              -> 388224
    float* lhs_s = ws + 388224;              // 192000              -> 580224
    float* rhs_s = ws + 580224;              // 192000              -> 772224
    float* pm    = ws + 772224;              // 131072              -> 903296
    float* ps    = ws + 903296;              // 131072              -> 1034368
    float* gm    = ws + 1034368;             // 16384               -> 1050752
    float* gs    = ws + 1050752;             // 16384               -> 1067136
    float* tcwT  = ws + 1067136;             // 12288               -> 1079424
    float* rcwT  = ws + 1079424;             // 2048                -> 1081472
    unsigned short* Vsb   = (unsigned short*)(ws + 1081472);   // 2048*2048 bf16 = 2097152 fl -> 3178624
    unsigned short* chebT = (unsigned short*)(ws + 3178624);   // 3*2048*2048 bf16 = 6291456 fl -> 9470080
    unsigned short* xT    = (unsigned short*)(ws + 9470080);   // 8*384*2048 bf16 = 3145728 fl -> 12615808
    unsigned short* sigT  = (unsigned short*)(ws + 12615808);  // 8*2048*2048 bf16 = 16777216 fl -> 29393024
    unsigned short* SAtT  = sigT;                              // reuse after gemm_S
    float* region1 = ws + 29393024;                            // 16,000,000 floats -> 45393024
    float* xTA = region1;                                      // 3,072,000 f32
    unsigned short* Sb = (unsigned short*)region1;             // 8*2000*2000 bf16
    unsigned short* h2 = (unsigned short*)region1;             // 24*2000*384 bf16 (after Sb dead)

    // prep
    k_wprep<<<56, 256, 0, stream>>>(tc_w, rc_w, tcwT, rcwT);
    k_vsb<<<2048, 256, 0, stream>>>(Vs, Vsb);
    k_chebT<<<dim3(32, 32, 3), 256, 0, stream>>>(cheb, chebT);
    k_xT<<<dim3(32, 6, 8), 256, 0, stream>>>(x, xT);
    // temporal attention
    k_lhs1<<<B_ * T_, 256, 0, stream>>>(x, U1, lhs1);
    k_rhs<<<(B_ * N_ * T_ + 255) / 256, 256, 0, stream>>>(x, U3, rhsT);
    k_lhsT<<<(B_ * T_ * N_ + 255) / 256, 256, 0, stream>>>(lhs1, U2, lhsT);
    k_tatt<<<B_, 256, 0, stream>>>(lhsT, rhsT, be, Ve, At);
    k_xTAt<<<2000, 256, 0, stream>>>(x, At, xTA);
    k_sprep<<<(B_ * N_ + 255) / 256, 256, 0, stream>>>(xTA, W1, W2, W3, lhs_s, rhs_s);
    // spatial attention
    k_sig<<<dim3(32, 32, 8), 256, 0, stream>>>(lhs_s, rhs_s, bs, sigT);
    k_gemm_S_mfma<<<dim3(16, 16, 8), 256, 0, stream>>>(Vsb, sigT, Sb);
    k_sm1<<<dim3(8, 8, 8), 256, 0, stream>>>(Sb, pm, ps);
    k_sm2<<<dim3(8, 8), 256, 0, stream>>>(pm, ps, gm, gs);
    k_sm3T<<<dim3(32, 32, 8), 256, 0, stream>>>(Sb, gm, gs, SAtT);
    // chebyshev gcn
    k_gemm_cheb_mfma<<<dim3(3, 16, 24), 256, 0, stream>>>(chebT, SAtT, xT, h2);
    // fused theta + conv + LN tail
    k_final3<<<dim3(32, 8), 512, 0, stream>>>(x, h2, Theta, tcwT, tc_b, rcwT, rc_b, ln_g, ln_b, out);
}

// Round 7
// 794.075 us; speedup vs baseline: 5.8181x; 1.1445x over previous
//
#include <hip/hip_runtime.h>
#include <hip/hip_bf16.h>
#include <math.h>

#define B_ 8
#define N_ 2000
#define C_ 32
#define T_ 12
#define K_ 3
#define FC_ 64
#define FT_ 64
#define PW 2048   // padded width (K and row pads, zero-filled)

typedef short bf16x8 __attribute__((ext_vector_type(8)));
typedef float f32x4 __attribute__((ext_vector_type(4)));

__device__ __forceinline__ float sigmoidf(float v) { return 1.0f / (1.0f + __expf(-v)); }
__device__ __forceinline__ float bf2f(unsigned short u) {
    union { unsigned int i; float f; } v; v.i = ((unsigned int)u) << 16; return v.f;
}
__device__ __forceinline__ unsigned short f2bf(float f) {
    union { __hip_bfloat16 h; unsigned short u; } v; v.h = __float2bfloat16(f); return v.u;
}
typedef const __attribute__((address_space(1))) void* gas_t;
typedef __attribute__((address_space(3))) void* las_t;
__device__ __forceinline__ void gload16(const unsigned short* g, unsigned short* l) {
    __builtin_amdgcn_global_load_lds((gas_t)g, (las_t)l, 16, 0, 0);
}

// ---------------- fused x-pass: lhs1 partials + rhsT ----------------
// grid (50, 8), 256 thr = 8 nodes x 32 c; 5 node-iterations -> 40 nodes/block
__global__ __launch_bounds__(256) void k_tprep(const float* __restrict__ x, const float* __restrict__ U1,
                                               const float* __restrict__ U3,
                                               float* __restrict__ rhsT, float* __restrict__ plh) {
    int b = blockIdx.y, chunk = blockIdx.x;
    int tid = threadIdx.x;
    int nl = tid >> 5, c = tid & 31;
    int w = tid >> 6;
    float u3 = U3[c];
    float plA[12];
#pragma unroll
    for (int t = 0; t < 12; ++t) plA[t] = 0.f;
    for (int it = 0; it < 5; ++it) {
        int n = chunk * 40 + it * 8 + nl;
        const float* xp = x + ((size_t)(b * 2000 + n) * 32 + c) * 12;
        float4 v0 = *(const float4*)xp, v1 = *(const float4*)(xp + 4), v2 = *(const float4*)(xp + 8);
        float xv[12] = {v0.x, v0.y, v0.z, v0.w, v1.x, v1.y, v1.z, v1.w, v2.x, v2.y, v2.z, v2.w};
        // rhsT
        float rv[12];
#pragma unroll
        for (int t = 0; t < 12; ++t) rv[t] = u3 * xv[t];
#pragma unroll
        for (int off = 16; off >= 1; off >>= 1)
#pragma unroll
            for (int t = 0; t < 12; ++t) rv[t] += __shfl_xor(rv[t], off);
        if (c == 0) {
#pragma unroll
            for (int t = 0; t < 12; ++t) rhsT[(size_t)(b * 2000 + n) * 12 + t] = rv[t];
        }
        // lhs1 partial
        float u1 = U1[n];
#pragma unroll
        for (int t = 0; t < 12; ++t) plA[t] += u1 * xv[t];
    }
    // pair-reduce nodes within wave (lane ^ 32 = same c, partner node)
#pragma unroll
    for (int t = 0; t < 12; ++t) plA[t] += __shfl_xor(plA[t], 32);
    __shared__ float accs[4][32][12];
    if ((tid & 63) < 32) {
#pragma unroll
        for (int t = 0; t < 12; ++t) accs[w][c][t] = plA[t];
    }
    __syncthreads();
    if (tid < 384) {
        int c2 = tid / 12, t2 = tid % 12;
        float s = accs[0][c2][t2] + accs[1][c2][t2] + accs[2][c2][t2] + accs[3][c2][t2];
        plh[((size_t)(b * 50 + chunk)) * 384 + tid] = s;
    }
}

// reduce plh over 50 chunks -> lhs1[b][t][c]
__global__ __launch_bounds__(256) void k_tred(const float* __restrict__ plh, float* __restrict__ lhs1) {
    int b = blockIdx.x;
    for (int q = threadIdx.x; q < 384; q += 256) {
        const float* p = plh + (size_t)b * 50 * 384 + q;
        float s = 0.f;
        for (int ch = 0; ch < 50; ++ch) s += p[(size_t)ch * 384];
        int c = q / 12, t = q % 12;
        lhs1[(b * 12 + t) * 32 + c] = s;
    }
}

// lhsT[b][t][n] = sum_c lhs1[b][t][c] * U2[c][n]
__global__ __launch_bounds__(256) void k_lhsT(const float* __restrict__ lhs1, const float* __restrict__ U2,
                                              float* __restrict__ lhsT) {
    int gid = blockIdx.x * 256 + threadIdx.x;
    if (gid >= B_ * T_ * N_) return;
    int n = gid % N_;
    int bt = gid / N_;
    const float* l1 = lhs1 + bt * C_;
    float a = 0.f;
#pragma unroll
    for (int c = 0; c < C_; ++c) a += l1[c] * U2[c * N_ + n];
    lhsT[gid] = a;
}

// partial P[t][u] over n-chunks: grid (16, 8)
__global__ __launch_bounds__(256) void k_tatt1(const float* __restrict__ lhsT, const float* __restrict__ rhsT,
                                               float* __restrict__ pP) {
    int b = blockIdx.y, ch = blockIdx.x;
    int tid = threadIdx.x;
    int n0 = ch * 125;
    __shared__ float sL[12][128];
    __shared__ float sR[128][12];
    for (int q = tid; q < 12 * 125; q += 256) {
        int t = q / 125, nn = q % 125;
        sL[t][nn] = lhsT[(size_t)(b * 12 + t) * 2000 + n0 + nn];
    }
    for (int q = tid; q < 125 * 12; q += 256) {
        int nn = q / 12, t = q % 12;
        sR[nn][t] = rhsT[(size_t)(b * 2000 + n0 + nn) * 12 + t];
    }
    __syncthreads();
    if (tid < 144) {
        int tP = tid / 12, uP = tid % 12;
        float a = 0.f;
#pragma unroll 5
        for (int nn = 0; nn < 125; ++nn) a += sL[tP][nn] * sR[nn][uP];
        pP[(size_t)(b * 16 + ch) * 144 + tid] = a;
    }
}

// finish temporal attention: reduce chunks, sigmoid, Ve, column softmax
__global__ __launch_bounds__(256) void k_tatt2(const float* __restrict__ pP, const float* __restrict__ be,
                                               const float* __restrict__ Ve, float* __restrict__ At) {
    int b = blockIdx.x, tid = threadIdx.x;
    __shared__ float sp[144], sE[144], mk[12], sk[12];
    int tP = tid / 12, uP = tid % 12;
    if (tid < 144) {
        float a = 0.f;
#pragma unroll
        for (int ch = 0; ch < 16; ++ch) a += pP[(size_t)(b * 16 + ch) * 144 + tid];
        sp[tid] = sigmoidf(a + be[tid]);
    }
    __syncthreads();
    if (tid < 144) {
        float e = 0.f;
#pragma unroll
        for (int j = 0; j < 12; ++j) e += Ve[tP * 12 + j] * sp[j * 12 + uP];
        sE[tid] = e;
    }
    __syncthreads();
    if (tid < 12) {
        float m = -1e30f;
#pragma unroll
        for (int i = 0; i < 12; ++i) m = fmaxf(m, sE[i * 12 + tid]);
        float s = 0.f;
#pragma unroll
        for (int i = 0; i < 12; ++i) s += __expf(sE[i * 12 + tid] - m);
        mk[tid] = m; sk[tid] = 1.0f / s;
    }
    __syncthreads();
    if (tid < 144) At[b * 144 + tid] = __expf(sE[tid] - mk[uP]) * sk[uP];
}

// fused xTAt + sprep: grid (250, 8), 8 nodes x 32 c
__global__ __launch_bounds__(256) void k_xsp(const float* __restrict__ x, const float* __restrict__ At,
                                             const float* __restrict__ W1, const float* __restrict__ W2,
                                             const float* __restrict__ W3,
                                             float* __restrict__ lhs_s, float* __restrict__ rhs_s) {
    int b = blockIdx.y, chunk = blockIdx.x;
    int tid = threadIdx.x, nl = tid >> 5, c = tid & 31;
    int n = chunk * 8 + nl;
    __shared__ float atl[144];
    __shared__ float w2l[384];
    __shared__ float w1l[12];
    if (tid < 144) atl[tid] = At[b * 144 + tid];
    if (tid >= 144 && tid < 156) w1l[tid - 144] = W1[tid - 144];
    for (int q = tid; q < 384; q += 256) w2l[q] = W2[q];
    __syncthreads();
    const float* xp = x + ((size_t)(b * 2000 + n) * 32 + c) * 12;
    float4 v0 = *(const float4*)xp, v1 = *(const float4*)(xp + 4), v2 = *(const float4*)(xp + 8);
    float xv[12] = {v0.x, v0.y, v0.z, v0.w, v1.x, v1.y, v1.z, v1.w, v2.x, v2.y, v2.z, v2.w};
    float xa[12];
#pragma unroll
    for (int t = 0; t < 12; ++t) {
        float s = 0.f;
#pragma unroll
        for (int u = 0; u < 12; ++u) s += xv[u] * atl[u * 12 + t];
        xa[t] = s;
    }
    float w3 = W3[c];
    float rv[12], lv[12];
    float l1 = 0.f;
#pragma unroll
    for (int t = 0; t < 12; ++t) l1 += xa[t] * w1l[t];
#pragma unroll
    for (int t = 0; t < 12; ++t) { rv[t] = w3 * xa[t]; lv[t] = l1 * w2l[c * 12 + t]; }
#pragma unroll
    for (int off = 16; off >= 1; off >>= 1)
#pragma unroll
        for (int t = 0; t < 12; ++t) { rv[t] += __shfl_xor(rv[t], off); lv[t] += __shfl_xor(lv[t], off); }
    if (c == 0) {
#pragma unroll
        for (int t = 0; t < 12; ++t) rhs_s[(size_t)(b * 12 + t) * 2000 + n] = rv[t];
#pragma unroll
        for (int t = 0; t < 12; ++t) lhs_s[(size_t)(b * 2000 + n) * 12 + t] = lv[t];
    }
}

// ---------------- weight transposes ----------------
__global__ __launch_bounds__(256) void k_wprep(const float* __restrict__ tc_w, const float* __restrict__ rc_w,
                                               float* __restrict__ tcwT, float* __restrict__ rcwT) {
    int gid = blockIdx.x * 256 + threadIdx.x;
    if (gid < 12288) {
        int fi = gid / 192, rem = gid % 192, f = rem / 3, d = rem % 3;
        tcwT[gid] = tc_w[(f * 64 + fi) * 3 + d];
    } else if (gid < 14336) {
        int q = gid - 12288;
        int c = q >> 6, f = q & 63;
        rcwT[q] = rc_w[f * 32 + c];
    }
}

// ---------------- conversions / transposes (padded to PW, zero-filled) ----------------
__global__ __launch_bounds__(256) void k_vsb(const float* __restrict__ Vs, unsigned short* __restrict__ Vsb) {
    int gid = blockIdx.x * 256 + threadIdx.x;
    int row = gid >> 8, chunk = gid & 255;
    int p0 = chunk * 8;
    unsigned short o[8];
#pragma unroll
    for (int e = 0; e < 8; ++e) {
        int p = p0 + e;
        o[e] = (row < N_ && p < N_) ? f2bf(Vs[row * N_ + p]) : (unsigned short)0;
    }
    *(int4*)(Vsb + (size_t)row * PW + p0) = *(int4*)o;
}

__global__ __launch_bounds__(256) void k_chebT(const float* __restrict__ cheb, unsigned short* __restrict__ chebT) {
    int j0 = blockIdx.x * 64, i0 = blockIdx.y * 64, kk = blockIdx.z;
    __shared__ float Tl[64][65];
    int t = threadIdx.x;
    int rr = t >> 2, c0 = (t & 3) * 16;
    int j = j0 + rr;
#pragma unroll
    for (int e = 0; e < 16; ++e) {
        int i = i0 + c0 + e;
        Tl[rr][c0 + e] = (j < N_ && i < N_) ? cheb[(size_t)kk * 4000000 + (size_t)j * N_ + i] : 0.f;
    }
    __syncthreads();
    int l = t & 63, w = t >> 6;
    unsigned short o[16];
#pragma unroll
    for (int e = 0; e < 16; ++e) o[e] = f2bf(Tl[w * 16 + e][l]);
    unsigned short* dst = chebT + (size_t)kk * PW * PW + (size_t)(i0 + l) * PW + j0 + w * 16;
    *(int4*)dst = *(int4*)o;
    *(int4*)(dst + 8) = *(int4*)(o + 8);
}

__global__ __launch_bounds__(256) void k_xT(const float* __restrict__ x, unsigned short* __restrict__ xT) {
    int j0 = blockIdx.x * 64, r0 = blockIdx.y * 64, b = blockIdx.z;
    __shared__ float Tl[64][65];
    int t = threadIdx.x;
    int rr = t >> 2, c0 = (t & 3) * 16;
    int j = j0 + rr;
#pragma unroll
    for (int e = 0; e < 16; ++e) {
        int r = r0 + c0 + e;
        Tl[rr][c0 + e] = (j < N_) ? x[(size_t)(b * N_ + j) * 384 + r] : 0.f;
    }
    __syncthreads();
    int l = t & 63, w = t >> 6;
    unsigned short o[16];
#pragma unroll
    for (int e = 0; e < 16; ++e) o[e] = f2bf(Tl[w * 16 + e][l]);
    unsigned short* dst = xT + (size_t)b * 384 * PW + (size_t)(r0 + l) * PW + j0 + w * 16;
    *(int4*)dst = *(int4*)o;
    *(int4*)(dst + 8) = *(int4*)(o + 8);
}

__global__ __launch_bounds__(256) void k_sig(const float* __restrict__ lhs_s, const float* __restrict__ rhs_s,
                                             const float* __restrict__ bs, unsigned short* __restrict__ sigT) {
    int p0 = blockIdx.x * 64, i0 = blockIdx.y * 64, b = blockIdx.z;
    __shared__ float sL[64][12];
    __shared__ float sR[12][64];
    __shared__ float bsl[64][65];
    int t = threadIdx.x;
    for (int q = t; q < 768; q += 256) {
        int pp = q / 12, tt = q % 12;
        int p = p0 + pp;
        sL[pp][tt] = (p < N_) ? lhs_s[(b * N_ + p) * 12 + tt] : 0.f;
    }
    for (int q = t; q < 768; q += 256) {
        int tt = q >> 6, ii = q & 63;
        int i = i0 + ii;
        sR[tt][ii] = (i < N_) ? rhs_s[b * (T_ * N_) + tt * N_ + i] : 0.f;
    }
    {
        int pp = t >> 2, c0 = (t & 3) * 16;
        int p = p0 + pp;
        if (p < N_ && i0 + c0 + 15 < N_) {
            const float* src = bs + (size_t)p * N_ + i0 + c0;
#pragma unroll
            for (int e = 0; e < 16; e += 4) *(float4*)&bsl[pp][c0 + e] = *(const float4*)(src + e);
        } else {
#pragma unroll
            for (int e = 0; e < 16; ++e) {
                int i = i0 + c0 + e;
                bsl[pp][c0 + e] = (p < N_ && i < N_) ? bs[(size_t)p * N_ + i] : 0.f;
            }
        }
    }
    __syncthreads();
    int ii = t & 63, w = t >> 6;
    int i = i0 + ii;
    unsigned short o[16];
#pragma unroll
    for (int e = 0; e < 16; ++e) {
        int pl = w * 16 + e;
        int p = p0 + pl;
        float v = 0.f;
        if (p < N_ && i < N_) {
            float d = bsl[pl][ii];
#pragma unroll
            for (int tt = 0; tt < 12; ++tt) d += sL[pl][tt] * sR[tt][ii];
            v = sigmoidf(d);
        }
        o[e] = f2bf(v);
    }
    unsigned short* dst = sigT + (size_t)b * PW * PW + (size_t)i * PW + p0 + w * 16;
    *(int4*)dst = *(int4*)o;
    *(int4*)(dst + 8) = *(int4*)(o + 8);
}

// ---------------- MFMA GEMM (gload_lds dbuf): S[j][i] = sum_p Vs[j][p]*sig[p][i] ----------------
__global__ __launch_bounds__(256) void k_gemm_S_mfma(const unsigned short* __restrict__ Vsb,
                                                     const unsigned short* __restrict__ sigT,
                                                     unsigned short* __restrict__ S) {
    int b = blockIdx.z;
    int i0 = blockIdx.x * 128, j0 = blockIdx.y * 128;
    const unsigned short* Bp = sigT + (size_t)b * PW * PW;
    __shared__ unsigned short As[2][4096];
    __shared__ unsigned short Bs[2][4096];
    int t = threadIdx.x, lane = t & 63, w = t >> 6;
    int wr = w >> 1, wc = w & 1;
    f32x4 acc[4][4];
#pragma unroll
    for (int a = 0; a < 4; ++a)
#pragma unroll
        for (int c = 0; c < 4; ++c)
#pragma unroll
            for (int q = 0; q < 4; ++q) acc[a][c][q] = 0.f;
    // pre-swizzled global source: seg = (t&3) ^ ((t>>2)&3); linear LDS dest
    int srow = t >> 2;
    int sseg = (t & 3) ^ (srow & 3);
    const unsigned short* gA = Vsb + (size_t)(j0 + srow) * PW + sseg * 8;
    const unsigned short* gB = Bp + (size_t)(i0 + srow) * PW + sseg * 8;
    int ldso = w * 512;
#define STAGE_S(buf, p) do { \
    gload16(gA + (p), &As[buf][ldso]); \
    gload16(gA + 64 * PW + (p), &As[buf][2048 + ldso]); \
    gload16(gB + (p), &Bs[buf][ldso]); \
    gload16(gB + 64 * PW + (p), &Bs[buf][2048 + ldso]); \
} while (0)
    STAGE_S(0, 0);
    __syncthreads();
    int cur = 0;
    int rswz = ((lane >> 4) ^ (lane & 3)) * 8;   // swizzled read seg offset
    for (int p = 0; p < PW; p += 32) {
        if (p + 32 < PW) STAGE_S(cur ^ 1, p + 32);
        bf16x8 af[4], bfr[4];
#pragma unroll
        for (int f = 0; f < 4; ++f) {
            af[f] = *(const bf16x8*)&As[cur][(wr * 64 + f * 16 + (lane & 15)) * 32 + rswz];
            bfr[f] = *(const bf16x8*)&Bs[cur][(wc * 64 + f * 16 + (lane & 15)) * 32 + rswz];
        }
#pragma unroll
        for (int fm = 0; fm < 4; ++fm)
#pragma unroll
            for (int fn = 0; fn < 4; ++fn)
                acc[fm][fn] = __builtin_amdgcn_mfma_f32_16x16x32_bf16(af[fm], bfr[fn], acc[fm][fn], 0, 0, 0);
        __syncthreads();
        cur ^= 1;
    }
#undef STAGE_S
    unsigned short* Sp = S + (size_t)b * 4000000;
#pragma unroll
    for (int fm = 0; fm < 4; ++fm) {
        int row0 = j0 + wr * 64 + fm * 16 + ((lane >> 4) << 2);
#pragma unroll
        for (int fn = 0; fn < 4; ++fn) {
            int col = i0 + wc * 64 + fn * 16 + (lane & 15);
            if (col >= N_) continue;
#pragma unroll
            for (int q = 0; q < 4; ++q) {
                int row = row0 + q;
                if (row < N_) Sp[(size_t)row * N_ + col] = f2bf(acc[fm][fn][q]);
            }
        }
    }
}

// ---- column softmax over rows j of S[b][j][i] (bf16) ----
__global__ __launch_bounds__(256) void k_sm1(const unsigned short* __restrict__ S, float* __restrict__ pm, float* __restrict__ ps) {
    int k = blockIdx.x * 256 + threadIdx.x;
    int is = blockIdx.y, b = blockIdx.z;
    if (k >= N_) return;
    const unsigned short* sp = S + (size_t)b * 4000000 + k;
    float m = -1e30f, s = 0.f;
    for (int i = is * 250; i < is * 250 + 250; ++i) {
        float v = bf2f(sp[(size_t)i * N_]);
        float mn = fmaxf(m, v);
        s = s * __expf(m - mn) + __expf(v - mn);
        m = mn;
    }
    int o = (b * 8 + is) * 2048 + k;
    pm[o] = m; ps[o] = s;
}

__global__ __launch_bounds__(256) void k_sm2(const float* __restrict__ pm, const float* __restrict__ ps,
                                             float* __restrict__ gm, float* __restrict__ gs) {
    int k = blockIdx.x * 256 + threadIdx.x;
    int b = blockIdx.y;
    if (k >= N_) return;
    float m = -1e30f;
#pragma unroll
    for (int is = 0; is < 8; ++is) m = fmaxf(m, pm[(b * 8 + is) * 2048 + k]);
    float s = 0.f;
#pragma unroll
    for (int is = 0; is < 8; ++is) s += ps[(b * 8 + is) * 2048 + k] * __expf(pm[(b * 8 + is) * 2048 + k] - m);
    gm[b * 2048 + k] = m;
    gs[b * 2048 + k] = 1.0f / s;
}

__global__ __launch_bounds__(256) void k_sm3T(const unsigned short* __restrict__ S,
                                              const float* __restrict__ gm, const float* __restrict__ gs,
                                              unsigned short* __restrict__ SAtT) {
    int j0 = blockIdx.x * 64, i0 = blockIdx.y * 64, b = blockIdx.z;
    __shared__ float Tl[64][65];
    int t = threadIdx.x;
    int rr = t >> 2, c0 = (t & 3) * 16;
    int j = j0 + rr;
#pragma unroll
    for (int e = 0; e < 16; ++e) {
        int i = i0 + c0 + e;
        float v = 0.f;
        if (j < N_ && i < N_) {
            float sv = bf2f(S[(size_t)b * 4000000 + (size_t)j * N_ + i]);
            v = __expf(sv - gm[b * 2048 + i]) * gs[b * 2048 + i];
        }
        Tl[rr][c0 + e] = v;
    }
    __syncthreads();
    int l = t & 63, w = t >> 6;
    unsigned short o[16];
#pragma unroll
    for (int e = 0; e < 16; ++e) o[e] = f2bf(Tl[w * 16 + e][l]);
    unsigned short* dst = SAtT + (size_t)b * PW * PW + (size_t)(i0 + l) * PW + j0 + w * 16;
    *(int4*)dst = *(int4*)o;
    *(int4*)(dst + 8) = *(int4*)(o + 8);
}

// ---------------- MFMA GEMM (512 thr, N=384): h2[i][r] = sum_j (chebT*SAtT)[i][j] * xT[r][j] ----------------
__global__ __launch_bounds__(512) void k_gemm_cheb_mfma(const unsigned short* __restrict__ chebT,
                                                        const unsigned short* __restrict__ SAtT,
                                                        const unsigned short* __restrict__ xT,
                                                        unsigned short* __restrict__ h2) {
    int bk = blockIdx.y;
    int b = bk / 3, kk = bk % 3;
    int i0 = blockIdx.x * 128;
    const unsigned short* Ac = chebT + (size_t)kk * PW * PW;
    const unsigned short* Sa = SAtT + (size_t)b * PW * PW;
    const unsigned short* Bx = xT + (size_t)b * 384 * PW;
    __shared__ unsigned short As[2][4096];
    __shared__ unsigned short Bs[2][12288];
    int t = threadIdx.x, lane = t & 63, w = t >> 6;
    int wr = w >> 2, wc = w & 3;
    f32x4 acc[4][6];
#pragma unroll
    for (int a = 0; a < 4; ++a)
#pragma unroll
        for (int c = 0; c < 6; ++c)
#pragma unroll
            for (int q = 0; q < 4; ++q) acc[a][c][q] = 0.f;
    // A reg-staged (one int4/thread), XOR-swizzled LDS
    int arow = t >> 2, aq = t & 3;
    const unsigned short* gc = Ac + (size_t)(i0 + arow) * PW + aq * 8;
    const unsigned short* gsat = Sa + (size_t)(i0 + arow) * PW + aq * 8;
    int aoff = arow * 32 + (aq ^ (arow & 3)) * 8;
    // B gload, pre-swizzled global source
    int bseg = (t & 3) ^ ((t >> 2) & 3);
    const unsigned short* gB = Bx + (size_t)(t >> 2) * PW + bseg * 8;
    int ldso = w * 512;
#define STAGE_B(buf, p) do { \
    gload16(gB + (p), &Bs[buf][ldso]); \
    gload16(gB + 128 * PW + (p), &Bs[buf][4096 + ldso]); \
    gload16(gB + 256 * PW + (p), &Bs[buf][8192 + ldso]); \
} while (0)
    union U8 { int4 v; unsigned short s[8]; };
    U8 ca, sa;
    ca.v = *(const int4*)gc;
    sa.v = *(const int4*)gsat;
    STAGE_B(0, 0);
    {
        U8 o;
#pragma unroll
        for (int e = 0; e < 8; ++e) o.s[e] = f2bf(bf2f(ca.s[e]) * bf2f(sa.s[e]));
        *(int4*)&As[0][aoff] = o.v;
    }
    ca.v = *(const int4*)(gc + 32);
    sa.v = *(const int4*)(gsat + 32);
    __syncthreads();
    int cur = 0;
    int rswz = ((lane >> 4) ^ (lane & 3)) * 8;
    for (int p = 0; p < PW; p += 32) {
        if (p + 32 < PW) {
            STAGE_B(cur ^ 1, p + 32);
            U8 o;
#pragma unroll
            for (int e = 0; e < 8; ++e) o.s[e] = f2bf(bf2f(ca.s[e]) * bf2f(sa.s[e]));
            *(int4*)&As[cur ^ 1][aoff] = o.v;
            int pn = (p + 64 < PW) ? p + 64 : 0;
            ca.v = *(const int4*)(gc + pn);
            sa.v = *(const int4*)(gsat + pn);
        }
        bf16x8 af[4], bfr[6];
#pragma unroll
        for (int fm = 0; fm < 4; ++fm)
            af[fm] = *(const bf16x8*)&As[cur][(wr * 64 + fm * 16 + (lane & 15)) * 32 + rswz];
#pragma unroll
        for (int fn = 0; fn < 6; ++fn)
            bfr[fn] = *(const bf16x8*)&Bs[cur][(wc * 96 + fn * 16 + (lane & 15)) * 32 + rswz];
#pragma unroll
        for (int fm = 0; fm < 4; ++fm)
#pragma unroll
            for (int fn = 0; fn < 6; ++fn)
                acc[fm][fn] = __builtin_amdgcn_mfma_f32_16x16x32_bf16(af[fm], bfr[fn], acc[fm][fn], 0, 0, 0);
        __syncthreads();
        cur ^= 1;
    }
#undef STAGE_B
    unsigned short* hp = h2 + (size_t)bk * 768000;
#pragma unroll
    for (int fm = 0; fm < 4; ++fm) {
        int row0 = i0 + wr * 64 + fm * 16 + ((lane >> 4) << 2);
#pragma unroll
        for (int fn = 0; fn < 6; ++fn) {
            int col = wc * 96 + fn * 16 + (lane & 15);
#pragma unroll
            for (int q = 0; q < 4; ++q) {
                int row = row0 + q;
                if (row < N_) hp[(size_t)row * 384 + col] = f2bf(acc[fm][fn][q]);
            }
        }
    }
}

// ---------------- fused tail: theta mix + time conv + residual + relu + LayerNorm ----------------
__global__ __launch_bounds__(512) void k_final3(const float* __restrict__ x, const unsigned short* __restrict__ h2,
                                                const float* __restrict__ ThetaG,
                                                const float* __restrict__ tcwT, const float* __restrict__ tc_b,
                                                const float* __restrict__ rcwT, const float* __restrict__ rc_b,
                                                const float* __restrict__ ln_g, const float* __restrict__ ln_b,
                                                float* __restrict__ out) {
    __shared__ __align__(16) char smem[110848];
    unsigned int* gl = (unsigned int*)smem;
    unsigned short* th = (unsigned short*)(smem + 98560);
    float* red_s = (float*)(smem + 98560);
    float* red_q = red_s + 64 * 13;

    int tid = threadIdx.x;
    int n_l = tid & 63, fg = tid >> 6;
    int b = blockIdx.y;
    int node = blockIdx.x * 64 + n_l;
    bool ok = node < N_;
    int nd = ok ? node : N_ - 1;

    for (int q = tid; q < 6144; q += 512) th[q] = f2bf(ThetaG[q]);
    __syncthreads();

    float acc[8][12];
#pragma unroll
    for (int ff = 0; ff < 8; ++ff)
#pragma unroll
        for (int t = 0; t < 12; ++t) acc[ff][t] = 0.f;
    const unsigned short* hb = h2 + (size_t)b * 3 * 768000 + (size_t)nd * 384;
#pragma unroll
    for (int kk = 0; kk < 3; ++kk) {
        const unsigned short* hp = hb + (size_t)kk * 768000;
#pragma unroll 2
        for (int c = 0; c < 32; ++c) {
            const unsigned short* hq = hp + c * 12;
            uint2 u0 = *(const uint2*)(hq);
            uint2 u1 = *(const uint2*)(hq + 4);
            uint2 u2 = *(const uint2*)(hq + 8);
            float h[12];
            h[0] = bf2f((unsigned short)u0.x);  h[1] = bf2f((unsigned short)(u0.x >> 16));
            h[2] = bf2f((unsigned short)u0.y);  h[3] = bf2f((unsigned short)(u0.y >> 16));
            h[4] = bf2f((unsigned short)u1.x);  h[5] = bf2f((unsigned short)(u1.x >> 16));
            h[6] = bf2f((unsigned short)u1.y);  h[7] = bf2f((unsigned short)(u1.y >> 16));
            h[8] = bf2f((unsigned short)u2.x);  h[9] = bf2f((unsigned short)(u2.x >> 16));
            h[10] = bf2f((unsigned short)u2.y); h[11] = bf2f((unsigned short)(u2.y >> 16));
            const unsigned short* wv = th + (kk * 32 + c) * 64 + fg * 8;
            uint2 w01 = *(const uint2*)wv;
            uint2 w23 = *(const uint2*)(wv + 4);
            float wf[8];
            wf[0] = bf2f((unsigned short)w01.x); wf[1] = bf2f((unsigned short)(w01.x >> 16));
            wf[2] = bf2f((unsigned short)w01.y); wf[3] = bf2f((unsigned short)(w01.y >> 16));
            wf[4] = bf2f((unsigned short)w23.x); wf[5] = bf2f((unsigned short)(w23.x >> 16));
            wf[6] = bf2f((unsigned short)w23.y); wf[7] = bf2f((unsigned short)(w23.y >> 16));
#pragma unroll
            for (int ff = 0; ff < 8; ++ff)
#pragma unroll
                for (int t = 0; t < 12; ++t) acc[ff][t] = fmaf(h[t], wf[ff], acc[ff][t]);
        }
    }
    unsigned int* gr = gl + n_l * 385 + fg * 48;
#pragma unroll
    for (int ff = 0; ff < 8; ++ff)
#pragma unroll
        for (int tp = 0; tp < 6; ++tp) {
            float a0 = fmaxf(acc[ff][2 * tp], 0.f), a1 = fmaxf(acc[ff][2 * tp + 1], 0.f);
            gr[ff * 6 + tp] = (unsigned int)f2bf(a0) | ((unsigned int)f2bf(a1) << 16);
        }
    __syncthreads();

    float z[8][12];
#pragma unroll
    for (int ff = 0; ff < 8; ++ff) {
        float bias = tc_b[fg * 8 + ff] + rc_b[fg * 8 + ff];
#pragma unroll
        for (int t = 0; t < 12; ++t) z[ff][t] = bias;
    }
    const float* xp = x + (size_t)(b * 2000 + nd) * 384;
#pragma unroll 2
    for (int c = 0; c < 32; ++c) {
        float4 x0 = *(const float4*)(xp + c * 12);
        float4 x1 = *(const float4*)(xp + c * 12 + 4);
        float4 x2 = *(const float4*)(xp + c * 12 + 8);
        float xv[12] = {x0.x, x0.y, x0.z, x0.w, x1.x, x1.y, x1.z, x1.w, x2.x, x2.y, x2.z, x2.w};
        float4 r0 = *(const float4*)(rcwT + c * 64 + fg * 8);
        float4 r1 = *(const float4*)(rcwT + c * 64 + fg * 8 + 4);
        float rw[8] = {r0.x, r0.y, r0.z, r0.w, r1.x, r1.y, r1.z, r1.w};
#pragma unroll
        for (int ff = 0; ff < 8; ++ff)
#pragma unroll
            for (int t = 0; t < 12; ++t) z[ff][t] = fmaf(xv[t], rw[ff], z[ff][t]);
    }
    const unsigned int* grow = gl + n_l * 385;
    for (int fi = 0; fi < 64; ++fi) {
        float g[12];
#pragma unroll
        for (int j = 0; j < 6; ++j) {
            unsigned int u = grow[fi * 6 + j];
            g[2 * j] = bf2f((unsigned short)u);
            g[2 * j + 1] = bf2f((unsigned short)(u >> 16));
        }
        const float* wp = tcwT + (fi * 64 + fg * 8) * 3;
        float4 w0 = *(const float4*)(wp);
        float4 w1 = *(const float4*)(wp + 4);
        float4 w2 = *(const float4*)(wp + 8);
        float4 w3 = *(const float4*)(wp + 12);
        float4 w4 = *(const float4*)(wp + 16);
        float4 w5 = *(const float4*)(wp + 20);
        float wb[24] = {w0.x, w0.y, w0.z, w0.w, w1.x, w1.y, w1.z, w1.w,
                        w2.x, w2.y, w2.z, w2.w, w3.x, w3.y, w3.z, w3.w,
                        w4.x, w4.y, w4.z, w4.w, w5.x, w5.y, w5.z, w5.w};
#pragma unroll
        for (int ff = 0; ff < 8; ++ff) {
            float a0 = wb[ff * 3], a1 = wb[ff * 3 + 1], a2 = wb[ff * 3 + 2];
            z[ff][0] = fmaf(g[0], a1, fmaf(g[1], a2, z[ff][0]));
#pragma unroll
            for (int t = 1; t < 11; ++t)
                z[ff][t] = fmaf(g[t - 1], a0, fmaf(g[t], a1, fmaf(g[t + 1], a2, z[ff][t])));
            z[ff][11] = fmaf(g[10], a0, fmaf(g[11], a1, z[ff][11]));
        }
    }
#pragma unroll
    for (int ff = 0; ff < 8; ++ff)
#pragma unroll
        for (int t = 0; t < 12; ++t) z[ff][t] = fmaxf(z[ff][t], 0.f);

    float s[12], q[12];
#pragma unroll
    for (int t = 0; t < 12; ++t) { s[t] = 0.f; q[t] = 0.f; }
#pragma unroll
    for (int ff = 0; ff < 8; ++ff)
#pragma unroll
        for (int t = 0; t < 12; ++t) { s[t] += z[ff][t]; q[t] += z[ff][t] * z[ff][t]; }
    __syncthreads();
    for (int g = 0; g < 8; ++g) {
        if (fg == g) {
            if (g == 0) {
#pragma unroll
                for (int t = 0; t < 12; ++t) { red_s[n_l * 13 + t] = s[t]; red_q[n_l * 13 + t] = q[t]; }
            } else {
#pragma unroll
                for (int t = 0; t < 12; ++t) { red_s[n_l * 13 + t] += s[t]; red_q[n_l * 13 + t] += q[t]; }
            }
        }
        __syncthreads();
    }
    float mu[12], rs[12];
#pragma unroll
    for (int t = 0; t < 12; ++t) {
        float m = red_s[n_l * 13 + t] * (1.0f / 64.0f);
        float v = red_q[n_l * 13 + t] * (1.0f / 64.0f) - m * m;
        mu[t] = m;
        rs[t] = rsqrtf(v + 1e-5f);
    }
    if (ok) {
        float* op = out + ((size_t)(b * 2000 + node) * 64 + fg * 8) * 12;
#pragma unroll
        for (int ff = 0; ff < 8; ++ff) {
            float lg = ln_g[fg * 8 + ff], lb = ln_b[fg * 8 + ff];
            float o[12];
#pragma unroll
            for (int t = 0; t < 12; ++t) o[t] = (z[ff][t] - mu[t]) * rs[t] * lg + lb;
#pragma unroll
            for (int tq = 0; tq < 3; ++tq)
                *(float4*)(op + ff * 12 + tq * 4) = make_float4(o[tq * 4], o[tq * 4 + 1], o[tq * 4 + 2], o[tq * 4 + 3]);
        }
    }
}

extern "C" void kernel_launch(void* const* d_in, const int* in_sizes, int n_in,
                              void* d_out, int out_size, void* d_ws, size_t ws_size,
                              hipStream_t stream) {
    const float* x     = (const float*)d_in[0];
    const float* cheb  = (const float*)d_in[1];
    const float* U1    = (const float*)d_in[2];
    const float* U2    = (const float*)d_in[3];
    const float* U3    = (const float*)d_in[4];
    const float* be    = (const float*)d_in[5];
    const float* Ve    = (const float*)d_in[6];
    const float* W1    = (const float*)d_in[7];
    const float* W2    = (const float*)d_in[8];
    const float* W3    = (const float*)d_in[9];
    const float* bs    = (const float*)d_in[10];
    const float* Vs    = (const float*)d_in[11];
    const float* Theta = (const float*)d_in[12];
    const float* tc_w  = (const float*)d_in[13];
    const float* tc_b  = (const float*)d_in[14];
    const float* rc_w  = (const float*)d_in[15];
    const float* rc_b  = (const float*)d_in[16];
    const float* ln_g  = (const float*)d_in[17];
    const float* ln_b  = (const float*)d_in[18];
    float* out = (float*)d_out;

    // ---- workspace layout (~182 MB) ----
    float* ws    = (float*)d_ws;
    float* At    = ws;                       // 1152      -> 1152
    float* lhs1  = ws + 1152;                // 3072      -> 4224
    float* lhsT  = ws + 4224;                // 192000    -> 196224
    float* rhsT  = ws + 196224;              // 192000    -> 388224
    float* lhs_s = ws + 388224;              // 192000    -> 580224
    float* rhs_s = ws + 580224;              // 192000    -> 772224
    float* pm    = ws + 772224;              // 131072    -> 903296
    float* ps    = ws + 903296;              // 131072    -> 1034368
    float* gm    = ws + 1034368;             // 16384     -> 1050752
    float* gs    = ws + 1050752;             // 16384     -> 1067136
    float* tcwT  = ws + 1067136;             // 12288     -> 1079424
    float* rcwT  = ws + 1079424;             // 2048      -> 1081472
    float* plh   = ws + 1081472;             // 153600    -> 1235072
    float* pP    = ws + 1235072;             // 18432     -> 1253504
    unsigned short* Vsb   = (unsigned short*)(ws + 1253504);   // 2,097,152 fl -> 3350656
    unsigned short* chebT = (unsigned short*)(ws + 3350656);   // 6,291,456 fl -> 9642112
    unsigned short* xT    = (unsigned short*)(ws + 9642112);   // 3,145,728 fl -> 12787840
    unsigned short* sigT  = (unsigned short*)(ws + 12787840);  // 16,777,216 fl -> 29565056
    unsigned short* SAtT  = sigT;                              // reuse after gemm_S
    float* region1 = ws + 29565056;                            // 16,000,000 fl -> 45565056
    unsigned short* Sb = (unsigned short*)region1;             // 8*2000*2000 bf16
    unsigned short* h2 = (unsigned short*)region1;             // 24*2000*384 bf16 (after Sb dead)

    // prep
    k_wprep<<<56, 256, 0, stream>>>(tc_w, rc_w, tcwT, rcwT);
    k_vsb<<<2048, 256, 0, stream>>>(Vs, Vsb);
    k_chebT<<<dim3(32, 32, 3), 256, 0, stream>>>(cheb, chebT);
    k_xT<<<dim3(32, 6, 8), 256, 0, stream>>>(x, xT);
    // temporal attention
    k_tprep<<<dim3(50, 8), 256, 0, stream>>>(x, U1, U3, rhsT, plh);
    k_tred<<<8, 256, 0, stream>>>(plh, lhs1);
    k_lhsT<<<750, 256, 0, stream>>>(lhs1, U2, lhsT);
    k_tatt1<<<dim3(16, 8), 256, 0, stream>>>(lhsT, rhsT, pP);
    k_tatt2<<<8, 256, 0, stream>>>(pP, be, Ve, At);
    k_xsp<<<dim3(250, 8), 256, 0, stream>>>(x, At, W1, W2, W3, lhs_s, rhs_s);
    // spatial attention
    k_sig<<<dim3(32, 32, 8), 256, 0, stream>>>(lhs_s, rhs_s, bs, sigT);
    k_gemm_S_mfma<<<dim3(16, 16, 8), 256, 0, stream>>>(Vsb, sigT, Sb);
    k_sm1<<<dim3(8, 8, 8), 256, 0, stream>>>(Sb, pm, ps);
    k_sm2<<<dim3(8, 8), 256, 0, stream>>>(pm, ps, gm, gs);
    k_sm3T<<<dim3(32, 32, 8), 256, 0, stream>>>(Sb, gm, gs, SAtT);
    // chebyshev gcn
    k_gemm_cheb_mfma<<<dim3(16, 24), 512, 0, stream>>>(chebT, SAtT, xT, h2);
    // fused theta + conv + LN tail
    k_final3<<<dim3(32, 8), 512, 0, stream>>>(x, h2, Theta, tcwT, tc_b, rcwT, rc_b, ln_g, ln_b, out);
}

// Round 8
// 646.224 us; speedup vs baseline: 7.1492x; 1.2288x over previous
//
#include <hip/hip_runtime.h>
#include <hip/hip_bf16.h>
#include <math.h>

#define B_ 8
#define N_ 2000
#define C_ 32
#define T_ 12
#define K_ 3
#define FC_ 64
#define FT_ 64
#define PW 2048   // padded width (K and row pads, zero-filled)

typedef short bf16x8 __attribute__((ext_vector_type(8)));
typedef float f32x4 __attribute__((ext_vector_type(4)));

__device__ __forceinline__ float sigmoidf(float v) { return 1.0f / (1.0f + __expf(-v)); }
__device__ __forceinline__ float bf2f(unsigned short u) {
    union { unsigned int i; float f; } v; v.i = ((unsigned int)u) << 16; return v.f;
}
__device__ __forceinline__ unsigned short f2bf(float f) {
    union { __hip_bfloat16 h; unsigned short u; } v; v.h = __float2bfloat16(f); return v.u;
}
typedef const __attribute__((address_space(1))) void* gas_t;
typedef __attribute__((address_space(3))) void* las_t;
__device__ __forceinline__ void gload16(const unsigned short* g, unsigned short* l) {
    __builtin_amdgcn_global_load_lds((gas_t)g, (las_t)l, 16, 0, 0);
}

// ---------------- fused x-pass: lhs1 partials + rhsT ----------------
__global__ __launch_bounds__(256) void k_tprep(const float* __restrict__ x, const float* __restrict__ U1,
                                               const float* __restrict__ U3,
                                               float* __restrict__ rhsT, float* __restrict__ plh) {
    int b = blockIdx.y, chunk = blockIdx.x;
    int tid = threadIdx.x;
    int nl = tid >> 5, c = tid & 31;
    int w = tid >> 6;
    float u3 = U3[c];
    float plA[12];
#pragma unroll
    for (int t = 0; t < 12; ++t) plA[t] = 0.f;
    for (int it = 0; it < 5; ++it) {
        int n = chunk * 40 + it * 8 + nl;
        const float* xp = x + ((size_t)(b * 2000 + n) * 32 + c) * 12;
        float4 v0 = *(const float4*)xp, v1 = *(const float4*)(xp + 4), v2 = *(const float4*)(xp + 8);
        float xv[12] = {v0.x, v0.y, v0.z, v0.w, v1.x, v1.y, v1.z, v1.w, v2.x, v2.y, v2.z, v2.w};
        float rv[12];
#pragma unroll
        for (int t = 0; t < 12; ++t) rv[t] = u3 * xv[t];
#pragma unroll
        for (int off = 16; off >= 1; off >>= 1)
#pragma unroll
            for (int t = 0; t < 12; ++t) rv[t] += __shfl_xor(rv[t], off);
        if (c == 0) {
#pragma unroll
            for (int t = 0; t < 12; ++t) rhsT[(size_t)(b * 2000 + n) * 12 + t] = rv[t];
        }
        float u1 = U1[n];
#pragma unroll
        for (int t = 0; t < 12; ++t) plA[t] += u1 * xv[t];
    }
#pragma unroll
    for (int t = 0; t < 12; ++t) plA[t] += __shfl_xor(plA[t], 32);
    __shared__ float accs[4][32][12];
    if ((tid & 63) < 32) {
#pragma unroll
        for (int t = 0; t < 12; ++t) accs[w][c][t] = plA[t];
    }
    __syncthreads();
    if (tid < 384) {
        int c2 = tid / 12, t2 = tid % 12;
        float s = accs[0][c2][t2] + accs[1][c2][t2] + accs[2][c2][t2] + accs[3][c2][t2];
        plh[((size_t)(b * 50 + chunk)) * 384 + tid] = s;
    }
}

__global__ __launch_bounds__(256) void k_tred(const float* __restrict__ plh, float* __restrict__ lhs1) {
    int b = blockIdx.x;
    for (int q = threadIdx.x; q < 384; q += 256) {
        const float* p = plh + (size_t)b * 50 * 384 + q;
        float s = 0.f;
        for (int ch = 0; ch < 50; ++ch) s += p[(size_t)ch * 384];
        int c = q / 12, t = q % 12;
        lhs1[(b * 12 + t) * 32 + c] = s;
    }
}

__global__ __launch_bounds__(256) void k_lhsT(const float* __restrict__ lhs1, const float* __restrict__ U2,
                                              float* __restrict__ lhsT) {
    int gid = blockIdx.x * 256 + threadIdx.x;
    if (gid >= B_ * T_ * N_) return;
    int n = gid % N_;
    int bt = gid / N_;
    const float* l1 = lhs1 + bt * C_;
    float a = 0.f;
#pragma unroll
    for (int c = 0; c < C_; ++c) a += l1[c] * U2[c * N_ + n];
    lhsT[gid] = a;
}

__global__ __launch_bounds__(256) void k_tatt1(const float* __restrict__ lhsT, const float* __restrict__ rhsT,
                                               float* __restrict__ pP) {
    int b = blockIdx.y, ch = blockIdx.x;
    int tid = threadIdx.x;
    int n0 = ch * 125;
    __shared__ float sL[12][128];
    __shared__ float sR[128][12];
    for (int q = tid; q < 12 * 125; q += 256) {
        int t = q / 125, nn = q % 125;
        sL[t][nn] = lhsT[(size_t)(b * 12 + t) * 2000 + n0 + nn];
    }
    for (int q = tid; q < 125 * 12; q += 256) {
        int nn = q / 12, t = q % 12;
        sR[nn][t] = rhsT[(size_t)(b * 2000 + n0 + nn) * 12 + t];
    }
    __syncthreads();
    if (tid < 144) {
        int tP = tid / 12, uP = tid % 12;
        float a = 0.f;
#pragma unroll 5
        for (int nn = 0; nn < 125; ++nn) a += sL[tP][nn] * sR[nn][uP];
        pP[(size_t)(b * 16 + ch) * 144 + tid] = a;
    }
}

__global__ __launch_bounds__(256) void k_tatt2(const float* __restrict__ pP, const float* __restrict__ be,
                                               const float* __restrict__ Ve, float* __restrict__ At) {
    int b = blockIdx.x, tid = threadIdx.x;
    __shared__ float sp[144], sE[144], mk[12], sk[12];
    int tP = tid / 12, uP = tid % 12;
    if (tid < 144) {
        float a = 0.f;
#pragma unroll
        for (int ch = 0; ch < 16; ++ch) a += pP[(size_t)(b * 16 + ch) * 144 + tid];
        sp[tid] = sigmoidf(a + be[tid]);
    }
    __syncthreads();
    if (tid < 144) {
        float e = 0.f;
#pragma unroll
        for (int j = 0; j < 12; ++j) e += Ve[tP * 12 + j] * sp[j * 12 + uP];
        sE[tid] = e;
    }
    __syncthreads();
    if (tid < 12) {
        float m = -1e30f;
#pragma unroll
        for (int i = 0; i < 12; ++i) m = fmaxf(m, sE[i * 12 + tid]);
        float s = 0.f;
#pragma unroll
        for (int i = 0; i < 12; ++i) s += __expf(sE[i * 12 + tid] - m);
        mk[tid] = m; sk[tid] = 1.0f / s;
    }
    __syncthreads();
    if (tid < 144) At[b * 144 + tid] = __expf(sE[tid] - mk[uP]) * sk[uP];
}

__global__ __launch_bounds__(256) void k_xsp(const float* __restrict__ x, const float* __restrict__ At,
                                             const float* __restrict__ W1, const float* __restrict__ W2,
                                             const float* __restrict__ W3,
                                             float* __restrict__ lhs_s, float* __restrict__ rhs_s) {
    int b = blockIdx.y, chunk = blockIdx.x;
    int tid = threadIdx.x, nl = tid >> 5, c = tid & 31;
    int n = chunk * 8 + nl;
    __shared__ float atl[144];
    __shared__ float w2l[384];
    __shared__ float w1l[12];
    if (tid < 144) atl[tid] = At[b * 144 + tid];
    if (tid >= 144 && tid < 156) w1l[tid - 144] = W1[tid - 144];
    for (int q = tid; q < 384; q += 256) w2l[q] = W2[q];
    __syncthreads();
    const float* xp = x + ((size_t)(b * 2000 + n) * 32 + c) * 12;
    float4 v0 = *(const float4*)xp, v1 = *(const float4*)(xp + 4), v2 = *(const float4*)(xp + 8);
    float xv[12] = {v0.x, v0.y, v0.z, v0.w, v1.x, v1.y, v1.z, v1.w, v2.x, v2.y, v2.z, v2.w};
    float xa[12];
#pragma unroll
    for (int t = 0; t < 12; ++t) {
        float s = 0.f;
#pragma unroll
        for (int u = 0; u < 12; ++u) s += xv[u] * atl[u * 12 + t];
        xa[t] = s;
    }
    float w3 = W3[c];
    float rv[12], lv[12];
    float l1 = 0.f;
#pragma unroll
    for (int t = 0; t < 12; ++t) l1 += xa[t] * w1l[t];
#pragma unroll
    for (int t = 0; t < 12; ++t) { rv[t] = w3 * xa[t]; lv[t] = l1 * w2l[c * 12 + t]; }
#pragma unroll
    for (int off = 16; off >= 1; off >>= 1)
#pragma unroll
        for (int t = 0; t < 12; ++t) { rv[t] += __shfl_xor(rv[t], off); lv[t] += __shfl_xor(lv[t], off); }
    if (c == 0) {
#pragma unroll
        for (int t = 0; t < 12; ++t) rhs_s[(size_t)(b * 12 + t) * 2000 + n] = rv[t];
#pragma unroll
        for (int t = 0; t < 12; ++t) lhs_s[(size_t)(b * 2000 + n) * 12 + t] = lv[t];
    }
}

// ---------------- weight transposes ----------------
__global__ __launch_bounds__(256) void k_wprep(const float* __restrict__ tc_w, const float* __restrict__ rc_w,
                                               float* __restrict__ tcwT, float* __restrict__ rcwT) {
    int gid = blockIdx.x * 256 + threadIdx.x;
    if (gid < 12288) {
        int fi = gid / 192, rem = gid % 192, f = rem / 3, d = rem % 3;
        tcwT[gid] = tc_w[(f * 64 + fi) * 3 + d];
    } else if (gid < 14336) {
        int q = gid - 12288;
        int c = q >> 6, f = q & 63;
        rcwT[q] = rc_w[f * 32 + c];
    }
}

// ---------------- conversions / transposes (padded to PW, zero-filled) ----------------
__global__ __launch_bounds__(256) void k_vsb(const float* __restrict__ Vs, unsigned short* __restrict__ Vsb) {
    int gid = blockIdx.x * 256 + threadIdx.x;
    int row = gid >> 8, chunk = gid & 255;
    int p0 = chunk * 8;
    unsigned short o[8];
#pragma unroll
    for (int e = 0; e < 8; ++e) {
        int p = p0 + e;
        o[e] = (row < N_ && p < N_) ? f2bf(Vs[row * N_ + p]) : (unsigned short)0;
    }
    *(int4*)(Vsb + (size_t)row * PW + p0) = *(int4*)o;
}

__global__ __launch_bounds__(256) void k_chebT(const float* __restrict__ cheb, unsigned short* __restrict__ chebT) {
    int j0 = blockIdx.x * 64, i0 = blockIdx.y * 64, kk = blockIdx.z;
    __shared__ float Tl[64][65];
    int t = threadIdx.x;
    int rr = t >> 2, c0 = (t & 3) * 16;
    int j = j0 + rr;
#pragma unroll
    for (int e = 0; e < 16; ++e) {
        int i = i0 + c0 + e;
        Tl[rr][c0 + e] = (j < N_ && i < N_) ? cheb[(size_t)kk * 4000000 + (size_t)j * N_ + i] : 0.f;
    }
    __syncthreads();
    int l = t & 63, w = t >> 6;
    unsigned short o[16];
#pragma unroll
    for (int e = 0; e < 16; ++e) o[e] = f2bf(Tl[w * 16 + e][l]);
    unsigned short* dst = chebT + (size_t)kk * PW * PW + (size_t)(i0 + l) * PW + j0 + w * 16;
    *(int4*)dst = *(int4*)o;
    *(int4*)(dst + 8) = *(int4*)(o + 8);
}

__global__ __launch_bounds__(256) void k_xT(const float* __restrict__ x, unsigned short* __restrict__ xT) {
    int j0 = blockIdx.x * 64, r0 = blockIdx.y * 64, b = blockIdx.z;
    __shared__ float Tl[64][65];
    int t = threadIdx.x;
    int rr = t >> 2, c0 = (t & 3) * 16;
    int j = j0 + rr;
#pragma unroll
    for (int e = 0; e < 16; ++e) {
        int r = r0 + c0 + e;
        Tl[rr][c0 + e] = (j < N_) ? x[(size_t)(b * N_ + j) * 384 + r] : 0.f;
    }
    __syncthreads();
    int l = t & 63, w = t >> 6;
    unsigned short o[16];
#pragma unroll
    for (int e = 0; e < 16; ++e) o[e] = f2bf(Tl[w * 16 + e][l]);
    unsigned short* dst = xT + (size_t)b * 384 * PW + (size_t)(r0 + l) * PW + j0 + w * 16;
    *(int4*)dst = *(int4*)o;
    *(int4*)(dst + 8) = *(int4*)(o + 8);
}

__global__ __launch_bounds__(256) void k_sig(const float* __restrict__ lhs_s, const float* __restrict__ rhs_s,
                                             const float* __restrict__ bs, unsigned short* __restrict__ sigT) {
    int p0 = blockIdx.x * 64, i0 = blockIdx.y * 64, b = blockIdx.z;
    __shared__ float sL[64][12];
    __shared__ float sR[12][64];
    __shared__ float bsl[64][65];
    int t = threadIdx.x;
    for (int q = t; q < 768; q += 256) {
        int pp = q / 12, tt = q % 12;
        int p = p0 + pp;
        sL[pp][tt] = (p < N_) ? lhs_s[(b * N_ + p) * 12 + tt] : 0.f;
    }
    for (int q = t; q < 768; q += 256) {
        int tt = q >> 6, ii = q & 63;
        int i = i0 + ii;
        sR[tt][ii] = (i < N_) ? rhs_s[b * (T_ * N_) + tt * N_ + i] : 0.f;
    }
    {
        int pp = t >> 2, c0 = (t & 3) * 16;
        int p = p0 + pp;
        if (p < N_ && i0 + c0 + 15 < N_) {
            const float* src = bs + (size_t)p * N_ + i0 + c0;
#pragma unroll
            for (int e = 0; e < 16; e += 4) *(float4*)&bsl[pp][c0 + e] = *(const float4*)(src + e);
        } else {
#pragma unroll
            for (int e = 0; e < 16; ++e) {
                int i = i0 + c0 + e;
                bsl[pp][c0 + e] = (p < N_ && i < N_) ? bs[(size_t)p * N_ + i] : 0.f;
            }
        }
    }
    __syncthreads();
    int ii = t & 63, w = t >> 6;
    int i = i0 + ii;
    unsigned short o[16];
#pragma unroll
    for (int e = 0; e < 16; ++e) {
        int pl = w * 16 + e;
        int p = p0 + pl;
        float v = 0.f;
        if (p < N_ && i < N_) {
            float d = bsl[pl][ii];
#pragma unroll
            for (int tt = 0; tt < 12; ++tt) d += sL[pl][tt] * sR[tt][ii];
            v = sigmoidf(d);
        }
        o[e] = f2bf(v);
    }
    unsigned short* dst = sigT + (size_t)b * PW * PW + (size_t)i * PW + p0 + w * 16;
    *(int4*)dst = *(int4*)o;
    *(int4*)(dst + 8) = *(int4*)(o + 8);
}

// ---------------- MFMA GEMM: ST[i][j] = sum_p sigT[i][p] * Vsb[j][p]  (= S^T) ----------------
__global__ __launch_bounds__(256) void k_gemm_S_mfma(const unsigned short* __restrict__ Vsb,
                                                     const unsigned short* __restrict__ sigT,
                                                     unsigned short* __restrict__ ST) {
    int b = blockIdx.z;
    int j0 = blockIdx.x * 128, i0 = blockIdx.y * 128;
    const unsigned short* Ap = sigT + (size_t)b * PW * PW;
    __shared__ unsigned short As[2][4096];
    __shared__ unsigned short Bs[2][4096];
    int t = threadIdx.x, lane = t & 63, w = t >> 6;
    int wr = w >> 1, wc = w & 1;
    f32x4 acc[4][4];
#pragma unroll
    for (int a = 0; a < 4; ++a)
#pragma unroll
        for (int c = 0; c < 4; ++c)
#pragma unroll
            for (int q = 0; q < 4; ++q) acc[a][c][q] = 0.f;
    int srow = t >> 2;
    int sseg = (t & 3) ^ (srow & 3);
    const unsigned short* gA = Ap + (size_t)(i0 + srow) * PW + sseg * 8;   // A rows = i (sigT)
    const unsigned short* gB = Vsb + (size_t)(j0 + srow) * PW + sseg * 8;  // B rows = j (Vs)
    int ldso = w * 512;
#define STAGE_S(buf, p) do { \
    gload16(gA + (p), &As[buf][ldso]); \
    gload16(gA + 64 * PW + (p), &As[buf][2048 + ldso]); \
    gload16(gB + (p), &Bs[buf][ldso]); \
    gload16(gB + 64 * PW + (p), &Bs[buf][2048 + ldso]); \
} while (0)
    STAGE_S(0, 0);
    __syncthreads();
    int cur = 0;
    int rswz = ((lane >> 4) ^ (lane & 3)) * 8;
    for (int p = 0; p < PW; p += 32) {
        if (p + 32 < PW) STAGE_S(cur ^ 1, p + 32);
        bf16x8 af[4], bfr[4];
#pragma unroll
        for (int f = 0; f < 4; ++f) {
            af[f] = *(const bf16x8*)&As[cur][(wr * 64 + f * 16 + (lane & 15)) * 32 + rswz];
            bfr[f] = *(const bf16x8*)&Bs[cur][(wc * 64 + f * 16 + (lane & 15)) * 32 + rswz];
        }
#pragma unroll
        for (int fm = 0; fm < 4; ++fm)
#pragma unroll
            for (int fn = 0; fn < 4; ++fn)
                acc[fm][fn] = __builtin_amdgcn_mfma_f32_16x16x32_bf16(af[fm], bfr[fn], acc[fm][fn], 0, 0, 0);
        __syncthreads();
        cur ^= 1;
    }
#undef STAGE_S
    unsigned short* Sp = ST + (size_t)b * PW * PW;
#pragma unroll
    for (int fm = 0; fm < 4; ++fm) {
        int row0 = i0 + wr * 64 + fm * 16 + ((lane >> 4) << 2);
#pragma unroll
        for (int fn = 0; fn < 4; ++fn) {
            int col = j0 + wc * 64 + fn * 16 + (lane & 15);
#pragma unroll
            for (int q = 0; q < 4; ++q)
                Sp[(size_t)(row0 + q) * PW + col] = f2bf(acc[fm][fn][q]);
        }
    }
}

// ---- row softmax stats over ST rows (reduction over j, i.e. original axis=1) ----
__global__ __launch_bounds__(256) void k_smrow(const unsigned short* __restrict__ ST,
                                               float* __restrict__ gm, float* __restrict__ gs) {
    int wid = threadIdx.x >> 6, lane = threadIdx.x & 63;
    int b = blockIdx.y;
    int i = blockIdx.x * 4 + wid;
    const unsigned short* rp = ST + (size_t)b * PW * PW + (size_t)i * PW;
    float vals[32];
    float m = -1e30f;
#pragma unroll
    for (int k = 0; k < 4; ++k) {
        int j0 = lane * 8 + k * 512;
        if (j0 < N_) {
            union { int4 v; unsigned short s[8]; } u;
            u.v = *(const int4*)(rp + j0);
#pragma unroll
            for (int e = 0; e < 8; ++e) {
                vals[k * 8 + e] = bf2f(u.s[e]);
                m = fmaxf(m, vals[k * 8 + e]);
            }
        } else {
#pragma unroll
            for (int e = 0; e < 8; ++e) vals[k * 8 + e] = -1e30f;  // exp -> 0
        }
    }
#pragma unroll
    for (int off = 32; off >= 1; off >>= 1) m = fmaxf(m, __shfl_xor(m, off));
    float s = 0.f;
#pragma unroll
    for (int k = 0; k < 32; ++k) s += __expf(vals[k] - m);
#pragma unroll
    for (int off = 32; off >= 1; off >>= 1) s += __shfl_xor(s, off);
    if (lane == 0) {
        gm[b * 2048 + i] = m;
        gs[b * 2048 + i] = 1.0f / s;
    }
}

// ---------------- MFMA GEMM (fused softmax-normalize in A-staging) ----------------
// h2[i][r] = sum_j chebT[i][j] * exp(ST[i][j]-gm[i]) * gs[i] * xT[r][j]
__global__ __launch_bounds__(512) void k_gemm_cheb_mfma(const unsigned short* __restrict__ chebT,
                                                        const unsigned short* __restrict__ ST,
                                                        const float* __restrict__ gm, const float* __restrict__ gs,
                                                        const unsigned short* __restrict__ xT,
                                                        unsigned short* __restrict__ h2) {
    int bk = blockIdx.y;
    int b = bk / 3, kk = bk % 3;
    int i0 = blockIdx.x * 128;
    const unsigned short* Ac = chebT + (size_t)kk * PW * PW;
    const unsigned short* Sa = ST + (size_t)b * PW * PW;
    const unsigned short* Bx = xT + (size_t)b * 384 * PW;
    __shared__ unsigned short As[2][4096];
    __shared__ unsigned short Bs[2][12288];
    int t = threadIdx.x, lane = t & 63, w = t >> 6;
    int wr = w >> 2, wc = w & 3;
    f32x4 acc[4][6];
#pragma unroll
    for (int a = 0; a < 4; ++a)
#pragma unroll
        for (int c = 0; c < 6; ++c)
#pragma unroll
            for (int q = 0; q < 4; ++q) acc[a][c][q] = 0.f;
    int arow = t >> 2, aq = t & 3;
    const unsigned short* gc = Ac + (size_t)(i0 + arow) * PW + aq * 8;
    const unsigned short* gsat = Sa + (size_t)(i0 + arow) * PW + aq * 8;
    float gmv = gm[b * 2048 + i0 + arow];
    float gsv = gs[b * 2048 + i0 + arow];
    int aoff = arow * 32 + (aq ^ (arow & 3)) * 8;
    int bseg = (t & 3) ^ ((t >> 2) & 3);
    const unsigned short* gB = Bx + (size_t)(t >> 2) * PW + bseg * 8;
    int ldso = w * 512;
#define STAGE_B(buf, p) do { \
    gload16(gB + (p), &Bs[buf][ldso]); \
    gload16(gB + 128 * PW + (p), &Bs[buf][4096 + ldso]); \
    gload16(gB + 256 * PW + (p), &Bs[buf][8192 + ldso]); \
} while (0)
    union U8 { int4 v; unsigned short s[8]; };
    U8 ca, sa;
    ca.v = *(const int4*)gc;
    sa.v = *(const int4*)gsat;
    STAGE_B(0, 0);
    {
        U8 o;
#pragma unroll
        for (int e = 0; e < 8; ++e) o.s[e] = f2bf(bf2f(ca.s[e]) * __expf(bf2f(sa.s[e]) - gmv) * gsv);
        *(int4*)&As[0][aoff] = o.v;
    }
    ca.v = *(const int4*)(gc + 32);
    sa.v = *(const int4*)(gsat + 32);
    __syncthreads();
    int cur = 0;
    int rswz = ((lane >> 4) ^ (lane & 3)) * 8;
    for (int p = 0; p < PW; p += 32) {
        if (p + 32 < PW) {
            STAGE_B(cur ^ 1, p + 32);
            U8 o;
#pragma unroll
            for (int e = 0; e < 8; ++e) o.s[e] = f2bf(bf2f(ca.s[e]) * __expf(bf2f(sa.s[e]) - gmv) * gsv);
            *(int4*)&As[cur ^ 1][aoff] = o.v;
            int pn = (p + 64 < PW) ? p + 64 : 0;
            ca.v = *(const int4*)(gc + pn);
            sa.v = *(const int4*)(gsat + pn);
        }
        bf16x8 af[4], bfr[6];
#pragma unroll
        for (int fm = 0; fm < 4; ++fm)
            af[fm] = *(const bf16x8*)&As[cur][(wr * 64 + fm * 16 + (lane & 15)) * 32 + rswz];
#pragma unroll
        for (int fn = 0; fn < 6; ++fn)
            bfr[fn] = *(const bf16x8*)&Bs[cur][(wc * 96 + fn * 16 + (lane & 15)) * 32 + rswz];
#pragma unroll
        for (int fm = 0; fm < 4; ++fm)
#pragma unroll
            for (int fn = 0; fn < 6; ++fn)
                acc[fm][fn] = __builtin_amdgcn_mfma_f32_16x16x32_bf16(af[fm], bfr[fn], acc[fm][fn], 0, 0, 0);
        __syncthreads();
        cur ^= 1;
    }
#undef STAGE_B
    unsigned short* hp = h2 + (size_t)bk * 768000;
#pragma unroll
    for (int fm = 0; fm < 4; ++fm) {
        int row0 = i0 + wr * 64 + fm * 16 + ((lane >> 4) << 2);
#pragma unroll
        for (int fn = 0; fn < 6; ++fn) {
            int col = wc * 96 + fn * 16 + (lane & 15);
#pragma unroll
            for (int q = 0; q < 4; ++q) {
                int row = row0 + q;
                if (row < N_) hp[(size_t)row * 384 + col] = f2bf(acc[fm][fn][q]);
            }
        }
    }
}

// ---------------- fused tail: theta mix + time conv + residual + relu + LayerNorm ----------------
__global__ __launch_bounds__(512) void k_final3(const float* __restrict__ x, const unsigned short* __restrict__ h2,
                                                const float* __restrict__ ThetaG,
                                                const float* __restrict__ tcwT, const float* __restrict__ tc_b,
                                                const float* __restrict__ rcwT, const float* __restrict__ rc_b,
                                                const float* __restrict__ ln_g, const float* __restrict__ ln_b,
                                                float* __restrict__ out) {
    __shared__ __align__(16) char smem[110848];
    unsigned int* gl = (unsigned int*)smem;
    unsigned short* th = (unsigned short*)(smem + 98560);
    float* red_s = (float*)(smem + 98560);
    float* red_q = red_s + 64 * 13;

    int tid = threadIdx.x;
    int n_l = tid & 63, fg = tid >> 6;
    int b = blockIdx.y;
    int node = blockIdx.x * 64 + n_l;
    bool ok = node < N_;
    int nd = ok ? node : N_ - 1;

    for (int q = tid; q < 6144; q += 512) th[q] = f2bf(ThetaG[q]);
    __syncthreads();

    float acc[8][12];
#pragma unroll
    for (int ff = 0; ff < 8; ++ff)
#pragma unroll
        for (int t = 0; t < 12; ++t) acc[ff][t] = 0.f;
    const unsigned short* hb = h2 + (size_t)b * 3 * 768000 + (size_t)nd * 384;
#pragma unroll
    for (int kk = 0; kk < 3; ++kk) {
        const unsigned short* hp = hb + (size_t)kk * 768000;
#pragma unroll 2
        for (int c = 0; c < 32; ++c) {
            const unsigned short* hq = hp + c * 12;
            uint2 u0 = *(const uint2*)(hq);
            uint2 u1 = *(const uint2*)(hq + 4);
            uint2 u2 = *(const uint2*)(hq + 8);
            float h[12];
            h[0] = bf2f((unsigned short)u0.x);  h[1] = bf2f((unsigned short)(u0.x >> 16));
            h[2] = bf2f((unsigned short)u0.y);  h[3] = bf2f((unsigned short)(u0.y >> 16));
            h[4] = bf2f((unsigned short)u1.x);  h[5] = bf2f((unsigned short)(u1.x >> 16));
            h[6] = bf2f((unsigned short)u1.y);  h[7] = bf2f((unsigned short)(u1.y >> 16));
            h[8] = bf2f((unsigned short)u2.x);  h[9] = bf2f((unsigned short)(u2.x >> 16));
            h[10] = bf2f((unsigned short)u2.y); h[11] = bf2f((unsigned short)(u2.y >> 16));
            const unsigned short* wv = th + (kk * 32 + c) * 64 + fg * 8;
            uint2 w01 = *(const uint2*)wv;
            uint2 w23 = *(const uint2*)(wv + 4);
            float wf[8];
            wf[0] = bf2f((unsigned short)w01.x); wf[1] = bf2f((unsigned short)(w01.x >> 16));
            wf[2] = bf2f((unsigned short)w01.y); wf[3] = bf2f((unsigned short)(w01.y >> 16));
            wf[4] = bf2f((unsigned short)w23.x); wf[5] = bf2f((unsigned short)(w23.x >> 16));
            wf[6] = bf2f((unsigned short)w23.y); wf[7] = bf2f((unsigned short)(w23.y >> 16));
#pragma unroll
            for (int ff = 0; ff < 8; ++ff)
#pragma unroll
                for (int t = 0; t < 12; ++t) acc[ff][t] = fmaf(h[t], wf[ff], acc[ff][t]);
        }
    }
    unsigned int* gr = gl + n_l * 385 + fg * 48;
#pragma unroll
    for (int ff = 0; ff < 8; ++ff)
#pragma unroll
        for (int tp = 0; tp < 6; ++tp) {
            float a0 = fmaxf(acc[ff][2 * tp], 0.f), a1 = fmaxf(acc[ff][2 * tp + 1], 0.f);
            gr[ff * 6 + tp] = (unsigned int)f2bf(a0) | ((unsigned int)f2bf(a1) << 16);
        }
    __syncthreads();

    float z[8][12];
#pragma unroll
    for (int ff = 0; ff < 8; ++ff) {
        float bias = tc_b[fg * 8 + ff] + rc_b[fg * 8 + ff];
#pragma unroll
        for (int t = 0; t < 12; ++t) z[ff][t] = bias;
    }
    const float* xp = x + (size_t)(b * 2000 + nd) * 384;
#pragma unroll 2
    for (int c = 0; c < 32; ++c) {
        float4 x0 = *(const float4*)(xp + c * 12);
        float4 x1 = *(const float4*)(xp + c * 12 + 4);
        float4 x2 = *(const float4*)(xp + c * 12 + 8);
        float xv[12] = {x0.x, x0.y, x0.z, x0.w, x1.x, x1.y, x1.z, x1.w, x2.x, x2.y, x2.z, x2.w};
        float4 r0 = *(const float4*)(rcwT + c * 64 + fg * 8);
        float4 r1 = *(const float4*)(rcwT + c * 64 + fg * 8 + 4);
        float rw[8] = {r0.x, r0.y, r0.z, r0.w, r1.x, r1.y, r1.z, r1.w};
#pragma unroll
        for (int ff = 0; ff < 8; ++ff)
#pragma unroll
            for (int t = 0; t < 12; ++t) z[ff][t] = fmaf(xv[t], rw[ff], z[ff][t]);
    }
    const unsigned int* grow = gl + n_l * 385;
    for (int fi = 0; fi < 64; ++fi) {
        float g[12];
#pragma unroll
        for (int j = 0; j < 6; ++j) {
            unsigned int u = grow[fi * 6 + j];
            g[2 * j] = bf2f((unsigned short)u);
            g[2 * j + 1] = bf2f((unsigned short)(u >> 16));
        }
        const float* wp = tcwT + (fi * 64 + fg * 8) * 3;
        float4 w0 = *(const float4*)(wp);
        float4 w1 = *(const float4*)(wp + 4);
        float4 w2 = *(const float4*)(wp + 8);
        float4 w3 = *(const float4*)(wp + 12);
        float4 w4 = *(const float4*)(wp + 16);
        float4 w5 = *(const float4*)(wp + 20);
        float wb[24] = {w0.x, w0.y, w0.z, w0.w, w1.x, w1.y, w1.z, w1.w,
                        w2.x, w2.y, w2.z, w2.w, w3.x, w3.y, w3.z, w3.w,
                        w4.x, w4.y, w4.z, w4.w, w5.x, w5.y, w5.z, w5.w};
#pragma unroll
        for (int ff = 0; ff < 8; ++ff) {
            float a0 = wb[ff * 3], a1 = wb[ff * 3 + 1], a2 = wb[ff * 3 + 2];
            z[ff][0] = fmaf(g[0], a1, fmaf(g[1], a2, z[ff][0]));
#pragma unroll
            for (int t = 1; t < 11; ++t)
                z[ff][t] = fmaf(g[t - 1], a0, fmaf(g[t], a1, fmaf(g[t + 1], a2, z[ff][t])));
            z[ff][11] = fmaf(g[10], a0, fmaf(g[11], a1, z[ff][11]));
        }
    }
#pragma unroll
    for (int ff = 0; ff < 8; ++ff)
#pragma unroll
        for (int t = 0; t < 12; ++t) z[ff][t] = fmaxf(z[ff][t], 0.f);

    float s[12], q[12];
#pragma unroll
    for (int t = 0; t < 12; ++t) { s[t] = 0.f; q[t] = 0.f; }
#pragma unroll
    for (int ff = 0; ff < 8; ++ff)
#pragma unroll
        for (int t = 0; t < 12; ++t) { s[t] += z[ff][t]; q[t] += z[ff][t] * z[ff][t]; }
    __syncthreads();
    for (int g = 0; g < 8; ++g) {
        if (fg == g) {
            if (g == 0) {
#pragma unroll
                for (int t = 0; t < 12; ++t) { red_s[n_l * 13 + t] = s[t]; red_q[n_l * 13 + t] = q[t]; }
            } else {
#pragma unroll
                for (int t = 0; t < 12; ++t) { red_s[n_l * 13 + t] += s[t]; red_q[n_l * 13 + t] += q[t]; }
            }
        }
        __syncthreads();
    }
    float mu[12], rs[12];
#pragma unroll
    for (int t = 0; t < 12; ++t) {
        float m = red_s[n_l * 13 + t] * (1.0f / 64.0f);
        float v = red_q[n_l * 13 + t] * (1.0f / 64.0f) - m * m;
        mu[t] = m;
        rs[t] = rsqrtf(v + 1e-5f);
    }
    if (ok) {
        float* op = out + ((size_t)(b * 2000 + node) * 64 + fg * 8) * 12;
#pragma unroll
        for (int ff = 0; ff < 8; ++ff) {
            float lg = ln_g[fg * 8 + ff], lb = ln_b[fg * 8 + ff];
            float o[12];
#pragma unroll
            for (int t = 0; t < 12; ++t) o[t] = (z[ff][t] - mu[t]) * rs[t] * lg + lb;
#pragma unroll
            for (int tq = 0; tq < 3; ++tq)
                *(float4*)(op + ff * 12 + tq * 4) = make_float4(o[tq * 4], o[tq * 4 + 1], o[tq * 4 + 2], o[tq * 4 + 3]);
        }
    }
}

extern "C" void kernel_launch(void* const* d_in, const int* in_sizes, int n_in,
                              void* d_out, int out_size, void* d_ws, size_t ws_size,
                              hipStream_t stream) {
    const float* x     = (const float*)d_in[0];
    const float* cheb  = (const float*)d_in[1];
    const float* U1    = (const float*)d_in[2];
    const float* U2    = (const float*)d_in[3];
    const float* U3    = (const float*)d_in[4];
    const float* be    = (const float*)d_in[5];
    const float* Ve    = (const float*)d_in[6];
    const float* W1    = (const float*)d_in[7];
    const float* W2    = (const float*)d_in[8];
    const float* W3    = (const float*)d_in[9];
    const float* bs    = (const float*)d_in[10];
    const float* Vs    = (const float*)d_in[11];
    const float* Theta = (const float*)d_in[12];
    const float* tc_w  = (const float*)d_in[13];
    const float* tc_b  = (const float*)d_in[14];
    const float* rc_w  = (const float*)d_in[15];
    const float* rc_b  = (const float*)d_in[16];
    const float* ln_g  = (const float*)d_in[17];
    const float* ln_b  = (const float*)d_in[18];
    float* out = (float*)d_out;

    // ---- workspace layout (~184.3 MB) ----
    float* ws    = (float*)d_ws;
    float* At    = ws;                       // 1152      -> 1152
    float* lhs1  = ws + 1152;                // 3072      -> 4224
    float* lhsT  = ws + 4224;                // 192000    -> 196224
    float* rhsT  = ws + 196224;              // 192000    -> 388224
    float* lhs_s = ws + 388224;              // 192000    -> 580224
    float* rhs_s = ws + 580224;              // 192000    -> 772224
    float* gm    = ws + 772224;              // 16384     -> 788608
    float* gs    = ws + 788608;              // 16384     -> 804992
    float* tcwT  = ws + 804992;              // 12288     -> 817280
    float* rcwT  = ws + 817280;              // 2048      -> 819328
    float* plh   = ws + 819328;              // 153600    -> 972928
    float* pP    = ws + 972928;              // 18432     -> 991360
    unsigned short* Vsb   = (unsigned short*)(ws + 991360);    // 2,097,152 fl -> 3,088,512
    unsigned short* chebT = (unsigned short*)(ws + 3088512);   // 6,291,456 fl -> 9,379,968
    unsigned short* xT    = (unsigned short*)(ws + 9379968);   // 3,145,728 fl -> 12,525,696
    unsigned short* sigT  = (unsigned short*)(ws + 12525696);  // 16,777,216 fl -> 29,302,912 (dead after gemm_S)
    unsigned short* h2    = sigT;                              // reuse: 9,216,000 fl as bf16
    unsigned short* STb   = (unsigned short*)(ws + 29302912);  // 16,777,216 fl -> 46,080,128

    // prep
    k_wprep<<<56, 256, 0, stream>>>(tc_w, rc_w, tcwT, rcwT);
    k_vsb<<<2048, 256, 0, stream>>>(Vs, Vsb);
    k_chebT<<<dim3(32, 32, 3), 256, 0, stream>>>(cheb, chebT);
    k_xT<<<dim3(32, 6, 8), 256, 0, stream>>>(x, xT);
    // temporal attention
    k_tprep<<<dim3(50, 8), 256, 0, stream>>>(x, U1, U3, rhsT, plh);
    k_tred<<<8, 256, 0, stream>>>(plh, lhs1);
    k_lhsT<<<750, 256, 0, stream>>>(lhs1, U2, lhsT);
    k_tatt1<<<dim3(16, 8), 256, 0, stream>>>(lhsT, rhsT, pP);
    k_tatt2<<<8, 256, 0, stream>>>(pP, be, Ve, At);
    k_xsp<<<dim3(250, 8), 256, 0, stream>>>(x, At, W1, W2, W3, lhs_s, rhs_s);
    // spatial attention (S^T directly)
    k_sig<<<dim3(32, 32, 8), 256, 0, stream>>>(lhs_s, rhs_s, bs, sigT);
    k_gemm_S_mfma<<<dim3(16, 16, 8), 256, 0, stream>>>(Vsb, sigT, STb);
    k_smrow<<<dim3(512, 8), 256, 0, stream>>>(STb, gm, gs);
    // chebyshev gcn with fused softmax normalization
    k_gemm_cheb_mfma<<<dim3(16, 24), 512, 0, stream>>>(chebT, STb, gm, gs, xT, h2);
    // fused theta + conv + LN tail
    k_final3<<<dim3(32, 8), 512, 0, stream>>>(x, h2, Theta, tcwT, tc_b, rcwT, rc_b, ln_g, ln_b, out);
}

// Round 9
// 643.150 us; speedup vs baseline: 7.1834x; 1.0048x over previous
//
#include <hip/hip_runtime.h>
#include <hip/hip_bf16.h>
#include <math.h>

#define B_ 8
#define N_ 2000
#define C_ 32
#define T_ 12
#define K_ 3
#define FC_ 64
#define FT_ 64
#define PW 2048   // padded width (K and row pads, zero-filled)

typedef short bf16x8 __attribute__((ext_vector_type(8)));
typedef float f32x4 __attribute__((ext_vector_type(4)));

__device__ __forceinline__ float sigmoidf(float v) { return 1.0f / (1.0f + __expf(-v)); }
__device__ __forceinline__ float bf2f(unsigned short u) {
    union { unsigned int i; float f; } v; v.i = ((unsigned int)u) << 16; return v.f;
}
__device__ __forceinline__ unsigned short f2bf(float f) {
    union { __hip_bfloat16 h; unsigned short u; } v; v.h = __float2bfloat16(f); return v.u;
}
typedef const __attribute__((address_space(1))) void* gas_t;
typedef __attribute__((address_space(3))) void* las_t;
__device__ __forceinline__ void gload16(const unsigned short* g, unsigned short* l) {
    __builtin_amdgcn_global_load_lds((gas_t)g, (las_t)l, 16, 0, 0);
}

// ---------------- fused x-pass: lhs1 partials + rhsT ----------------
__global__ __launch_bounds__(256) void k_tprep(const float* __restrict__ x, const float* __restrict__ U1,
                                               const float* __restrict__ U3,
                                               float* __restrict__ rhsT, float* __restrict__ plh) {
    int b = blockIdx.y, chunk = blockIdx.x;
    int tid = threadIdx.x;
    int nl = tid >> 5, c = tid & 31;
    int w = tid >> 6;
    float u3 = U3[c];
    float plA[12];
#pragma unroll
    for (int t = 0; t < 12; ++t) plA[t] = 0.f;
    for (int it = 0; it < 5; ++it) {
        int n = chunk * 40 + it * 8 + nl;
        const float* xp = x + ((size_t)(b * 2000 + n) * 32 + c) * 12;
        float4 v0 = *(const float4*)xp, v1 = *(const float4*)(xp + 4), v2 = *(const float4*)(xp + 8);
        float xv[12] = {v0.x, v0.y, v0.z, v0.w, v1.x, v1.y, v1.z, v1.w, v2.x, v2.y, v2.z, v2.w};
        float rv[12];
#pragma unroll
        for (int t = 0; t < 12; ++t) rv[t] = u3 * xv[t];
#pragma unroll
        for (int off = 16; off >= 1; off >>= 1)
#pragma unroll
            for (int t = 0; t < 12; ++t) rv[t] += __shfl_xor(rv[t], off);
        if (c == 0) {
#pragma unroll
            for (int t = 0; t < 12; ++t) rhsT[(size_t)(b * 2000 + n) * 12 + t] = rv[t];
        }
        float u1 = U1[n];
#pragma unroll
        for (int t = 0; t < 12; ++t) plA[t] += u1 * xv[t];
    }
#pragma unroll
    for (int t = 0; t < 12; ++t) plA[t] += __shfl_xor(plA[t], 32);
    __shared__ float accs[4][32][12];
    if ((tid & 63) < 32) {
#pragma unroll
        for (int t = 0; t < 12; ++t) accs[w][c][t] = plA[t];
    }
    __syncthreads();
    if (tid < 384) {
        int c2 = tid / 12, t2 = tid % 12;
        float s = accs[0][c2][t2] + accs[1][c2][t2] + accs[2][c2][t2] + accs[3][c2][t2];
        plh[((size_t)(b * 50 + chunk)) * 384 + tid] = s;
    }
}

__global__ __launch_bounds__(256) void k_tred(const float* __restrict__ plh, float* __restrict__ lhs1) {
    int b = blockIdx.x;
    for (int q = threadIdx.x; q < 384; q += 256) {
        const float* p = plh + (size_t)b * 50 * 384 + q;
        float s = 0.f;
        for (int ch = 0; ch < 50; ++ch) s += p[(size_t)ch * 384];
        int c = q / 12, t = q % 12;
        lhs1[(b * 12 + t) * 32 + c] = s;
    }
}

__global__ __launch_bounds__(256) void k_lhsT(const float* __restrict__ lhs1, const float* __restrict__ U2,
                                              float* __restrict__ lhsT) {
    int gid = blockIdx.x * 256 + threadIdx.x;
    if (gid >= B_ * T_ * N_) return;
    int n = gid % N_;
    int bt = gid / N_;
    const float* l1 = lhs1 + bt * C_;
    float a = 0.f;
#pragma unroll
    for (int c = 0; c < C_; ++c) a += l1[c] * U2[c * N_ + n];
    lhsT[gid] = a;
}

__global__ __launch_bounds__(256) void k_tatt1(const float* __restrict__ lhsT, const float* __restrict__ rhsT,
                                               float* __restrict__ pP) {
    int b = blockIdx.y, ch = blockIdx.x;
    int tid = threadIdx.x;
    int n0 = ch * 125;
    __shared__ float sL[12][128];
    __shared__ float sR[128][12];
    for (int q = tid; q < 12 * 125; q += 256) {
        int t = q / 125, nn = q % 125;
        sL[t][nn] = lhsT[(size_t)(b * 12 + t) * 2000 + n0 + nn];
    }
    for (int q = tid; q < 125 * 12; q += 256) {
        int nn = q / 12, t = q % 12;
        sR[nn][t] = rhsT[(size_t)(b * 2000 + n0 + nn) * 12 + t];
    }
    __syncthreads();
    if (tid < 144) {
        int tP = tid / 12, uP = tid % 12;
        float a = 0.f;
#pragma unroll 5
        for (int nn = 0; nn < 125; ++nn) a += sL[tP][nn] * sR[nn][uP];
        pP[(size_t)(b * 16 + ch) * 144 + tid] = a;
    }
}

__global__ __launch_bounds__(256) void k_tatt2(const float* __restrict__ pP, const float* __restrict__ be,
                                               const float* __restrict__ Ve, float* __restrict__ At) {
    int b = blockIdx.x, tid = threadIdx.x;
    __shared__ float sp[144], sE[144], mk[12], sk[12];
    int tP = tid / 12, uP = tid % 12;
    if (tid < 144) {
        float a = 0.f;
#pragma unroll
        for (int ch = 0; ch < 16; ++ch) a += pP[(size_t)(b * 16 + ch) * 144 + tid];
        sp[tid] = sigmoidf(a + be[tid]);
    }
    __syncthreads();
    if (tid < 144) {
        float e = 0.f;
#pragma unroll
        for (int j = 0; j < 12; ++j) e += Ve[tP * 12 + j] * sp[j * 12 + uP];
        sE[tid] = e;
    }
    __syncthreads();
    if (tid < 12) {
        float m = -1e30f;
#pragma unroll
        for (int i = 0; i < 12; ++i) m = fmaxf(m, sE[i * 12 + tid]);
        float s = 0.f;
#pragma unroll
        for (int i = 0; i < 12; ++i) s += __expf(sE[i * 12 + tid] - m);
        mk[tid] = m; sk[tid] = 1.0f / s;
    }
    __syncthreads();
    if (tid < 144) At[b * 144 + tid] = __expf(sE[tid] - mk[uP]) * sk[uP];
}

__global__ __launch_bounds__(256) void k_xsp(const float* __restrict__ x, const float* __restrict__ At,
                                             const float* __restrict__ W1, const float* __restrict__ W2,
                                             const float* __restrict__ W3,
                                             float* __restrict__ lhs_s, float* __restrict__ rhs_s) {
    int b = blockIdx.y, chunk = blockIdx.x;
    int tid = threadIdx.x, nl = tid >> 5, c = tid & 31;
    int n = chunk * 8 + nl;
    __shared__ float atl[144];
    __shared__ float w2l[384];
    __shared__ float w1l[12];
    if (tid < 144) atl[tid] = At[b * 144 + tid];
    if (tid >= 144 && tid < 156) w1l[tid - 144] = W1[tid - 144];
    for (int q = tid; q < 384; q += 256) w2l[q] = W2[q];
    __syncthreads();
    const float* xp = x + ((size_t)(b * 2000 + n) * 32 + c) * 12;
    float4 v0 = *(const float4*)xp, v1 = *(const float4*)(xp + 4), v2 = *(const float4*)(xp + 8);
    float xv[12] = {v0.x, v0.y, v0.z, v0.w, v1.x, v1.y, v1.z, v1.w, v2.x, v2.y, v2.z, v2.w};
    float xa[12];
#pragma unroll
    for (int t = 0; t < 12; ++t) {
        float s = 0.f;
#pragma unroll
        for (int u = 0; u < 12; ++u) s += xv[u] * atl[u * 12 + t];
        xa[t] = s;
    }
    float w3 = W3[c];
    float rv[12], lv[12];
    float l1 = 0.f;
#pragma unroll
    for (int t = 0; t < 12; ++t) l1 += xa[t] * w1l[t];
#pragma unroll
    for (int t = 0; t < 12; ++t) { rv[t] = w3 * xa[t]; lv[t] = l1 * w2l[c * 12 + t]; }
#pragma unroll
    for (int off = 16; off >= 1; off >>= 1)
#pragma unroll
        for (int t = 0; t < 12; ++t) { rv[t] += __shfl_xor(rv[t], off); lv[t] += __shfl_xor(lv[t], off); }
    if (c == 0) {
#pragma unroll
        for (int t = 0; t < 12; ++t) rhs_s[(size_t)(b * 12 + t) * 2000 + n] = rv[t];
#pragma unroll
        for (int t = 0; t < 12; ++t) lhs_s[(size_t)(b * 2000 + n) * 12 + t] = lv[t];
    }
}

// ---------------- weight transposes ----------------
__global__ __launch_bounds__(256) void k_wprep(const float* __restrict__ tc_w, const float* __restrict__ rc_w,
                                               float* __restrict__ tcwT, float* __restrict__ rcwT) {
    int gid = blockIdx.x * 256 + threadIdx.x;
    if (gid < 12288) {
        int fi = gid / 192, rem = gid % 192, f = rem / 3, d = rem % 3;
        tcwT[gid] = tc_w[(f * 64 + fi) * 3 + d];
    } else if (gid < 14336) {
        int q = gid - 12288;
        int c = q >> 6, f = q & 63;
        rcwT[q] = rc_w[f * 32 + c];
    }
}

// ---------------- conversions / transposes (padded to PW, zero-filled) ----------------
__global__ __launch_bounds__(256) void k_vsb(const float* __restrict__ Vs, unsigned short* __restrict__ Vsb) {
    int gid = blockIdx.x * 256 + threadIdx.x;
    int row = gid >> 8, chunk = gid & 255;
    int p0 = chunk * 8;
    unsigned short o[8];
#pragma unroll
    for (int e = 0; e < 8; ++e) {
        int p = p0 + e;
        o[e] = (row < N_ && p < N_) ? f2bf(Vs[row * N_ + p]) : (unsigned short)0;
    }
    *(int4*)(Vsb + (size_t)row * PW + p0) = *(int4*)o;
}

__global__ __launch_bounds__(256) void k_chebT(const float* __restrict__ cheb, unsigned short* __restrict__ chebT) {
    int j0 = blockIdx.x * 64, i0 = blockIdx.y * 64, kk = blockIdx.z;
    __shared__ float Tl[64][65];
    int t = threadIdx.x;
    int rr = t >> 2, c0 = (t & 3) * 16;
    int j = j0 + rr;
#pragma unroll
    for (int e = 0; e < 16; ++e) {
        int i = i0 + c0 + e;
        Tl[rr][c0 + e] = (j < N_ && i < N_) ? cheb[(size_t)kk * 4000000 + (size_t)j * N_ + i] : 0.f;
    }
    __syncthreads();
    int l = t & 63, w = t >> 6;
    unsigned short o[16];
#pragma unroll
    for (int e = 0; e < 16; ++e) o[e] = f2bf(Tl[w * 16 + e][l]);
    unsigned short* dst = chebT + (size_t)kk * PW * PW + (size_t)(i0 + l) * PW + j0 + w * 16;
    *(int4*)dst = *(int4*)o;
    *(int4*)(dst + 8) = *(int4*)(o + 8);
}

__global__ __launch_bounds__(256) void k_xT(const float* __restrict__ x, unsigned short* __restrict__ xT) {
    int j0 = blockIdx.x * 64, r0 = blockIdx.y * 64, b = blockIdx.z;
    __shared__ float Tl[64][65];
    int t = threadIdx.x;
    int rr = t >> 2, c0 = (t & 3) * 16;
    int j = j0 + rr;
#pragma unroll
    for (int e = 0; e < 16; ++e) {
        int r = r0 + c0 + e;
        Tl[rr][c0 + e] = (j < N_) ? x[(size_t)(b * N_ + j) * 384 + r] : 0.f;
    }
    __syncthreads();
    int l = t & 63, w = t >> 6;
    unsigned short o[16];
#pragma unroll
    for (int e = 0; e < 16; ++e) o[e] = f2bf(Tl[w * 16 + e][l]);
    unsigned short* dst = xT + (size_t)b * 384 * PW + (size_t)(r0 + l) * PW + j0 + w * 16;
    *(int4*)dst = *(int4*)o;
    *(int4*)(dst + 8) = *(int4*)(o + 8);
}

__global__ __launch_bounds__(256) void k_sig(const float* __restrict__ lhs_s, const float* __restrict__ rhs_s,
                                             const float* __restrict__ bs, unsigned short* __restrict__ sigT) {
    int p0 = blockIdx.x * 64, i0 = blockIdx.y * 64, b = blockIdx.z;
    __shared__ float sL[64][12];
    __shared__ float sR[12][64];
    __shared__ float bsl[64][65];
    int t = threadIdx.x;
    for (int q = t; q < 768; q += 256) {
        int pp = q / 12, tt = q % 12;
        int p = p0 + pp;
        sL[pp][tt] = (p < N_) ? lhs_s[(b * N_ + p) * 12 + tt] : 0.f;
    }
    for (int q = t; q < 768; q += 256) {
        int tt = q >> 6, ii = q & 63;
        int i = i0 + ii;
        sR[tt][ii] = (i < N_) ? rhs_s[b * (T_ * N_) + tt * N_ + i] : 0.f;
    }
    {
        int pp = t >> 2, c0 = (t & 3) * 16;
        int p = p0 + pp;
        if (p < N_ && i0 + c0 + 15 < N_) {
            const float* src = bs + (size_t)p * N_ + i0 + c0;
#pragma unroll
            for (int e = 0; e < 16; e += 4) *(float4*)&bsl[pp][c0 + e] = *(const float4*)(src + e);
        } else {
#pragma unroll
            for (int e = 0; e < 16; ++e) {
                int i = i0 + c0 + e;
                bsl[pp][c0 + e] = (p < N_ && i < N_) ? bs[(size_t)p * N_ + i] : 0.f;
            }
        }
    }
    __syncthreads();
    int ii = t & 63, w = t >> 6;
    int i = i0 + ii;
    unsigned short o[16];
#pragma unroll
    for (int e = 0; e < 16; ++e) {
        int pl = w * 16 + e;
        int p = p0 + pl;
        float v = 0.f;
        if (p < N_ && i < N_) {
            float d = bsl[pl][ii];
#pragma unroll
            for (int tt = 0; tt < 12; ++tt) d += sL[pl][tt] * sR[tt][ii];
            v = sigmoidf(d);
        }
        o[e] = f2bf(v);
    }
    unsigned short* dst = sigT + (size_t)b * PW * PW + (size_t)i * PW + p0 + w * 16;
    *(int4*)dst = *(int4*)o;
    *(int4*)(dst + 8) = *(int4*)(o + 8);
}

// ---------------- MFMA GEMM (3-slot, counted vmcnt): ST[i][j] = sum_p sigT[i][p]*Vsb[j][p] ----------------
__global__ __launch_bounds__(256) void k_gemm_S_mfma(const unsigned short* __restrict__ Vsb,
                                                     const unsigned short* __restrict__ sigT,
                                                     unsigned short* __restrict__ ST) {
    // bijective XCD swizzle: each XCD gets one batch b; within, 16 consecutive blocks share i0
    int lid = blockIdx.x + (blockIdx.y << 4) + (blockIdx.z << 8);
    int swz = (lid & 7) * 256 + (lid >> 3);
    int j0 = (swz & 15) * 128;
    int i0 = ((swz >> 4) & 15) * 128;
    int b = swz >> 8;
    const unsigned short* Ap = sigT + (size_t)b * PW * PW;
    __shared__ unsigned short As[3][4096];
    __shared__ unsigned short Bs[3][4096];
    int t = threadIdx.x, lane = t & 63, w = t >> 6;
    int wr = w >> 1, wc = w & 1;
    f32x4 acc[4][4];
#pragma unroll
    for (int a = 0; a < 4; ++a)
#pragma unroll
        for (int c = 0; c < 4; ++c)
#pragma unroll
            for (int q = 0; q < 4; ++q) acc[a][c][q] = 0.f;
    int srow = t >> 2;
    int sseg = (t & 3) ^ (srow & 3);
    const unsigned short* gA = Ap + (size_t)(i0 + srow) * PW + sseg * 8;   // A rows = i (sigT)
    const unsigned short* gB = Vsb + (size_t)(j0 + srow) * PW + sseg * 8;  // B rows = j (Vs)
    int ldso = w * 512;
#define STAGE_S(buf, p) do { \
    gload16(gA + (p), &As[buf][ldso]); \
    gload16(gA + 64 * PW + (p), &As[buf][2048 + ldso]); \
    gload16(gB + (p), &Bs[buf][ldso]); \
    gload16(gB + 64 * PW + (p), &Bs[buf][2048 + ldso]); \
} while (0)
    STAGE_S(0, 0);
    STAGE_S(1, 32);
    int s0 = 0, s1 = 1, s2 = 2;
    int rswz = ((lane >> 4) ^ (lane & 3)) * 8;
    const int nk = PW / 32;   // 64
    for (int k = 0; k < nk; ++k) {
        // tile k landed? (in-order retire: wait until only tile k+1's 4 loads outstanding)
        if (k < nk - 1) {
            asm volatile("s_waitcnt vmcnt(4)" ::: "memory");
        } else {
            asm volatile("s_waitcnt vmcnt(0)" ::: "memory");
        }
        __builtin_amdgcn_sched_barrier(0);
        __builtin_amdgcn_s_barrier();   // collective: tile k landed, slot s2 reads (iter k-1) done
        if (k + 2 < nk) STAGE_S(s2, (k + 2) * 32);
        bf16x8 af[4], bfr[4];
#pragma unroll
        for (int f = 0; f < 4; ++f) {
            af[f] = *(const bf16x8*)&As[s0][(wr * 64 + f * 16 + (lane & 15)) * 32 + rswz];
            bfr[f] = *(const bf16x8*)&Bs[s0][(wc * 64 + f * 16 + (lane & 15)) * 32 + rswz];
        }
#pragma unroll
        for (int fm = 0; fm < 4; ++fm)
#pragma unroll
            for (int fn = 0; fn < 4; ++fn)
                acc[fm][fn] = __builtin_amdgcn_mfma_f32_16x16x32_bf16(af[fm], bfr[fn], acc[fm][fn], 0, 0, 0);
        int tmp = s0; s0 = s1; s1 = s2; s2 = tmp;
    }
#undef STAGE_S
    unsigned short* Sp = ST + (size_t)b * PW * PW;
#pragma unroll
    for (int fm = 0; fm < 4; ++fm) {
        int row0 = i0 + wr * 64 + fm * 16 + ((lane >> 4) << 2);
#pragma unroll
        for (int fn = 0; fn < 4; ++fn) {
            int col = j0 + wc * 64 + fn * 16 + (lane & 15);
#pragma unroll
            for (int q = 0; q < 4; ++q)
                Sp[(size_t)(row0 + q) * PW + col] = f2bf(acc[fm][fn][q]);
        }
    }
}

// ---- row softmax stats over ST rows ----
__global__ __launch_bounds__(256) void k_smrow(const unsigned short* __restrict__ ST,
                                               float* __restrict__ gm, float* __restrict__ gs) {
    int wid = threadIdx.x >> 6, lane = threadIdx.x & 63;
    int b = blockIdx.y;
    int i = blockIdx.x * 4 + wid;
    const unsigned short* rp = ST + (size_t)b * PW * PW + (size_t)i * PW;
    float vals[32];
    float m = -1e30f;
#pragma unroll
    for (int k = 0; k < 4; ++k) {
        int j0 = lane * 8 + k * 512;
        if (j0 < N_) {
            union { int4 v; unsigned short s[8]; } u;
            u.v = *(const int4*)(rp + j0);
#pragma unroll
            for (int e = 0; e < 8; ++e) {
                vals[k * 8 + e] = bf2f(u.s[e]);
                m = fmaxf(m, vals[k * 8 + e]);
            }
        } else {
#pragma unroll
            for (int e = 0; e < 8; ++e) vals[k * 8 + e] = -1e30f;
        }
    }
#pragma unroll
    for (int off = 32; off >= 1; off >>= 1) m = fmaxf(m, __shfl_xor(m, off));
    float s = 0.f;
#pragma unroll
    for (int k = 0; k < 32; ++k) s += __expf(vals[k] - m);
#pragma unroll
    for (int off = 32; off >= 1; off >>= 1) s += __shfl_xor(s, off);
    if (lane == 0) {
        gm[b * 2048 + i] = m;
        gs[b * 2048 + i] = 1.0f / s;
    }
}

// ---------------- MFMA GEMM (fused softmax-normalize in A-staging) ----------------
__global__ __launch_bounds__(512) void k_gemm_cheb_mfma(const unsigned short* __restrict__ chebT,
                                                        const unsigned short* __restrict__ ST,
                                                        const float* __restrict__ gm, const float* __restrict__ gs,
                                                        const unsigned short* __restrict__ xT,
                                                        unsigned short* __restrict__ h2) {
    int bk = blockIdx.y;
    int b = bk / 3, kk = bk % 3;
    int i0 = blockIdx.x * 128;
    const unsigned short* Ac = chebT + (size_t)kk * PW * PW;
    const unsigned short* Sa = ST + (size_t)b * PW * PW;
    const unsigned short* Bx = xT + (size_t)b * 384 * PW;
    __shared__ unsigned short As[2][4096];
    __shared__ unsigned short Bs[2][12288];
    int t = threadIdx.x, lane = t & 63, w = t >> 6;
    int wr = w >> 2, wc = w & 3;
    f32x4 acc[4][6];
#pragma unroll
    for (int a = 0; a < 4; ++a)
#pragma unroll
        for (int c = 0; c < 6; ++c)
#pragma unroll
            for (int q = 0; q < 4; ++q) acc[a][c][q] = 0.f;
    int arow = t >> 2, aq = t & 3;
    const unsigned short* gc = Ac + (size_t)(i0 + arow) * PW + aq * 8;
    const unsigned short* gsat = Sa + (size_t)(i0 + arow) * PW + aq * 8;
    float gmv = gm[b * 2048 + i0 + arow];
    float gsv = gs[b * 2048 + i0 + arow];
    int aoff = arow * 32 + (aq ^ (arow & 3)) * 8;
    int bseg = (t & 3) ^ ((t >> 2) & 3);
    const unsigned short* gB = Bx + (size_t)(t >> 2) * PW + bseg * 8;
    int ldso = w * 512;
#define STAGE_B(buf, p) do { \
    gload16(gB + (p), &Bs[buf][ldso]); \
    gload16(gB + 128 * PW + (p), &Bs[buf][4096 + ldso]); \
    gload16(gB + 256 * PW + (p), &Bs[buf][8192 + ldso]); \
} while (0)
    union U8 { int4 v; unsigned short s[8]; };
    U8 ca, sa;
    ca.v = *(const int4*)gc;
    sa.v = *(const int4*)gsat;
    STAGE_B(0, 0);
    {
        U8 o;
#pragma unroll
        for (int e = 0; e < 8; ++e) o.s[e] = f2bf(bf2f(ca.s[e]) * __expf(bf2f(sa.s[e]) - gmv) * gsv);
        *(int4*)&As[0][aoff] = o.v;
    }
    ca.v = *(const int4*)(gc + 32);
    sa.v = *(const int4*)(gsat + 32);
    __syncthreads();
    int cur = 0;
    int rswz = ((lane >> 4) ^ (lane & 3)) * 8;
    for (int p = 0; p < PW; p += 32) {
        if (p + 32 < PW) {
            STAGE_B(cur ^ 1, p + 32);
            U8 o;
#pragma unroll
            for (int e = 0; e < 8; ++e) o.s[e] = f2bf(bf2f(ca.s[e]) * __expf(bf2f(sa.s[e]) - gmv) * gsv);
            *(int4*)&As[cur ^ 1][aoff] = o.v;
            int pn = (p + 64 < PW) ? p + 64 : 0;
            ca.v = *(const int4*)(gc + pn);
            sa.v = *(const int4*)(gsat + pn);
        }
        bf16x8 af[4], bfr[6];
#pragma unroll
        for (int fm = 0; fm < 4; ++fm)
            af[fm] = *(const bf16x8*)&As[cur][(wr * 64 + fm * 16 + (lane & 15)) * 32 + rswz];
#pragma unroll
        for (int fn = 0; fn < 6; ++fn)
            bfr[fn] = *(const bf16x8*)&Bs[cur][(wc * 96 + fn * 16 + (lane & 15)) * 32 + rswz];
#pragma unroll
        for (int fm = 0; fm < 4; ++fm)
#pragma unroll
            for (int fn = 0; fn < 6; ++fn)
                acc[fm][fn] = __builtin_amdgcn_mfma_f32_16x16x32_bf16(af[fm], bfr[fn], acc[fm][fn], 0, 0, 0);
        __syncthreads();
        cur ^= 1;
    }
#undef STAGE_B
    unsigned short* hp = h2 + (size_t)bk * 768000;
#pragma unroll
    for (int fm = 0; fm < 4; ++fm) {
        int row0 = i0 + wr * 64 + fm * 16 + ((lane >> 4) << 2);
#pragma unroll
        for (int fn = 0; fn < 6; ++fn) {
            int col = wc * 96 + fn * 16 + (lane & 15);
#pragma unroll
            for (int q = 0; q < 4; ++q) {
                int row = row0 + q;
                if (row < N_) hp[(size_t)row * 384 + col] = f2bf(acc[fm][fn][q]);
            }
        }
    }
}

// ---------------- fused tail: theta mix + time conv + residual + relu + LayerNorm ----------------
__global__ __launch_bounds__(512) void k_final3(const float* __restrict__ x, const unsigned short* __restrict__ h2,
                                                const float* __restrict__ ThetaG,
                                                const float* __restrict__ tcwT, const float* __restrict__ tc_b,
                                                const float* __restrict__ rcwT, const float* __restrict__ rc_b,
                                                const float* __restrict__ ln_g, const float* __restrict__ ln_b,
                                                float* __restrict__ out) {
    __shared__ __align__(16) char smem[110848];
    unsigned int* gl = (unsigned int*)smem;
    unsigned short* th = (unsigned short*)(smem + 98560);
    float* red_s = (float*)(smem + 98560);
    float* red_q = red_s + 64 * 13;

    int tid = threadIdx.x;
    int n_l = tid & 63, fg = tid >> 6;
    int b = blockIdx.y;
    int node = blockIdx.x * 64 + n_l;
    bool ok = node < N_;
    int nd = ok ? node : N_ - 1;

    for (int q = tid; q < 6144; q += 512) th[q] = f2bf(ThetaG[q]);
    __syncthreads();

    float acc[8][12];
#pragma unroll
    for (int ff = 0; ff < 8; ++ff)
#pragma unroll
        for (int t = 0; t < 12; ++t) acc[ff][t] = 0.f;
    const unsigned short* hb = h2 + (size_t)b * 3 * 768000 + (size_t)nd * 384;
#pragma unroll
    for (int kk = 0; kk < 3; ++kk) {
        const unsigned short* hp = hb + (size_t)kk * 768000;
#pragma unroll 2
        for (int c = 0; c < 32; ++c) {
            const unsigned short* hq = hp + c * 12;
            uint2 u0 = *(const uint2*)(hq);
            uint2 u1 = *(const uint2*)(hq + 4);
            uint2 u2 = *(const uint2*)(hq + 8);
            float h[12];
            h[0] = bf2f((unsigned short)u0.x);  h[1] = bf2f((unsigned short)(u0.x >> 16));
            h[2] = bf2f((unsigned short)u0.y);  h[3] = bf2f((unsigned short)(u0.y >> 16));
            h[4] = bf2f((unsigned short)u1.x);  h[5] = bf2f((unsigned short)(u1.x >> 16));
            h[6] = bf2f((unsigned short)u1.y);  h[7] = bf2f((unsigned short)(u1.y >> 16));
            h[8] = bf2f((unsigned short)u2.x);  h[9] = bf2f((unsigned short)(u2.x >> 16));
            h[10] = bf2f((unsigned short)u2.y); h[11] = bf2f((unsigned short)(u2.y >> 16));
            const unsigned short* wv = th + (kk * 32 + c) * 64 + fg * 8;
            uint2 w01 = *(const uint2*)wv;
            uint2 w23 = *(const uint2*)(wv + 4);
            float wf[8];
            wf[0] = bf2f((unsigned short)w01.x); wf[1] = bf2f((unsigned short)(w01.x >> 16));
            wf[2] = bf2f((unsigned short)w01.y); wf[3] = bf2f((unsigned short)(w01.y >> 16));
            wf[4] = bf2f((unsigned short)w23.x); wf[5] = bf2f((unsigned short)(w23.x >> 16));
            wf[6] = bf2f((unsigned short)w23.y); wf[7] = bf2f((unsigned short)(w23.y >> 16));
#pragma unroll
            for (int ff = 0; ff < 8; ++ff)
#pragma unroll
                for (int t = 0; t < 12; ++t) acc[ff][t] = fmaf(h[t], wf[ff], acc[ff][t]);
        }
    }
    unsigned int* gr = gl + n_l * 385 + fg * 48;
#pragma unroll
    for (int ff = 0; ff < 8; ++ff)
#pragma unroll
        for (int tp = 0; tp < 6; ++tp) {
            float a0 = fmaxf(acc[ff][2 * tp], 0.f), a1 = fmaxf(acc[ff][2 * tp + 1], 0.f);
            gr[ff * 6 + tp] = (unsigned int)f2bf(a0) | ((unsigned int)f2bf(a1) << 16);
        }
    __syncthreads();

    float z[8][12];
#pragma unroll
    for (int ff = 0; ff < 8; ++ff) {
        float bias = tc_b[fg * 8 + ff] + rc_b[fg * 8 + ff];
#pragma unroll
        for (int t = 0; t < 12; ++t) z[ff][t] = bias;
    }
    const float* xp = x + (size_t)(b * 2000 + nd) * 384;
#pragma unroll 2
    for (int c = 0; c < 32; ++c) {
        float4 x0 = *(const float4*)(xp + c * 12);
        float4 x1 = *(const float4*)(xp + c * 12 + 4);
        float4 x2 = *(const float4*)(xp + c * 12 + 8);
        float xv[12] = {x0.x, x0.y, x0.z, x0.w, x1.x, x1.y, x1.z, x1.w, x2.x, x2.y, x2.z, x2.w};
        float4 r0 = *(const float4*)(rcwT + c * 64 + fg * 8);
        float4 r1 = *(const float4*)(rcwT + c * 64 + fg * 8 + 4);
        float rw[8] = {r0.x, r0.y, r0.z, r0.w, r1.x, r1.y, r1.z, r1.w};
#pragma unroll
        for (int ff = 0; ff < 8; ++ff)
#pragma unroll
            for (int t = 0; t < 12; ++t) z[ff][t] = fmaf(xv[t], rw[ff], z[ff][t]);
    }
    const unsigned int* grow = gl + n_l * 385;
    for (int fi = 0; fi < 64; ++fi) {
        float g[12];
#pragma unroll
        for (int j = 0; j < 6; ++j) {
            unsigned int u = grow[fi * 6 + j];
            g[2 * j] = bf2f((unsigned short)u);
            g[2 * j + 1] = bf2f((unsigned short)(u >> 16));
        }
        const float* wp = tcwT + (fi * 64 + fg * 8) * 3;
        float4 w0 = *(const float4*)(wp);
        float4 w1 = *(const float4*)(wp + 4);
        float4 w2 = *(const float4*)(wp + 8);
        float4 w3 = *(const float4*)(wp + 12);
        float4 w4 = *(const float4*)(wp + 16);
        float4 w5 = *(const float4*)(wp + 20);
        float wb[24] = {w0.x, w0.y, w0.z, w0.w, w1.x, w1.y, w1.z, w1.w,
                        w2.x, w2.y, w2.z, w2.w, w3.x, w3.y, w3.z, w3.w,
                        w4.x, w4.y, w4.z, w4.w, w5.x, w5.y, w5.z, w5.w};
#pragma unroll
        for (int ff = 0; ff < 8; ++ff) {
            float a0 = wb[ff * 3], a1 = wb[ff * 3 + 1], a2 = wb[ff * 3 + 2];
            z[ff][0] = fmaf(g[0], a1, fmaf(g[1], a2, z[ff][0]));
#pragma unroll
            for (int t = 1; t < 11; ++t)
                z[ff][t] = fmaf(g[t - 1], a0, fmaf(g[t], a1, fmaf(g[t + 1], a2, z[ff][t])));
            z[ff][11] = fmaf(g[10], a0, fmaf(g[11], a1, z[ff][11]));
        }
    }
#pragma unroll
    for (int ff = 0; ff < 8; ++ff)
#pragma unroll
        for (int t = 0; t < 12; ++t) z[ff][t] = fmaxf(z[ff][t], 0.f);

    float s[12], q[12];
#pragma unroll
    for (int t = 0; t < 12; ++t) { s[t] = 0.f; q[t] = 0.f; }
#pragma unroll
    for (int ff = 0; ff < 8; ++ff)
#pragma unroll
        for (int t = 0; t < 12; ++t) { s[t] += z[ff][t]; q[t] += z[ff][t] * z[ff][t]; }
    __syncthreads();
    for (int g = 0; g < 8; ++g) {
        if (fg == g) {
            if (g == 0) {
#pragma unroll
                for (int t = 0; t < 12; ++t) { red_s[n_l * 13 + t] = s[t]; red_q[n_l * 13 + t] = q[t]; }
            } else {
#pragma unroll
                for (int t = 0; t < 12; ++t) { red_s[n_l * 13 + t] += s[t]; red_q[n_l * 13 + t] += q[t]; }
            }
        }
        __syncthreads();
    }
    float mu[12], rs[12];
#pragma unroll
    for (int t = 0; t < 12; ++t) {
        float m = red_s[n_l * 13 + t] * (1.0f / 64.0f);
        float v = red_q[n_l * 13 + t] * (1.0f / 64.0f) - m * m;
        mu[t] = m;
        rs[t] = rsqrtf(v + 1e-5f);
    }
    if (ok) {
        float* op = out + ((size_t)(b * 2000 + node) * 64 + fg * 8) * 12;
#pragma unroll
        for (int ff = 0; ff < 8; ++ff) {
            float lg = ln_g[fg * 8 + ff], lb = ln_b[fg * 8 + ff];
            float o[12];
#pragma unroll
            for (int t = 0; t < 12; ++t) o[t] = (z[ff][t] - mu[t]) * rs[t] * lg + lb;
#pragma unroll
            for (int tq = 0; tq < 3; ++tq)
                *(float4*)(op + ff * 12 + tq * 4) = make_float4(o[tq * 4], o[tq * 4 + 1], o[tq * 4 + 2], o[tq * 4 + 3]);
        }
    }
}

extern "C" void kernel_launch(void* const* d_in, const int* in_sizes, int n_in,
                              void* d_out, int out_size, void* d_ws, size_t ws_size,
                              hipStream_t stream) {
    const float* x     = (const float*)d_in[0];
    const float* cheb  = (const float*)d_in[1];
    const float* U1    = (const float*)d_in[2];
    const float* U2    = (const float*)d_in[3];
    const float* U3    = (const float*)d_in[4];
    const float* be    = (const float*)d_in[5];
    const float* Ve    = (const float*)d_in[6];
    const float* W1    = (const float*)d_in[7];
    const float* W2    = (const float*)d_in[8];
    const float* W3    = (const float*)d_in[9];
    const float* bs    = (const float*)d_in[10];
    const float* Vs    = (const float*)d_in[11];
    const float* Theta = (const float*)d_in[12];
    const float* tc_w  = (const float*)d_in[13];
    const float* tc_b  = (const float*)d_in[14];
    const float* rc_w  = (const float*)d_in[15];
    const float* rc_b  = (const float*)d_in[16];
    const float* ln_g  = (const float*)d_in[17];
    const float* ln_b  = (const float*)d_in[18];
    float* out = (float*)d_out;

    // ---- workspace layout (~184.3 MB) ----
    float* ws    = (float*)d_ws;
    float* At    = ws;                       // 1152      -> 1152
    float* lhs1  = ws + 1152;                // 3072      -> 4224
    float* lhsT  = ws + 4224;                // 192000    -> 196224
    float* rhsT  = ws + 196224;              // 192000    -> 388224
    float* lhs_s = ws + 388224;              // 192000    -> 580224
    float* rhs_s = ws + 580224;              // 192000    -> 772224
    float* gm    = ws + 772224;              // 16384     -> 788608
    float* gs    = ws + 788608;              // 16384     -> 804992
    float* tcwT  = ws + 804992;              // 12288     -> 817280
    float* rcwT  = ws + 817280;              // 2048      -> 819328
    float* plh   = ws + 819328;              // 153600    -> 972928
    float* pP    = ws + 972928;              // 18432     -> 991360
    unsigned short* Vsb   = (unsigned short*)(ws + 991360);    // 2,097,152 fl -> 3,088,512
    unsigned short* chebT = (unsigned short*)(ws + 3088512);   // 6,291,456 fl -> 9,379,968
    unsigned short* xT    = (unsigned short*)(ws + 9379968);   // 3,145,728 fl -> 12,525,696
    unsigned short* sigT  = (unsigned short*)(ws + 12525696);  // 16,777,216 fl -> 29,302,912 (dead after gemm_S)
    unsigned short* h2    = sigT;                              // reuse after gemm_S
    unsigned short* STb   = (unsigned short*)(ws + 29302912);  // 16,777,216 fl -> 46,080,128

    // prep
    k_wprep<<<56, 256, 0, stream>>>(tc_w, rc_w, tcwT, rcwT);
    k_vsb<<<2048, 256, 0, stream>>>(Vs, Vsb);
    k_chebT<<<dim3(32, 32, 3), 256, 0, stream>>>(cheb, chebT);
    k_xT<<<dim3(32, 6, 8), 256, 0, stream>>>(x, xT);
    // temporal attention
    k_tprep<<<dim3(50, 8), 256, 0, stream>>>(x, U1, U3, rhsT, plh);
    k_tred<<<8, 256, 0, stream>>>(plh, lhs1);
    k_lhsT<<<750, 256, 0, stream>>>(lhs1, U2, lhsT);
    k_tatt1<<<dim3(16, 8), 256, 0, stream>>>(lhsT, rhsT, pP);
    k_tatt2<<<8, 256, 0, stream>>>(pP, be, Ve, At);
    k_xsp<<<dim3(250, 8), 256, 0, stream>>>(x, At, W1, W2, W3, lhs_s, rhs_s);
    // spatial attention (S^T directly)
    k_sig<<<dim3(32, 32, 8), 256, 0, stream>>>(lhs_s, rhs_s, bs, sigT);
    k_gemm_S_mfma<<<dim3(16, 16, 8), 256, 0, stream>>>(Vsb, sigT, STb);
    k_smrow<<<dim3(512, 8), 256, 0, stream>>>(STb, gm, gs);
    // chebyshev gcn with fused softmax normalization
    k_gemm_cheb_mfma<<<dim3(16, 24), 512, 0, stream>>>(chebT, STb, gm, gs, xT, h2);
    // fused theta + conv + LN tail
    k_final3<<<dim3(32, 8), 512, 0, stream>>>(x, h2, Theta, tcwT, tc_b, rcwT, rc_b, ln_g, ln_b, out);
}